// Round 6
// baseline (2016.868 us; speedup 1.0000x reference)
//
#include <hip/hip_runtime.h>

#define EMB   64
#define NCON  50000
#define NVAR  100000
#define NEDGE 1600000
#define EPSLN 1e-5f

// padded-CSR capacities (worst case: every node pads +15)
#define PADEC (NEDGE + 15 * NCON)    // 2,350,000
#define PADEV (NEDGE + 15 * NVAR)    // 3,100,000

// LDS-chunked histogram: 12544 counters/chunk (50 KB LDS), C=4 chunks, V=8.
#define HCHUNK 12544
#define HSEG   32
#define HCHC   4
#define HCHV   8

typedef _Float16 half2_t __attribute__((ext_vector_type(2)));
typedef _Float16 f16x8  __attribute__((ext_vector_type(8)));
typedef float    f32x2  __attribute__((ext_vector_type(2)));

// ---- wave-total via DPP (no DS ops) ----
template <int CTRL, int RMASK>
__device__ __forceinline__ float dpp_add_f(float x) {
    int m = __builtin_amdgcn_update_dpp(0, __builtin_bit_cast(int, x), CTRL, RMASK, 0xf, true);
    return x + __builtin_bit_cast(float, m);
}
__device__ __forceinline__ float wtotal64(float x) {
    x = dpp_add_f<0x111, 0xf>(x);
    x = dpp_add_f<0x112, 0xf>(x);
    x = dpp_add_f<0x114, 0xf>(x);
    x = dpp_add_f<0x118, 0xf>(x);
    x = dpp_add_f<0x142, 0xa>(x);
    x = dpp_add_f<0x143, 0xc>(x);
    return __builtin_bit_cast(float, __builtin_amdgcn_readlane(__builtin_bit_cast(int, x), 63));
}
template <int CTRL, int RMASK>
__device__ __forceinline__ int dpp_add_i(int x) {
    return x + __builtin_amdgcn_update_dpp(0, x, CTRL, RMASK, 0xf, true);
}
__device__ __forceinline__ int wtotal64_i(int x) {
    x = dpp_add_i<0x111, 0xf>(x);
    x = dpp_add_i<0x112, 0xf>(x);
    x = dpp_add_i<0x114, 0xf>(x);
    x = dpp_add_i<0x118, 0xf>(x);
    x = dpp_add_i<0x142, 0xa>(x);
    x = dpp_add_i<0x143, 0xc>(x);
    return __builtin_amdgcn_readlane(x, 63);
}

__device__ __forceinline__ float dot2f(half2_t a, half2_t b, float c) {
    return __builtin_amdgcn_fdot2(a, b, c, false);
}

__device__ __forceinline__ half2_t hmax2(half2_t a, half2_t b) {
#if defined(__has_builtin) && __has_builtin(__builtin_elementwise_max)
    return __builtin_elementwise_max(a, b);
#else
    half2_t r;
    r.x = a.x > b.x ? a.x : b.x;
    r.y = a.y > b.y ? a.y : b.y;
    return r;
#endif
}

// 8 x ds_read_b128 + 32 x v_dot2 with 4 independent accumulator chains
__device__ __forceinline__ float matvec_f16(const _Float16* __restrict__ buf,
                                            const half2_t* __restrict__ wh, float acc) {
    const float4* hp4 = (const float4*)buf;
    float a0 = acc, a1 = 0.0f, a2 = 0.0f, a3 = 0.0f;
#pragma unroll
    for (int j4 = 0; j4 < 8; ++j4) {
        float4 t = hp4[j4];
        a0 = dot2f(wh[4 * j4 + 0], __builtin_bit_cast(half2_t, t.x), a0);
        a1 = dot2f(wh[4 * j4 + 1], __builtin_bit_cast(half2_t, t.y), a1);
        a2 = dot2f(wh[4 * j4 + 2], __builtin_bit_cast(half2_t, t.z), a2);
        a3 = dot2f(wh[4 * j4 + 3], __builtin_bit_cast(half2_t, t.w), a3);
    }
    return (a0 + a1) + (a2 + a3);
}

__device__ __forceinline__ void load_w_f16(const float* __restrict__ W, int stride,
                                           int lane, half2_t* wh) {
#pragma unroll
    for (int j4 = 0; j4 < 16; ++j4) {
        float4 t = *(const float4*)(W + (size_t)lane * stride + j4 * 4);
        wh[2 * j4 + 0] = half2_t{(_Float16)t.x, (_Float16)t.y};
        wh[2 * j4 + 1] = half2_t{(_Float16)t.z, (_Float16)t.w};
    }
}

// ---------------- CSR build ----------------

// LDS-chunked histogram, NO global atomics (round-2: 3.2M device atomicAdds
// = ~31B memory-side partial-sector writes each; 99.7 MB WRITE, 129 us).
__global__ __launch_bounds__(256) void hist_part_kernel(
        const int* __restrict__ ci, const int* __restrict__ vi,
        int* __restrict__ partC, int* __restrict__ partV, int E) {
    __shared__ int lh[HCHUNK];
    const int seg  = blockIdx.x % HSEG;
    const int cg   = blockIdx.x / HSEG;
    const bool isC = cg < HCHC;
    const int chunk = isC ? cg : cg - HCHC;
    const int base  = chunk * HCHUNK;
    const int* __restrict__ dst = isC ? ci : vi;
    int* __restrict__ part = (isC ? partC : partV) + (size_t)(chunk * HSEG + seg) * HCHUNK;

    int4* l4 = (int4*)lh;
    for (int i = threadIdx.x; i < HCHUNK / 4; i += 256) l4[i] = make_int4(0, 0, 0, 0);
    __syncthreads();

    const int s0 = (int)((long long)seg * E / HSEG);
    const int s1 = (int)((long long)(seg + 1) * E / HSEG);
    for (int i = s0 + threadIdx.x; i < s1; i += 256) {
        const unsigned rel = (unsigned)(dst[i] - base);
        if (rel < (unsigned)HCHUNK) atomicAdd(&lh[rel], 1);
    }
    __syncthreads();
    int4* p4 = (int4*)part;
    for (int i = threadIdx.x; i < HCHUNK / 4; i += 256) p4[i] = l4[i];
}

// sum the HSEG segment-partials per counter -> degC/degV (coalesced reads)
__global__ __launch_bounds__(256) void hist_reduce_kernel(
        const int* __restrict__ partC, const int* __restrict__ partV,
        int* __restrict__ degC, int* __restrict__ degV) {
    int j = blockIdx.x * blockDim.x + threadIdx.x;
    const int tot = NCON + NVAR;
    for (; j < tot; j += gridDim.x * blockDim.x) {
        if (j < NCON) {
            const int chunk = j / HCHUNK, off = j - chunk * HCHUNK;
            const int* p = partC + (size_t)chunk * HSEG * HCHUNK + off;
            int s = 0;
#pragma unroll
            for (int t = 0; t < HSEG; ++t) s += p[(size_t)t * HCHUNK];
            degC[j] = s;
        } else {
            const int jj = j - NCON;
            const int chunk = jj / HCHUNK, off = jj - chunk * HCHUNK;
            const int* p = partV + (size_t)chunk * HSEG * HCHUNK + off;
            int s = 0;
#pragma unroll
            for (int t = 0; t < HSEG; ++t) s += p[(size_t)t * HCHUNK];
            degV[jj] = s;
        }
    }
}

// fallback: atomic histogram (used only if ws can't fit the partials)
__global__ __launch_bounds__(256) void hist2_kernel(
        const int* __restrict__ ci, const int* __restrict__ vi,
        int* __restrict__ degC, int* __restrict__ degV, int E) {
    int i = blockIdx.x * blockDim.x + threadIdx.x;
    for (; i < E; i += gridDim.x * blockDim.x) {
        atomicAdd(&degC[ci[i]], 1);
        atomicAdd(&degV[vi[i]], 1);
    }
}

template <bool PAD>
__global__ __launch_bounds__(256) void chunk_sum_kernel(const int* __restrict__ hist,
                                                        int* __restrict__ csum, int N) {
    __shared__ int wpart[4];
    const int base = blockIdx.x * 1024 + threadIdx.x * 4;
    int s = 0;
    if (base + 3 < N) {
        int4 t = *(const int4*)(hist + base);
        if (PAD) s = ((t.x+15)&~15) + ((t.y+15)&~15) + ((t.z+15)&~15) + ((t.w+15)&~15);
        else     s = t.x + t.y + t.z + t.w;
    } else {
#pragma unroll
        for (int j = 0; j < 4; ++j)
            if (base + j < N) { int v = hist[base + j]; s += PAD ? ((v+15)&~15) : v; }
    }
    s = wtotal64_i(s);
    if ((threadIdx.x & 63) == 0) wpart[threadIdx.x >> 6] = s;
    __syncthreads();
    if (threadIdx.x == 0) csum[blockIdx.x] = wpart[0] + wpart[1] + wpart[2] + wpart[3];
}

__global__ void chunk_offsets_kernel(const int* __restrict__ csum, int* __restrict__ coff,
                                     int* __restrict__ rowptr, int nchunk, int N) {
    const int lane = threadIdx.x;
    int carry = 0;
    for (int base = 0; base < nchunk; base += 64) {
        const int i = base + lane;
        int val = (i < nchunk) ? csum[i] : 0;
        int incl = val;
#pragma unroll
        for (int off = 1; off < 64; off <<= 1) {
            int t = __shfl_up(incl, off, 64);
            if (lane >= off) incl += t;
        }
        if (i < nchunk) coff[i] = incl - val + carry;
        carry += __shfl(incl, 63, 64);
    }
    if (lane == 0) rowptr[N] = carry;
}

template <bool PAD>
__global__ __launch_bounds__(256) void chunk_apply_kernel(
        const int* __restrict__ hist, const int* __restrict__ coff,
        int* __restrict__ rowptr, int* __restrict__ cursor, int N) {
    __shared__ int wpart[4];
    const int wv = threadIdx.x >> 6;
    const int lane = threadIdx.x & 63;
    const int base = blockIdx.x * 1024 + threadIdx.x * 4;
    int v0 = 0, v1 = 0, v2 = 0, v3 = 0;
    if (base + 3 < N) {
        int4 t = *(const int4*)(hist + base);
        v0 = t.x; v1 = t.y; v2 = t.z; v3 = t.w;
    } else {
        if (base + 0 < N) v0 = hist[base + 0];
        if (base + 1 < N) v1 = hist[base + 1];
        if (base + 2 < N) v2 = hist[base + 2];
        if (base + 3 < N) v3 = hist[base + 3];
    }
    if (PAD) { v0 = (v0+15)&~15; v1 = (v1+15)&~15; v2 = (v2+15)&~15; v3 = (v3+15)&~15; }
    const int s = v0 + v1 + v2 + v3;
    int incl = s;
#pragma unroll
    for (int off = 1; off < 64; off <<= 1) {
        int t = __shfl_up(incl, off, 64);
        if (lane >= off) incl += t;
    }
    if (lane == 63) wpart[wv] = incl;
    __syncthreads();
    int excl = coff[blockIdx.x] + incl - s;
    for (int w = 0; w < wv; ++w) excl += wpart[w];
    if (base + 0 < N) { rowptr[base + 0] = excl; cursor[base + 0] = excl; excl += v0; }
    if (base + 1 < N) { rowptr[base + 1] = excl; cursor[base + 1] = excl; excl += v1; }
    if (base + 2 < N) { rowptr[base + 2] = excl; cursor[base + 2] = excl; excl += v2; }
    if (base + 3 < N) { rowptr[base + 3] = excl; cursor[base + 3] = excl; excl += v3; }
}

// XCD-bucketed scatter, ONE direction per launch (round-2 verified: each
// XCD's L2 holds one bucket's CSR region -> write combining).
template <int NDST>
__global__ __launch_bounds__(256) void scatter_dir_kernel(
        const int* __restrict__ dst, const int* __restrict__ src,
        const float* __restrict__ ef,
        int* __restrict__ cur, int2* __restrict__ ep, int E) {
    const int rep = blockIdx.x & 7;
    const int stride = (gridDim.x >> 3) * blockDim.x;
    int i = (blockIdx.x >> 3) * blockDim.x + threadIdx.x;
    for (; i < E; i += stride) {
        const int d = dst[i];
        const int b = (int)(((long long)d * 8) / NDST);
        if (b == rep) {
            const int slot = atomicAdd(&cur[d], 1);
            ep[slot] = make_int2(src[i], __float_as_int(ef[i]));
        }
    }
}

// ---------------- fused node linear: RL segment + LL segment -> f16 ----------------

__global__ __launch_bounds__(256, 4) void lin2_kernel(
        const float* __restrict__ XR, const float* __restrict__ WR,
        const float* __restrict__ bR, _Float16* __restrict__ YR, int NR,
        const float* __restrict__ XL, const float* __restrict__ WL,
        _Float16* __restrict__ YL, int NL, int nbR) {
    __shared__ __align__(16) _Float16 xbuf[4][EMB];
    const int wv = threadIdx.x >> 6;
    const int lane = threadIdx.x & 63;
    const bool isR = (int)blockIdx.x < nbR;
    const float* X = isR ? XR : XL;
    _Float16* Y    = isR ? YR : YL;
    const int N    = isR ? NR : NL;
    const int b0   = isR ? 0 : nbR;
    const int nb   = isR ? nbR : (gridDim.x - nbR);
    half2_t wh[32];
    load_w_f16(isR ? WR : WL, EMB, lane, wh);
    const float bias = isR ? bR[lane] : 0.0f;
    const int nW = nb * 4;
    for (int n = ((int)blockIdx.x - b0) * 4 + wv; n < N; n += nW) {
        xbuf[wv][lane] = (_Float16)X[(size_t)n * EMB + lane];
        Y[(size_t)n * EMB + lane] = (_Float16)matvec_f16(xbuf[wv], wh, bias);
    }
}

// ---------------- edge stage: wave per node, abar accumulate, Wf once/node ----------------
// Key identity: sum_e relu(LN(h_e)) @ Wf^T = (sum_e relu(LN(h_e))) @ Wf^T  (matvec is linear).
// Round-5 lesson: on this toolchain the 2nd __launch_bounds__ arg acts as an
// occupancy TARGET/CAP: (256,4)->~16 waves/CU (37%), (256,3)->~12 (27%).
// The kernel is latency-bound on the LL gather -> wants MORE waves. VGPR=68
// (72 alloc) supports 7 waves/SIMD; LDS 17.9KB supports 8 blocks/CU. (256,6)
// sets VGPR budget 512/6=85 (>68 achieved under the looser cap -> no spill)
// and asks for 24 waves/CU, 2x round-4 residency.
//  (a) LDS-transpose reduce: 4x ds_write_b128 into [16][68]-padded tile + 16x
//      ds_read_b32 column tree-sum replaces the 128-VALU shuffle butterfly.
//  (b) cross-node pipeline: next node's meta at iteration top; next node's
//      first ep-group + LL gather issued in the last group's prefetch slot.

__global__ __launch_bounds__(256, 6) void edge_abar_kernel(
        const int* __restrict__ rp16, const int* __restrict__ deg,
        const int2* __restrict__ ep,
        const _Float16* __restrict__ RL, const _Float16* __restrict__ LL,
        const float* __restrict__ We, const float* __restrict__ g1,
        const float* __restrict__ b1, const float* __restrict__ Wf,
        const float* __restrict__ bfp, _Float16* __restrict__ AGG, int Nr) {
    __shared__ __align__(16) _Float16 abuf[4][EMB];
    __shared__ __align__(16) float tbuf[4][16][68];   // [wave][col][k] padded stride
    const int wv   = threadIdx.x >> 6;
    const int lane = threadIdx.x & 63;
    const int col  = lane & 15;
    const int quad = lane >> 4;
    const int kb   = quad * 8;

    half2_t weh[8], gkh[8], bkh[8];
#pragma unroll
    for (int j = 0; j < 4; ++j) {
        weh[j]     = half2_t{(_Float16)We[kb + 2*j],      (_Float16)We[kb + 2*j + 1]};
        weh[4 + j] = half2_t{(_Float16)We[kb + 32 + 2*j], (_Float16)We[kb + 32 + 2*j + 1]};
        gkh[j]     = half2_t{(_Float16)g1[kb + 2*j],      (_Float16)g1[kb + 2*j + 1]};
        gkh[4 + j] = half2_t{(_Float16)g1[kb + 32 + 2*j], (_Float16)g1[kb + 32 + 2*j + 1]};
        bkh[j]     = half2_t{(_Float16)b1[kb + 2*j],      (_Float16)b1[kb + 2*j + 1]};
        bkh[4 + j] = half2_t{(_Float16)b1[kb + 32 + 2*j], (_Float16)b1[kb + 32 + 2*j + 1]};
    }
    half2_t whF[32];
    load_w_f16(Wf, EMB, lane, whF);
    const float bfv = bfp[lane];

    const int nW = gridDim.x * 4;
    int n = blockIdx.x * 4 + wv;          // Nr >= 50000 > grid*4, so n < Nr here
    int pg0 = rp16[n] >> 4;
    int pg1 = rp16[n + 1] >> 4;
    int pdn = deg[n];

    bool livN = false; float fN = 0.0f;
    f16x8 llaN = {}, llbN = {};
    auto issue_group = [&](int gbase, int cnt) {
        livN = col < cnt;
        int2 p = ep[(gbase << 4) + col];
        const int s2 = livN ? p.x : 0;
        fN = livN ? __int_as_float(p.y) : 0.0f;
        llaN = *(const f16x8*)(LL + (size_t)s2 * EMB + kb);
        llbN = *(const f16x8*)(LL + (size_t)s2 * EMB + kb + 32);
    };
    if (pg0 < pg1) issue_group(pg0, pdn);     // prime first node's first group

    while (true) {
        const int g0 = pg0, g1e = pg1, dn = pdn;
        const int nn = n + nW;
        const bool hasNext = nn < Nr;
        if (hasNext) {                         // issue next node's meta EARLY
            pg0 = rp16[nn] >> 4;
            pg1 = rp16[nn + 1] >> 4;
            pdn = deg[nn];
        }

        half2_t rl2[8];
        *(f16x8*)&rl2[0] = *(const f16x8*)(RL + (size_t)n * EMB + kb);
        *(f16x8*)&rl2[4] = *(const f16x8*)(RL + (size_t)n * EMB + kb + 32);

        f32x2 acc2[8];
#pragma unroll
        for (int j = 0; j < 8; ++j) acc2[j] = f32x2{0.0f, 0.0f};

        bool didNext = false;
        for (int g = g0; g < g1e; ++g) {
            const bool liv = livN;
            const float f = fN;
            half2_t h2[8];
            *(f16x8*)&h2[0] = llaN;
            *(f16x8*)&h2[4] = llbN;
            if (g + 1 < g1e) {
                issue_group(g + 1, dn - ((g + 1 - g0) << 4));   // in-node prefetch
            } else if (hasNext && pg0 < pg1) {
                issue_group(pg0, pdn);                           // next-node prefetch
                didNext = true;
            }
            const _Float16 fh = (_Float16)f;
            const half2_t f2 = half2_t{fh, fh};
            const half2_t one2 = half2_t{(_Float16)1.0f, (_Float16)1.0f};
            float ps = 0.0f, pq = 0.0f;
#pragma unroll
            for (int j = 0; j < 8; ++j) {
                h2[j] = (h2[j] + rl2[j]) + f2 * weh[j];
                ps = dot2f(h2[j], one2, ps);
                pq = dot2f(h2[j], h2[j], pq);
            }
            ps += __shfl_xor(ps, 16, 64); ps += __shfl_xor(ps, 32, 64);
            pq += __shfl_xor(pq, 16, 64); pq += __shfl_xor(pq, 32, 64);
            const float mean = ps * (1.0f / EMB);
            const float var  = pq * (1.0f / EMB) - mean * mean;
            const float rs   = rsqrtf(var + EPSLN);
            const _Float16 rsh = (_Float16)rs;
            const _Float16 mnh = (_Float16)mean;
            const half2_t rs2 = half2_t{rsh, rsh};
            const half2_t mn2 = half2_t{mnh, mnh};
            const half2_t z2  = half2_t{(_Float16)0.0f, (_Float16)0.0f};
            if (liv) {
#pragma unroll
                for (int j = 0; j < 8; ++j) {
                    const half2_t sc = gkh[j] * rs2;
                    half2_t a = (h2[j] - mn2) * sc + bkh[j];
                    a = hmax2(a, z2);
                    f32x2 cv; cv.x = (float)a.x; cv.y = (float)a.y;
                    acc2[j] += cv;
                }
            }
        }

        // ---- LDS-transpose reduce: acc2[j] of lane (col,quad) covers
        //      k = kb..kb+7 (acc2[0..3]) and kb+32..kb+39 (acc2[4..7]) ----
        float* tb = &tbuf[wv][col][0];
        *(float4*)(tb + kb)      = make_float4(acc2[0].x, acc2[0].y, acc2[1].x, acc2[1].y);
        *(float4*)(tb + kb + 4)  = make_float4(acc2[2].x, acc2[2].y, acc2[3].x, acc2[3].y);
        *(float4*)(tb + kb + 32) = make_float4(acc2[4].x, acc2[4].y, acc2[5].x, acc2[5].y);
        *(float4*)(tb + kb + 36) = make_float4(acc2[6].x, acc2[6].y, acc2[7].x, acc2[7].y);
        // tree-sum 16 statically-indexed column reads (short dep chain)
        float t0[16];
#pragma unroll
        for (int c2 = 0; c2 < 16; ++c2) t0[c2] = tbuf[wv][c2][lane];
        const float s01 = (t0[0] + t0[1]) + (t0[2] + t0[3]);
        const float s23 = (t0[4] + t0[5]) + (t0[6] + t0[7]);
        const float s45 = (t0[8] + t0[9]) + (t0[10] + t0[11]);
        const float s67 = (t0[12] + t0[13]) + (t0[14] + t0[15]);
        abuf[wv][lane] = (_Float16)((s01 + s23) + (s45 + s67));
        // agg = abar @ Wf^T + deg*bf   (one matvec per node)
        AGG[(size_t)n * EMB + lane] = (_Float16)matvec_f16(abuf[wv], whF, (float)dn * bfv);

        if (!hasNext) break;
        if (!didNext && pg0 < pg1) issue_group(pg0, pdn);   // zero-group edge cases
        n = nn;
    }
}

// ---------------- fallback edge path (wave per node, dot2, f16 RL/LL) ----------------

__global__ __launch_bounds__(256, 4) void edge_csr_kernel(
        const int* __restrict__ rowptr, const int2* __restrict__ ep,
        const _Float16* __restrict__ RL, const _Float16* __restrict__ LL,
        const float* __restrict__ Wecol, const float* __restrict__ g1,
        const float* __restrict__ b1,
        const float* __restrict__ Wf, const float* __restrict__ bfp,
        _Float16* __restrict__ AGG, int Nr) {
    __shared__ __align__(16) _Float16 hbuf[4][EMB];
    const int wv = threadIdx.x >> 6;
    const int lane = threadIdx.x & 63;
    half2_t wh[32];
    load_w_f16(Wf, EMB, lane, wh);
    const float we  = Wecol[lane];
    const float g   = g1[lane];
    const float bb  = b1[lane];
    const float bf_ = bfp[lane];
    const int nW = gridDim.x * 4;
    for (int n = blockIdx.x * 4 + wv; n < Nr; n += nW) {
        const int beg = rowptr[n];
        const int end = rowptr[n + 1];
        const float rl = (float)RL[(size_t)n * EMB + lane];
        float acc = 0.0f;
        for (int idx = beg; idx < end; ++idx) {
            const int2 p = ep[idx];
            const float f = __int_as_float(p.y);
            float h = rl + (float)LL[(size_t)p.x * EMB + lane] + f * we;
            const float s1 = wtotal64(h);
            const float s2 = wtotal64(h * h);
            const float m   = s1 * (1.0f / EMB);
            const float var = s2 * (1.0f / EMB) - m * m;
            float hn = fmaxf((h - m) * rsqrtf(var + EPSLN) * g + bb, 0.0f);
            hbuf[wv][lane] = (_Float16)hn;
            acc = matvec_f16(hbuf[wv], wh, acc);
        }
        AGG[(size_t)n * EMB + lane] = (_Float16)(acc + (float)(end - beg) * bf_);
    }
}

// ---------------- fused output MLP ----------------
// z = LN(AGG); o = relu(Wo1a@z + Wo1b@right + bo1); right += Wo2@o + bo2

__global__ __launch_bounds__(256, 3) void out_kernel(
        const _Float16* __restrict__ AGG, float* __restrict__ right,
        const float* __restrict__ g2, const float* __restrict__ b2,
        const float* __restrict__ Wo1, const float* __restrict__ Wo2,
        const float* __restrict__ bo1, const float* __restrict__ bo2, int N) {
    __shared__ __align__(16) _Float16 zbuf[4][EMB];
    __shared__ __align__(16) _Float16 rbuf[4][EMB];
    __shared__ __align__(16) _Float16 obuf[4][EMB];
    const int wv = threadIdx.x >> 6;
    const int lane = threadIdx.x & 63;
    half2_t wh1[32], whB[32], wh2[32];
    load_w_f16(Wo1, 2 * EMB, lane, wh1);            // Wo1[:, 0:64]
    load_w_f16(Wo1 + EMB, 2 * EMB, lane, whB);      // Wo1[:, 64:128]
    load_w_f16(Wo2, EMB, lane, wh2);
    const float g    = g2[lane];
    const float bb   = b2[lane];
    const float bo1v = bo1[lane];
    const float bo2v = bo2[lane];
    const int nW = gridDim.x * 4;
    for (int n = blockIdx.x * 4 + wv; n < N; n += nW) {
        const float a = (float)AGG[(size_t)n * EMB + lane];
        const float rf = right[(size_t)n * EMB + lane];
        const float s1 = wtotal64(a);
        const float s2 = wtotal64(a * a);
        const float m   = s1 * (1.0f / EMB);
        const float var = s2 * (1.0f / EMB) - m * m;
        const float z = (a - m) * rsqrtf(var + EPSLN) * g + bb;
        zbuf[wv][lane] = (_Float16)z;
        rbuf[wv][lane] = (_Float16)rf;
        float acc = matvec_f16(zbuf[wv], wh1, bo1v);
        acc = matvec_f16(rbuf[wv], whB, acc);
        obuf[wv][lane] = (_Float16)fmaxf(acc, 0.0f);
        float acc2 = matvec_f16(obuf[wv], wh2, bo2v);
        right[(size_t)n * EMB + lane] = rf + acc2;
    }
}

extern "C" void kernel_launch(void* const* d_in, const int* in_sizes, int n_in,
                              void* d_out, int out_size, void* d_ws, size_t ws_size,
                              hipStream_t stream) {
    const float* cf  = (const float*)d_in[0];
    const float* vfp = (const float*)d_in[1];
    const int*   ei  = (const int*)d_in[2];
    const float* ef  = (const float*)d_in[3];
    const float* Wl  = (const float*)d_in[4];
    const float* bl  = (const float*)d_in[5];
    const float* We  = (const float*)d_in[6];
    const float* Wr  = (const float*)d_in[7];
    const float* g1  = (const float*)d_in[8];
    const float* b1  = (const float*)d_in[9];
    const float* Wf  = (const float*)d_in[10];
    const float* bfp = (const float*)d_in[11];
    const float* g2  = (const float*)d_in[12];
    const float* b2  = (const float*)d_in[13];
    const float* Wo1 = (const float*)d_in[14];
    const float* bo1 = (const float*)d_in[15];
    const float* Wo2 = (const float*)d_in[16];
    const float* bo2 = (const float*)d_in[17];

    float* c = (float*)d_out;
    float* v = c + (size_t)NCON * EMB;
    (void)hipMemcpyAsync(c, cf,  (size_t)NCON * EMB * sizeof(float), hipMemcpyDeviceToDevice, stream);
    (void)hipMemcpyAsync(v, vfp, (size_t)NVAR * EMB * sizeof(float), hipMemcpyDeviceToDevice, stream);

    float* wsf = (float*)d_ws;
    size_t off = 0;
    _Float16* AGG = (_Float16*)(wsf + off); off += (size_t)NVAR * EMB / 2;  // f16
    _Float16* RL  = (_Float16*)(wsf + off); off += (size_t)NVAR * EMB / 2;  // f16
    _Float16* LL  = (_Float16*)(wsf + off); off += (size_t)NVAR * EMB / 2;  // f16
    int* degC  = (int*)(wsf + off); off += NCON;
    int* degV  = (int*)(wsf + off); off += NVAR;
    int* rp16C = (int*)(wsf + off); off += NCON + 4;
    int* curC  = (int*)(wsf + off); off += NCON;
    int* rp16V = (int*)(wsf + off); off += NVAR + 4;
    int* curV  = (int*)(wsf + off); off += NVAR;
    int* csumC = (int*)(wsf + off); off += 128;
    int* coffC = (int*)(wsf + off); off += 128;
    int* csumV = (int*)(wsf + off); off += 128;
    int* coffV = (int*)(wsf + off); off += 128;
    size_t off_edges = off;
    int2* epC = (int2*)(wsf + off); off += (size_t)2 * PADEC;
    int2* epV = (int2*)(wsf + off); off += (size_t)2 * PADEV;
    const bool use_mfma = ws_size >= off * sizeof(float);
    // histogram partials (19.3 MB) after the edge arrays
    int* partC = (int*)(wsf + off); off += (size_t)HCHC * HSEG * HCHUNK;
    int* partV = (int*)(wsf + off); off += (size_t)HCHV * HSEG * HCHUNK;
    const bool use_ldshist = use_mfma && ws_size >= off * sizeof(float);
    if (!use_mfma) {
        off = off_edges;
        epC = (int2*)(wsf + off); off += (size_t)2 * NEDGE;
        epV = (int2*)(wsf + off); off += (size_t)2 * NEDGE;
    }

    const int* ci = ei;
    const int* vi = ei + NEDGE;

    const dim3 blk(256);
    const int NB = 2048;
    const int NBL = 1536;
    const int nchC = (NCON + 1023) / 1024;   // 49
    const int nchV = (NVAR + 1023) / 1024;   // 98

    if (use_ldshist) {
        hist_part_kernel<<<(HCHC + HCHV) * HSEG, blk, 0, stream>>>(ci, vi, partC, partV, NEDGE);
        hist_reduce_kernel<<<640, blk, 0, stream>>>(partC, partV, degC, degV);
    } else {
        (void)hipMemsetAsync(degC, 0, NCON * sizeof(int), stream);
        (void)hipMemsetAsync(degV, 0, NVAR * sizeof(int), stream);
        hist2_kernel<<<1024, blk, 0, stream>>>(ci, vi, degC, degV, NEDGE);
    }
    if (use_mfma) {
        chunk_sum_kernel<true><<<nchC, blk, 0, stream>>>(degC, csumC, NCON);
        chunk_sum_kernel<true><<<nchV, blk, 0, stream>>>(degV, csumV, NVAR);
        chunk_offsets_kernel<<<1, 64, 0, stream>>>(csumC, coffC, rp16C, nchC, NCON);
        chunk_offsets_kernel<<<1, 64, 0, stream>>>(csumV, coffV, rp16V, nchV, NVAR);
        chunk_apply_kernel<true><<<nchC, blk, 0, stream>>>(degC, coffC, rp16C, curC, NCON);
        chunk_apply_kernel<true><<<nchV, blk, 0, stream>>>(degV, coffV, rp16V, curV, NVAR);
    } else {
        chunk_sum_kernel<false><<<nchC, blk, 0, stream>>>(degC, csumC, NCON);
        chunk_sum_kernel<false><<<nchV, blk, 0, stream>>>(degV, csumV, NVAR);
        chunk_offsets_kernel<<<1, 64, 0, stream>>>(csumC, coffC, rp16C, nchC, NCON);
        chunk_offsets_kernel<<<1, 64, 0, stream>>>(csumV, coffV, rp16V, nchV, NVAR);
        chunk_apply_kernel<false><<<nchC, blk, 0, stream>>>(degC, coffC, rp16C, curC, NCON);
        chunk_apply_kernel<false><<<nchV, blk, 0, stream>>>(degV, coffV, rp16V, curV, NVAR);
    }
    // one direction per launch: hard temporal separation so each XCD's L2
    // holds only that direction's bucket region (C: 2.35 MB, V: 3.1 MB).
    scatter_dir_kernel<NCON><<<2048, blk, 0, stream>>>(ci, vi, ef, curC, epC, NEDGE);
    scatter_dir_kernel<NVAR><<<2048, blk, 0, stream>>>(vi, ci, ef, curV, epV, NEDGE);

    for (int k = 0; k < 4; ++k) {
        const bool v2c = ((k & 1) == 0);
        float* right   = v2c ? c : v;
        float* left    = v2c ? v : c;
        const int Nr   = v2c ? NCON : NVAR;
        const int Nl   = v2c ? NVAR : NCON;
        const int nbR  = v2c ? NBL / 3 : 2 * NBL / 3;   // split blocks ~ Nr : Nl

        lin2_kernel<<<NBL, blk, 0, stream>>>(
            right, Wl + (size_t)k * EMB * EMB, bl + (size_t)k * EMB, RL, Nr,
            left,  Wr + (size_t)k * EMB * EMB, LL, Nl, nbR);

        if (use_mfma) {
            edge_abar_kernel<<<NB, blk, 0, stream>>>(
                v2c ? rp16C : rp16V, v2c ? degC : degV, v2c ? epC : epV,
                RL, LL, We + (size_t)k * EMB,
                g1 + (size_t)k * EMB, b1 + (size_t)k * EMB,
                Wf + (size_t)k * EMB * EMB, bfp + (size_t)k * EMB, AGG, Nr);
        } else {
            edge_csr_kernel<<<NB, blk, 0, stream>>>(
                v2c ? rp16C : rp16V, v2c ? epC : epV,
                RL, LL, We + (size_t)k * EMB,
                g1 + (size_t)k * EMB, b1 + (size_t)k * EMB,
                Wf + (size_t)k * EMB * EMB, bfp + (size_t)k * EMB, AGG, Nr);
        }
        out_kernel<<<NB, blk, 0, stream>>>(AGG, right,
                                           g2 + (size_t)k * EMB, b2 + (size_t)k * EMB,
                                           Wo1 + (size_t)k * EMB * 2 * EMB,
                                           Wo2 + (size_t)k * EMB * EMB,
                                           bo1 + (size_t)k * EMB, bo2 + (size_t)k * EMB,
                                           Nr);
    }
}

// Round 7
// 1146.121 us; speedup vs baseline: 1.7597x; 1.7597x over previous
//
#include <hip/hip_runtime.h>

#define EMB   64
#define NCON  50000
#define NVAR  100000
#define NEDGE 1600000
#define EPSLN 1e-5f

// padded-CSR capacities (worst case: every node pads +15)
#define PADEC (NEDGE + 15 * NCON)    // 2,350,000
#define PADEV (NEDGE + 15 * NVAR)    // 3,100,000

// LDS-chunked histogram: 12544 counters/chunk (50 KB LDS), C=4 chunks, V=8.
#define HCHUNK 12544
#define HSEG   32
#define HCHC   4
#define HCHV   8

typedef _Float16 half2_t __attribute__((ext_vector_type(2)));
typedef _Float16 f16x8  __attribute__((ext_vector_type(8)));
typedef float    f32x2  __attribute__((ext_vector_type(2)));

// ---- wave-total via DPP (no DS ops) ----
template <int CTRL, int RMASK>
__device__ __forceinline__ float dpp_add_f(float x) {
    int m = __builtin_amdgcn_update_dpp(0, __builtin_bit_cast(int, x), CTRL, RMASK, 0xf, true);
    return x + __builtin_bit_cast(float, m);
}
__device__ __forceinline__ float wtotal64(float x) {
    x = dpp_add_f<0x111, 0xf>(x);
    x = dpp_add_f<0x112, 0xf>(x);
    x = dpp_add_f<0x114, 0xf>(x);
    x = dpp_add_f<0x118, 0xf>(x);
    x = dpp_add_f<0x142, 0xa>(x);
    x = dpp_add_f<0x143, 0xc>(x);
    return __builtin_bit_cast(float, __builtin_amdgcn_readlane(__builtin_bit_cast(int, x), 63));
}
template <int CTRL, int RMASK>
__device__ __forceinline__ int dpp_add_i(int x) {
    return x + __builtin_amdgcn_update_dpp(0, x, CTRL, RMASK, 0xf, true);
}
__device__ __forceinline__ int wtotal64_i(int x) {
    x = dpp_add_i<0x111, 0xf>(x);
    x = dpp_add_i<0x112, 0xf>(x);
    x = dpp_add_i<0x114, 0xf>(x);
    x = dpp_add_i<0x118, 0xf>(x);
    x = dpp_add_i<0x142, 0xa>(x);
    x = dpp_add_i<0x143, 0xc>(x);
    return __builtin_amdgcn_readlane(x, 63);
}

__device__ __forceinline__ float dot2f(half2_t a, half2_t b, float c) {
    return __builtin_amdgcn_fdot2(a, b, c, false);
}

__device__ __forceinline__ half2_t hmax2(half2_t a, half2_t b) {
#if defined(__has_builtin) && __has_builtin(__builtin_elementwise_max)
    return __builtin_elementwise_max(a, b);
#else
    half2_t r;
    r.x = a.x > b.x ? a.x : b.x;
    r.y = a.y > b.y ? a.y : b.y;
    return r;
#endif
}

// 8 x ds_read_b128 + 32 x v_dot2 with 4 independent accumulator chains
__device__ __forceinline__ float matvec_f16(const _Float16* __restrict__ buf,
                                            const half2_t* __restrict__ wh, float acc) {
    const float4* hp4 = (const float4*)buf;
    float a0 = acc, a1 = 0.0f, a2 = 0.0f, a3 = 0.0f;
#pragma unroll
    for (int j4 = 0; j4 < 8; ++j4) {
        float4 t = hp4[j4];
        a0 = dot2f(wh[4 * j4 + 0], __builtin_bit_cast(half2_t, t.x), a0);
        a1 = dot2f(wh[4 * j4 + 1], __builtin_bit_cast(half2_t, t.y), a1);
        a2 = dot2f(wh[4 * j4 + 2], __builtin_bit_cast(half2_t, t.z), a2);
        a3 = dot2f(wh[4 * j4 + 3], __builtin_bit_cast(half2_t, t.w), a3);
    }
    return (a0 + a1) + (a2 + a3);
}

__device__ __forceinline__ void load_w_f16(const float* __restrict__ W, int stride,
                                           int lane, half2_t* wh) {
#pragma unroll
    for (int j4 = 0; j4 < 16; ++j4) {
        float4 t = *(const float4*)(W + (size_t)lane * stride + j4 * 4);
        wh[2 * j4 + 0] = half2_t{(_Float16)t.x, (_Float16)t.y};
        wh[2 * j4 + 1] = half2_t{(_Float16)t.z, (_Float16)t.w};
    }
}

// ---------------- CSR build ----------------

// LDS-chunked histogram, NO global atomics (round-2: 3.2M device atomicAdds
// = ~31B memory-side partial-sector writes each; 99.7 MB WRITE, 129 us).
__global__ __launch_bounds__(256) void hist_part_kernel(
        const int* __restrict__ ci, const int* __restrict__ vi,
        int* __restrict__ partC, int* __restrict__ partV, int E) {
    __shared__ int lh[HCHUNK];
    const int seg  = blockIdx.x % HSEG;
    const int cg   = blockIdx.x / HSEG;
    const bool isC = cg < HCHC;
    const int chunk = isC ? cg : cg - HCHC;
    const int base  = chunk * HCHUNK;
    const int* __restrict__ dst = isC ? ci : vi;
    int* __restrict__ part = (isC ? partC : partV) + (size_t)(chunk * HSEG + seg) * HCHUNK;

    int4* l4 = (int4*)lh;
    for (int i = threadIdx.x; i < HCHUNK / 4; i += 256) l4[i] = make_int4(0, 0, 0, 0);
    __syncthreads();

    const int s0 = (int)((long long)seg * E / HSEG);
    const int s1 = (int)((long long)(seg + 1) * E / HSEG);
    for (int i = s0 + threadIdx.x; i < s1; i += 256) {
        const unsigned rel = (unsigned)(dst[i] - base);
        if (rel < (unsigned)HCHUNK) atomicAdd(&lh[rel], 1);
    }
    __syncthreads();
    int4* p4 = (int4*)part;
    for (int i = threadIdx.x; i < HCHUNK / 4; i += 256) p4[i] = l4[i];
}

// sum the HSEG segment-partials per counter -> degC/degV (coalesced reads)
__global__ __launch_bounds__(256) void hist_reduce_kernel(
        const int* __restrict__ partC, const int* __restrict__ partV,
        int* __restrict__ degC, int* __restrict__ degV) {
    int j = blockIdx.x * blockDim.x + threadIdx.x;
    const int tot = NCON + NVAR;
    for (; j < tot; j += gridDim.x * blockDim.x) {
        if (j < NCON) {
            const int chunk = j / HCHUNK, off = j - chunk * HCHUNK;
            const int* p = partC + (size_t)chunk * HSEG * HCHUNK + off;
            int s = 0;
#pragma unroll
            for (int t = 0; t < HSEG; ++t) s += p[(size_t)t * HCHUNK];
            degC[j] = s;
        } else {
            const int jj = j - NCON;
            const int chunk = jj / HCHUNK, off = jj - chunk * HCHUNK;
            const int* p = partV + (size_t)chunk * HSEG * HCHUNK + off;
            int s = 0;
#pragma unroll
            for (int t = 0; t < HSEG; ++t) s += p[(size_t)t * HCHUNK];
            degV[jj] = s;
        }
    }
}

// fallback: atomic histogram (used only if ws can't fit the partials)
__global__ __launch_bounds__(256) void hist2_kernel(
        const int* __restrict__ ci, const int* __restrict__ vi,
        int* __restrict__ degC, int* __restrict__ degV, int E) {
    int i = blockIdx.x * blockDim.x + threadIdx.x;
    for (; i < E; i += gridDim.x * blockDim.x) {
        atomicAdd(&degC[ci[i]], 1);
        atomicAdd(&degV[vi[i]], 1);
    }
}

template <bool PAD>
__global__ __launch_bounds__(256) void chunk_sum_kernel(const int* __restrict__ hist,
                                                        int* __restrict__ csum, int N) {
    __shared__ int wpart[4];
    const int base = blockIdx.x * 1024 + threadIdx.x * 4;
    int s = 0;
    if (base + 3 < N) {
        int4 t = *(const int4*)(hist + base);
        if (PAD) s = ((t.x+15)&~15) + ((t.y+15)&~15) + ((t.z+15)&~15) + ((t.w+15)&~15);
        else     s = t.x + t.y + t.z + t.w;
    } else {
#pragma unroll
        for (int j = 0; j < 4; ++j)
            if (base + j < N) { int v = hist[base + j]; s += PAD ? ((v+15)&~15) : v; }
    }
    s = wtotal64_i(s);
    if ((threadIdx.x & 63) == 0) wpart[threadIdx.x >> 6] = s;
    __syncthreads();
    if (threadIdx.x == 0) csum[blockIdx.x] = wpart[0] + wpart[1] + wpart[2] + wpart[3];
}

__global__ void chunk_offsets_kernel(const int* __restrict__ csum, int* __restrict__ coff,
                                     int* __restrict__ rowptr, int nchunk, int N) {
    const int lane = threadIdx.x;
    int carry = 0;
    for (int base = 0; base < nchunk; base += 64) {
        const int i = base + lane;
        int val = (i < nchunk) ? csum[i] : 0;
        int incl = val;
#pragma unroll
        for (int off = 1; off < 64; off <<= 1) {
            int t = __shfl_up(incl, off, 64);
            if (lane >= off) incl += t;
        }
        if (i < nchunk) coff[i] = incl - val + carry;
        carry += __shfl(incl, 63, 64);
    }
    if (lane == 0) rowptr[N] = carry;
}

template <bool PAD>
__global__ __launch_bounds__(256) void chunk_apply_kernel(
        const int* __restrict__ hist, const int* __restrict__ coff,
        int* __restrict__ rowptr, int* __restrict__ cursor, int N) {
    __shared__ int wpart[4];
    const int wv = threadIdx.x >> 6;
    const int lane = threadIdx.x & 63;
    const int base = blockIdx.x * 1024 + threadIdx.x * 4;
    int v0 = 0, v1 = 0, v2 = 0, v3 = 0;
    if (base + 3 < N) {
        int4 t = *(const int4*)(hist + base);
        v0 = t.x; v1 = t.y; v2 = t.z; v3 = t.w;
    } else {
        if (base + 0 < N) v0 = hist[base + 0];
        if (base + 1 < N) v1 = hist[base + 1];
        if (base + 2 < N) v2 = hist[base + 2];
        if (base + 3 < N) v3 = hist[base + 3];
    }
    if (PAD) { v0 = (v0+15)&~15; v1 = (v1+15)&~15; v2 = (v2+15)&~15; v3 = (v3+15)&~15; }
    const int s = v0 + v1 + v2 + v3;
    int incl = s;
#pragma unroll
    for (int off = 1; off < 64; off <<= 1) {
        int t = __shfl_up(incl, off, 64);
        if (lane >= off) incl += t;
    }
    if (lane == 63) wpart[wv] = incl;
    __syncthreads();
    int excl = coff[blockIdx.x] + incl - s;
    for (int w = 0; w < wv; ++w) excl += wpart[w];
    if (base + 0 < N) { rowptr[base + 0] = excl; cursor[base + 0] = excl; excl += v0; }
    if (base + 1 < N) { rowptr[base + 1] = excl; cursor[base + 1] = excl; excl += v1; }
    if (base + 2 < N) { rowptr[base + 2] = excl; cursor[base + 2] = excl; excl += v2; }
    if (base + 3 < N) { rowptr[base + 3] = excl; cursor[base + 3] = excl; excl += v3; }
}

// XCD-bucketed scatter, ONE direction per launch (round-2 verified: each
// XCD's L2 holds one bucket's CSR region -> write combining).
template <int NDST>
__global__ __launch_bounds__(256) void scatter_dir_kernel(
        const int* __restrict__ dst, const int* __restrict__ src,
        const float* __restrict__ ef,
        int* __restrict__ cur, int2* __restrict__ ep, int E) {
    const int rep = blockIdx.x & 7;
    const int stride = (gridDim.x >> 3) * blockDim.x;
    int i = (blockIdx.x >> 3) * blockDim.x + threadIdx.x;
    for (; i < E; i += stride) {
        const int d = dst[i];
        const int b = (int)(((long long)d * 8) / NDST);
        if (b == rep) {
            const int slot = atomicAdd(&cur[d], 1);
            ep[slot] = make_int2(src[i], __float_as_int(ef[i]));
        }
    }
}

// ---------------- fused node linear: RL segment + LL segment -> f16 ----------------

__global__ __launch_bounds__(256, 4) void lin2_kernel(
        const float* __restrict__ XR, const float* __restrict__ WR,
        const float* __restrict__ bR, _Float16* __restrict__ YR, int NR,
        const float* __restrict__ XL, const float* __restrict__ WL,
        _Float16* __restrict__ YL, int NL, int nbR) {
    __shared__ __align__(16) _Float16 xbuf[4][EMB];
    const int wv = threadIdx.x >> 6;
    const int lane = threadIdx.x & 63;
    const bool isR = (int)blockIdx.x < nbR;
    const float* X = isR ? XR : XL;
    _Float16* Y    = isR ? YR : YL;
    const int N    = isR ? NR : NL;
    const int b0   = isR ? 0 : nbR;
    const int nb   = isR ? nbR : (gridDim.x - nbR);
    half2_t wh[32];
    load_w_f16(isR ? WR : WL, EMB, lane, wh);
    const float bias = isR ? bR[lane] : 0.0f;
    const int nW = nb * 4;
    for (int n = ((int)blockIdx.x - b0) * 4 + wv; n < N; n += nW) {
        xbuf[wv][lane] = (_Float16)X[(size_t)n * EMB + lane];
        Y[(size_t)n * EMB + lane] = (_Float16)matvec_f16(xbuf[wv], wh, bias);
    }
}

// ---------------- edge stage: wave per node, abar accumulate ----------------
// Key identity: sum_e relu(LN(h_e)) @ Wf^T = (sum_e relu(LN(h_e))) @ Wf^T.
// Round-6 lesson: compiler VGPR budget behaves as ~256/(waves-per-SIMD arg):
// (256,3)->85 (68 used, clean), (256,4)->64 (spilled 68-reg kernel),
// (256,6)->40 (1.2 GB spill traffic). The kernel naturally needs ~68 regs, 32
// of which are whF for the per-node Wf matvec. Fix: move that matvec to
// out_kernel (which already reads this row) -> real footprint < 64 -> fits the
// (256,4) budget spill-free. This kernel now writes ABAR (f16) only.

__global__ __launch_bounds__(256, 4) void edge_abar_kernel(
        const int* __restrict__ rp16, const int* __restrict__ deg,
        const int2* __restrict__ ep,
        const _Float16* __restrict__ RL, const _Float16* __restrict__ LL,
        const float* __restrict__ We, const float* __restrict__ g1,
        const float* __restrict__ b1, _Float16* __restrict__ ABAR, int Nr) {
    __shared__ __align__(16) float tbuf[4][16][68];   // [wave][col][k] padded stride
    const int wv   = threadIdx.x >> 6;
    const int lane = threadIdx.x & 63;
    const int col  = lane & 15;
    const int quad = lane >> 4;
    const int kb   = quad * 8;

    half2_t weh[8], gkh[8], bkh[8];
#pragma unroll
    for (int j = 0; j < 4; ++j) {
        weh[j]     = half2_t{(_Float16)We[kb + 2*j],      (_Float16)We[kb + 2*j + 1]};
        weh[4 + j] = half2_t{(_Float16)We[kb + 32 + 2*j], (_Float16)We[kb + 32 + 2*j + 1]};
        gkh[j]     = half2_t{(_Float16)g1[kb + 2*j],      (_Float16)g1[kb + 2*j + 1]};
        gkh[4 + j] = half2_t{(_Float16)g1[kb + 32 + 2*j], (_Float16)g1[kb + 32 + 2*j + 1]};
        bkh[j]     = half2_t{(_Float16)b1[kb + 2*j],      (_Float16)b1[kb + 2*j + 1]};
        bkh[4 + j] = half2_t{(_Float16)b1[kb + 32 + 2*j], (_Float16)b1[kb + 32 + 2*j + 1]};
    }

    const int nW = gridDim.x * 4;
    int n = blockIdx.x * 4 + wv;          // Nr >= 50000 > grid*4, so n < Nr here
    int pg0 = rp16[n] >> 4;
    int pg1 = rp16[n + 1] >> 4;
    int pdn = deg[n];

    bool livN = false; float fN = 0.0f;
    f16x8 llaN = {}, llbN = {};
    auto issue_group = [&](int gbase, int cnt) {
        livN = col < cnt;
        int2 p = ep[(gbase << 4) + col];
        const int s2 = livN ? p.x : 0;
        fN = livN ? __int_as_float(p.y) : 0.0f;
        llaN = *(const f16x8*)(LL + (size_t)s2 * EMB + kb);
        llbN = *(const f16x8*)(LL + (size_t)s2 * EMB + kb + 32);
    };
    if (pg0 < pg1) issue_group(pg0, pdn);     // prime first node's first group

    while (true) {
        const int g0 = pg0, g1e = pg1, dn = pdn;
        const int nn = n + nW;
        const bool hasNext = nn < Nr;
        if (hasNext) {                         // issue next node's meta EARLY
            pg0 = rp16[nn] >> 4;
            pg1 = rp16[nn + 1] >> 4;
            pdn = deg[nn];
        }

        half2_t rl2[8];
        *(f16x8*)&rl2[0] = *(const f16x8*)(RL + (size_t)n * EMB + kb);
        *(f16x8*)&rl2[4] = *(const f16x8*)(RL + (size_t)n * EMB + kb + 32);

        f32x2 acc2[8];
#pragma unroll
        for (int j = 0; j < 8; ++j) acc2[j] = f32x2{0.0f, 0.0f};

        bool didNext = false;
        for (int g = g0; g < g1e; ++g) {
            const bool liv = livN;
            const float f = fN;
            half2_t h2[8];
            *(f16x8*)&h2[0] = llaN;
            *(f16x8*)&h2[4] = llbN;
            if (g + 1 < g1e) {
                issue_group(g + 1, dn - ((g + 1 - g0) << 4));   // in-node prefetch
            } else if (hasNext && pg0 < pg1) {
                issue_group(pg0, pdn);                           // next-node prefetch
                didNext = true;
            }
            const _Float16 fh = (_Float16)f;
            const half2_t f2 = half2_t{fh, fh};
            const half2_t one2 = half2_t{(_Float16)1.0f, (_Float16)1.0f};
            float ps = 0.0f, pq = 0.0f;
#pragma unroll
            for (int j = 0; j < 8; ++j) {
                h2[j] = (h2[j] + rl2[j]) + f2 * weh[j];
                ps = dot2f(h2[j], one2, ps);
                pq = dot2f(h2[j], h2[j], pq);
            }
            ps += __shfl_xor(ps, 16, 64); ps += __shfl_xor(ps, 32, 64);
            pq += __shfl_xor(pq, 16, 64); pq += __shfl_xor(pq, 32, 64);
            const float mean = ps * (1.0f / EMB);
            const float var  = pq * (1.0f / EMB) - mean * mean;
            const float rs   = rsqrtf(var + EPSLN);
            const _Float16 rsh = (_Float16)rs;
            const _Float16 mnh = (_Float16)mean;
            const half2_t rs2 = half2_t{rsh, rsh};
            const half2_t mn2 = half2_t{mnh, mnh};
            const half2_t z2  = half2_t{(_Float16)0.0f, (_Float16)0.0f};
            if (liv) {
#pragma unroll
                for (int j = 0; j < 8; ++j) {
                    const half2_t sc = gkh[j] * rs2;
                    half2_t a = (h2[j] - mn2) * sc + bkh[j];
                    a = hmax2(a, z2);
                    f32x2 cv; cv.x = (float)a.x; cv.y = (float)a.y;
                    acc2[j] += cv;
                }
            }
        }

        // ---- LDS-transpose reduce: acc2[j] of lane (col,quad) covers
        //      k = kb..kb+7 (acc2[0..3]) and kb+32..kb+39 (acc2[4..7]) ----
        float* tb = &tbuf[wv][col][0];
        *(float4*)(tb + kb)      = make_float4(acc2[0].x, acc2[0].y, acc2[1].x, acc2[1].y);
        *(float4*)(tb + kb + 4)  = make_float4(acc2[2].x, acc2[2].y, acc2[3].x, acc2[3].y);
        *(float4*)(tb + kb + 32) = make_float4(acc2[4].x, acc2[4].y, acc2[5].x, acc2[5].y);
        *(float4*)(tb + kb + 36) = make_float4(acc2[6].x, acc2[6].y, acc2[7].x, acc2[7].y);
        // tree-sum 16 statically-indexed column reads (short dep chain)
        float t0[16];
#pragma unroll
        for (int c2 = 0; c2 < 16; ++c2) t0[c2] = tbuf[wv][c2][lane];
        const float s01 = (t0[0] + t0[1]) + (t0[2] + t0[3]);
        const float s23 = (t0[4] + t0[5]) + (t0[6] + t0[7]);
        const float s45 = (t0[8] + t0[9]) + (t0[10] + t0[11]);
        const float s67 = (t0[12] + t0[13]) + (t0[14] + t0[15]);
        ABAR[(size_t)n * EMB + lane] = (_Float16)((s01 + s23) + (s45 + s67));

        if (!hasNext) break;
        if (!didNext && pg0 < pg1) issue_group(pg0, pdn);   // zero-group edge cases
        n = nn;
    }
}

// ---------------- fallback edge path (wave per node, abar accumulate) ----------------

__global__ __launch_bounds__(256, 4) void edge_csr_kernel(
        const int* __restrict__ rowptr, const int2* __restrict__ ep,
        const _Float16* __restrict__ RL, const _Float16* __restrict__ LL,
        const float* __restrict__ Wecol, const float* __restrict__ g1,
        const float* __restrict__ b1,
        _Float16* __restrict__ ABAR, int Nr) {
    const int wv = threadIdx.x >> 6;
    (void)wv;
    const int lane = threadIdx.x & 63;
    const float we  = Wecol[lane];
    const float g   = g1[lane];
    const float bb  = b1[lane];
    const int nW = gridDim.x * 4;
    for (int n = blockIdx.x * 4 + (threadIdx.x >> 6); n < Nr; n += nW) {
        const int beg = rowptr[n];
        const int end = rowptr[n + 1];
        const float rl = (float)RL[(size_t)n * EMB + lane];
        float acc = 0.0f;
        for (int idx = beg; idx < end; ++idx) {
            const int2 p = ep[idx];
            const float f = __int_as_float(p.y);
            float h = rl + (float)LL[(size_t)p.x * EMB + lane] + f * we;
            const float s1 = wtotal64(h);
            const float s2 = wtotal64(h * h);
            const float m   = s1 * (1.0f / EMB);
            const float var = s2 * (1.0f / EMB) - m * m;
            acc += fmaxf((h - m) * rsqrtf(var + EPSLN) * g + bb, 0.0f);
        }
        ABAR[(size_t)n * EMB + lane] = (_Float16)acc;
    }
}

// ---------------- fused output MLP (now also applies Wf) ----------------
// agg = abar @ Wf^T + deg*bf; z = LN(agg);
// o = relu(Wo1a@z + Wo1b@right + bo1); right += Wo2@o + bo2
// (256,1): weight regs alone are ~160 (whF+wh1+whB+wh2); any tighter cap
// spills (round-6 model: budget ~ 256/arg).

__global__ __launch_bounds__(256, 1) void out_kernel(
        const _Float16* __restrict__ ABAR, const int* __restrict__ deg,
        float* __restrict__ right,
        const float* __restrict__ g2, const float* __restrict__ b2,
        const float* __restrict__ Wf, const float* __restrict__ bfp,
        const float* __restrict__ Wo1, const float* __restrict__ Wo2,
        const float* __restrict__ bo1, const float* __restrict__ bo2, int N) {
    __shared__ __align__(16) _Float16 abuf[4][EMB];
    __shared__ __align__(16) _Float16 zbuf[4][EMB];
    __shared__ __align__(16) _Float16 rbuf[4][EMB];
    __shared__ __align__(16) _Float16 obuf[4][EMB];
    const int wv = threadIdx.x >> 6;
    const int lane = threadIdx.x & 63;
    half2_t whF[32], wh1[32], whB[32], wh2[32];
    load_w_f16(Wf, EMB, lane, whF);
    load_w_f16(Wo1, 2 * EMB, lane, wh1);            // Wo1[:, 0:64]
    load_w_f16(Wo1 + EMB, 2 * EMB, lane, whB);      // Wo1[:, 64:128]
    load_w_f16(Wo2, EMB, lane, wh2);
    const float bfv  = bfp[lane];
    const float g    = g2[lane];
    const float bb   = b2[lane];
    const float bo1v = bo1[lane];
    const float bo2v = bo2[lane];
    const int nW = gridDim.x * 4;
    for (int n = blockIdx.x * 4 + wv; n < N; n += nW) {
        abuf[wv][lane] = ABAR[(size_t)n * EMB + lane];
        const int dn = deg[n];
        const float rf = right[(size_t)n * EMB + lane];
        // agg = abar @ Wf^T + deg*bf
        const float a = matvec_f16(abuf[wv], whF, (float)dn * bfv);
        const float s1 = wtotal64(a);
        const float s2 = wtotal64(a * a);
        const float m   = s1 * (1.0f / EMB);
        const float var = s2 * (1.0f / EMB) - m * m;
        const float z = (a - m) * rsqrtf(var + EPSLN) * g + bb;
        zbuf[wv][lane] = (_Float16)z;
        rbuf[wv][lane] = (_Float16)rf;
        float acc = matvec_f16(zbuf[wv], wh1, bo1v);
        acc = matvec_f16(rbuf[wv], whB, acc);
        obuf[wv][lane] = (_Float16)fmaxf(acc, 0.0f);
        float acc2 = matvec_f16(obuf[wv], wh2, bo2v);
        right[(size_t)n * EMB + lane] = rf + acc2;
    }
}

extern "C" void kernel_launch(void* const* d_in, const int* in_sizes, int n_in,
                              void* d_out, int out_size, void* d_ws, size_t ws_size,
                              hipStream_t stream) {
    const float* cf  = (const float*)d_in[0];
    const float* vfp = (const float*)d_in[1];
    const int*   ei  = (const int*)d_in[2];
    const float* ef  = (const float*)d_in[3];
    const float* Wl  = (const float*)d_in[4];
    const float* bl  = (const float*)d_in[5];
    const float* We  = (const float*)d_in[6];
    const float* Wr  = (const float*)d_in[7];
    const float* g1  = (const float*)d_in[8];
    const float* b1  = (const float*)d_in[9];
    const float* Wf  = (const float*)d_in[10];
    const float* bfp = (const float*)d_in[11];
    const float* g2  = (const float*)d_in[12];
    const float* b2  = (const float*)d_in[13];
    const float* Wo1 = (const float*)d_in[14];
    const float* bo1 = (const float*)d_in[15];
    const float* Wo2 = (const float*)d_in[16];
    const float* bo2 = (const float*)d_in[17];

    float* c = (float*)d_out;
    float* v = c + (size_t)NCON * EMB;
    (void)hipMemcpyAsync(c, cf,  (size_t)NCON * EMB * sizeof(float), hipMemcpyDeviceToDevice, stream);
    (void)hipMemcpyAsync(v, vfp, (size_t)NVAR * EMB * sizeof(float), hipMemcpyDeviceToDevice, stream);

    float* wsf = (float*)d_ws;
    size_t off = 0;
    _Float16* AGG = (_Float16*)(wsf + off); off += (size_t)NVAR * EMB / 2;  // f16 (abar)
    _Float16* RL  = (_Float16*)(wsf + off); off += (size_t)NVAR * EMB / 2;  // f16
    _Float16* LL  = (_Float16*)(wsf + off); off += (size_t)NVAR * EMB / 2;  // f16
    int* degC  = (int*)(wsf + off); off += NCON;
    int* degV  = (int*)(wsf + off); off += NVAR;
    int* rp16C = (int*)(wsf + off); off += NCON + 4;
    int* curC  = (int*)(wsf + off); off += NCON;
    int* rp16V = (int*)(wsf + off); off += NVAR + 4;
    int* curV  = (int*)(wsf + off); off += NVAR;
    int* csumC = (int*)(wsf + off); off += 128;
    int* coffC = (int*)(wsf + off); off += 128;
    int* csumV = (int*)(wsf + off); off += 128;
    int* coffV = (int*)(wsf + off); off += 128;
    size_t off_edges = off;
    int2* epC = (int2*)(wsf + off); off += (size_t)2 * PADEC;
    int2* epV = (int2*)(wsf + off); off += (size_t)2 * PADEV;
    const bool use_mfma = ws_size >= off * sizeof(float);
    // histogram partials (19.3 MB) after the edge arrays
    int* partC = (int*)(wsf + off); off += (size_t)HCHC * HSEG * HCHUNK;
    int* partV = (int*)(wsf + off); off += (size_t)HCHV * HSEG * HCHUNK;
    const bool use_ldshist = use_mfma && ws_size >= off * sizeof(float);
    if (!use_mfma) {
        off = off_edges;
        epC = (int2*)(wsf + off); off += (size_t)2 * NEDGE;
        epV = (int2*)(wsf + off); off += (size_t)2 * NEDGE;
    }

    const int* ci = ei;
    const int* vi = ei + NEDGE;

    const dim3 blk(256);
    const int NB = 2048;
    const int NBL = 1536;
    const int nchC = (NCON + 1023) / 1024;   // 49
    const int nchV = (NVAR + 1023) / 1024;   // 98

    if (use_ldshist) {
        hist_part_kernel<<<(HCHC + HCHV) * HSEG, blk, 0, stream>>>(ci, vi, partC, partV, NEDGE);
        hist_reduce_kernel<<<640, blk, 0, stream>>>(partC, partV, degC, degV);
    } else {
        (void)hipMemsetAsync(degC, 0, NCON * sizeof(int), stream);
        (void)hipMemsetAsync(degV, 0, NVAR * sizeof(int), stream);
        hist2_kernel<<<1024, blk, 0, stream>>>(ci, vi, degC, degV, NEDGE);
    }
    if (use_mfma) {
        chunk_sum_kernel<true><<<nchC, blk, 0, stream>>>(degC, csumC, NCON);
        chunk_sum_kernel<true><<<nchV, blk, 0, stream>>>(degV, csumV, NVAR);
        chunk_offsets_kernel<<<1, 64, 0, stream>>>(csumC, coffC, rp16C, nchC, NCON);
        chunk_offsets_kernel<<<1, 64, 0, stream>>>(csumV, coffV, rp16V, nchV, NVAR);
        chunk_apply_kernel<true><<<nchC, blk, 0, stream>>>(degC, coffC, rp16C, curC, NCON);
        chunk_apply_kernel<true><<<nchV, blk, 0, stream>>>(degV, coffV, rp16V, curV, NVAR);
    } else {
        chunk_sum_kernel<false><<<nchC, blk, 0, stream>>>(degC, csumC, NCON);
        chunk_sum_kernel<false><<<nchV, blk, 0, stream>>>(degV, csumV, NVAR);
        chunk_offsets_kernel<<<1, 64, 0, stream>>>(csumC, coffC, rp16C, nchC, NCON);
        chunk_offsets_kernel<<<1, 64, 0, stream>>>(csumV, coffV, rp16V, nchV, NVAR);
        chunk_apply_kernel<false><<<nchC, blk, 0, stream>>>(degC, coffC, rp16C, curC, NCON);
        chunk_apply_kernel<false><<<nchV, blk, 0, stream>>>(degV, coffV, rp16V, curV, NVAR);
    }
    // one direction per launch: hard temporal separation so each XCD's L2
    // holds only that direction's bucket region (C: 2.35 MB, V: 3.1 MB).
    scatter_dir_kernel<NCON><<<2048, blk, 0, stream>>>(ci, vi, ef, curC, epC, NEDGE);
    scatter_dir_kernel<NVAR><<<2048, blk, 0, stream>>>(vi, ci, ef, curV, epV, NEDGE);

    for (int k = 0; k < 4; ++k) {
        const bool v2c = ((k & 1) == 0);
        float* right   = v2c ? c : v;
        float* left    = v2c ? v : c;
        const int Nr   = v2c ? NCON : NVAR;
        const int Nl   = v2c ? NVAR : NCON;
        const int nbR  = v2c ? NBL / 3 : 2 * NBL / 3;   // split blocks ~ Nr : Nl
        const int* degR = v2c ? degC : degV;

        lin2_kernel<<<NBL, blk, 0, stream>>>(
            right, Wl + (size_t)k * EMB * EMB, bl + (size_t)k * EMB, RL, Nr,
            left,  Wr + (size_t)k * EMB * EMB, LL, Nl, nbR);

        if (use_mfma) {
            edge_abar_kernel<<<NB, blk, 0, stream>>>(
                v2c ? rp16C : rp16V, degR, v2c ? epC : epV,
                RL, LL, We + (size_t)k * EMB,
                g1 + (size_t)k * EMB, b1 + (size_t)k * EMB,
                AGG, Nr);
        } else {
            edge_csr_kernel<<<NB, blk, 0, stream>>>(
                v2c ? rp16C : rp16V, v2c ? epC : epV,
                RL, LL, We + (size_t)k * EMB,
                g1 + (size_t)k * EMB, b1 + (size_t)k * EMB,
                AGG, Nr);
        }
        out_kernel<<<NB, blk, 0, stream>>>(AGG, degR, right,
                                           g2 + (size_t)k * EMB, b2 + (size_t)k * EMB,
                                           Wf + (size_t)k * EMB * EMB,
                                           bfp + (size_t)k * EMB,
                                           Wo1 + (size_t)k * EMB * 2 * EMB,
                                           Wo2 + (size_t)k * EMB * EMB,
                                           bo1 + (size_t)k * EMB, bo2 + (size_t)k * EMB,
                                           Nr);
    }
}

// Round 8
// 1122.639 us; speedup vs baseline: 1.7965x; 1.0209x over previous
//
#include <hip/hip_runtime.h>

#define EMB   64
#define NCON  50000
#define NVAR  100000
#define NEDGE 1600000
#define EPSLN 1e-5f

// padded-CSR capacities (worst case: every node pads +15)
#define PADEC (NEDGE + 15 * NCON)    // 2,350,000
#define PADEV (NEDGE + 15 * NVAR)    // 3,100,000

// LDS-chunked histogram: 12544 counters/chunk (50 KB LDS), C=4 chunks, V=8.
#define HCHUNK 12544
#define HSEG   32
#define HCHC   4
#define HCHV   8

typedef _Float16 half2_t __attribute__((ext_vector_type(2)));
typedef _Float16 f16x8  __attribute__((ext_vector_type(8)));
typedef float    f32x2  __attribute__((ext_vector_type(2)));
typedef float    f32x4  __attribute__((ext_vector_type(4)));

// ---- wave-total via DPP (no DS ops) ----
template <int CTRL, int RMASK>
__device__ __forceinline__ float dpp_add_f(float x) {
    int m = __builtin_amdgcn_update_dpp(0, __builtin_bit_cast(int, x), CTRL, RMASK, 0xf, true);
    return x + __builtin_bit_cast(float, m);
}
__device__ __forceinline__ float wtotal64(float x) {
    x = dpp_add_f<0x111, 0xf>(x);
    x = dpp_add_f<0x112, 0xf>(x);
    x = dpp_add_f<0x114, 0xf>(x);
    x = dpp_add_f<0x118, 0xf>(x);
    x = dpp_add_f<0x142, 0xa>(x);
    x = dpp_add_f<0x143, 0xc>(x);
    return __builtin_bit_cast(float, __builtin_amdgcn_readlane(__builtin_bit_cast(int, x), 63));
}
template <int CTRL, int RMASK>
__device__ __forceinline__ int dpp_add_i(int x) {
    return x + __builtin_amdgcn_update_dpp(0, x, CTRL, RMASK, 0xf, true);
}
__device__ __forceinline__ int wtotal64_i(int x) {
    x = dpp_add_i<0x111, 0xf>(x);
    x = dpp_add_i<0x112, 0xf>(x);
    x = dpp_add_i<0x114, 0xf>(x);
    x = dpp_add_i<0x118, 0xf>(x);
    x = dpp_add_i<0x142, 0xa>(x);
    x = dpp_add_i<0x143, 0xc>(x);
    return __builtin_amdgcn_readlane(x, 63);
}

__device__ __forceinline__ float dot2f(half2_t a, half2_t b, float c) {
    return __builtin_amdgcn_fdot2(a, b, c, false);
}

__device__ __forceinline__ half2_t hmax2(half2_t a, half2_t b) {
#if defined(__has_builtin) && __has_builtin(__builtin_elementwise_max)
    return __builtin_elementwise_max(a, b);
#else
    half2_t r;
    r.x = a.x > b.x ? a.x : b.x;
    r.y = a.y > b.y ? a.y : b.y;
    return r;
#endif
}

// 8 x ds_read_b128 + 32 x v_dot2 with 4 independent accumulator chains
__device__ __forceinline__ float matvec_f16(const _Float16* __restrict__ buf,
                                            const half2_t* __restrict__ wh, float acc) {
    const float4* hp4 = (const float4*)buf;
    float a0 = acc, a1 = 0.0f, a2 = 0.0f, a3 = 0.0f;
#pragma unroll
    for (int j4 = 0; j4 < 8; ++j4) {
        float4 t = hp4[j4];
        a0 = dot2f(wh[4 * j4 + 0], __builtin_bit_cast(half2_t, t.x), a0);
        a1 = dot2f(wh[4 * j4 + 1], __builtin_bit_cast(half2_t, t.y), a1);
        a2 = dot2f(wh[4 * j4 + 2], __builtin_bit_cast(half2_t, t.z), a2);
        a3 = dot2f(wh[4 * j4 + 3], __builtin_bit_cast(half2_t, t.w), a3);
    }
    return (a0 + a1) + (a2 + a3);
}

__device__ __forceinline__ void load_w_f16(const float* __restrict__ W, int stride,
                                           int lane, half2_t* wh) {
#pragma unroll
    for (int j4 = 0; j4 < 16; ++j4) {
        float4 t = *(const float4*)(W + (size_t)lane * stride + j4 * 4);
        wh[2 * j4 + 0] = half2_t{(_Float16)t.x, (_Float16)t.y};
        wh[2 * j4 + 1] = half2_t{(_Float16)t.z, (_Float16)t.w};
    }
}

__device__ __forceinline__ f16x8 cvt8_f16(float4 u, float4 v) {
    f16x8 r;
    r[0] = (_Float16)u.x; r[1] = (_Float16)u.y; r[2] = (_Float16)u.z; r[3] = (_Float16)u.w;
    r[4] = (_Float16)v.x; r[5] = (_Float16)v.y; r[6] = (_Float16)v.z; r[7] = (_Float16)v.w;
    return r;
}

// ---------------- CSR build ----------------

// LDS-chunked histogram, NO global atomics (round-2: 3.2M device atomicAdds
// = ~31B memory-side partial-sector writes each; 99.7 MB WRITE, 129 us).
__global__ __launch_bounds__(256) void hist_part_kernel(
        const int* __restrict__ ci, const int* __restrict__ vi,
        int* __restrict__ partC, int* __restrict__ partV, int E) {
    __shared__ int lh[HCHUNK];
    const int seg  = blockIdx.x % HSEG;
    const int cg   = blockIdx.x / HSEG;
    const bool isC = cg < HCHC;
    const int chunk = isC ? cg : cg - HCHC;
    const int base  = chunk * HCHUNK;
    const int* __restrict__ dst = isC ? ci : vi;
    int* __restrict__ part = (isC ? partC : partV) + (size_t)(chunk * HSEG + seg) * HCHUNK;

    int4* l4 = (int4*)lh;
    for (int i = threadIdx.x; i < HCHUNK / 4; i += 256) l4[i] = make_int4(0, 0, 0, 0);
    __syncthreads();

    const int s0 = (int)((long long)seg * E / HSEG);
    const int s1 = (int)((long long)(seg + 1) * E / HSEG);
    for (int i = s0 + threadIdx.x; i < s1; i += 256) {
        const unsigned rel = (unsigned)(dst[i] - base);
        if (rel < (unsigned)HCHUNK) atomicAdd(&lh[rel], 1);
    }
    __syncthreads();
    int4* p4 = (int4*)part;
    for (int i = threadIdx.x; i < HCHUNK / 4; i += 256) p4[i] = l4[i];
}

// sum the HSEG segment-partials per counter -> degC/degV (coalesced reads)
__global__ __launch_bounds__(256) void hist_reduce_kernel(
        const int* __restrict__ partC, const int* __restrict__ partV,
        int* __restrict__ degC, int* __restrict__ degV) {
    int j = blockIdx.x * blockDim.x + threadIdx.x;
    const int tot = NCON + NVAR;
    for (; j < tot; j += gridDim.x * blockDim.x) {
        if (j < NCON) {
            const int chunk = j / HCHUNK, off = j - chunk * HCHUNK;
            const int* p = partC + (size_t)chunk * HSEG * HCHUNK + off;
            int s = 0;
#pragma unroll
            for (int t = 0; t < HSEG; ++t) s += p[(size_t)t * HCHUNK];
            degC[j] = s;
        } else {
            const int jj = j - NCON;
            const int chunk = jj / HCHUNK, off = jj - chunk * HCHUNK;
            const int* p = partV + (size_t)chunk * HSEG * HCHUNK + off;
            int s = 0;
#pragma unroll
            for (int t = 0; t < HSEG; ++t) s += p[(size_t)t * HCHUNK];
            degV[jj] = s;
        }
    }
}

// fallback: atomic histogram (used only if ws can't fit the partials)
__global__ __launch_bounds__(256) void hist2_kernel(
        const int* __restrict__ ci, const int* __restrict__ vi,
        int* __restrict__ degC, int* __restrict__ degV, int E) {
    int i = blockIdx.x * blockDim.x + threadIdx.x;
    for (; i < E; i += gridDim.x * blockDim.x) {
        atomicAdd(&degC[ci[i]], 1);
        atomicAdd(&degV[vi[i]], 1);
    }
}

template <bool PAD>
__global__ __launch_bounds__(256) void chunk_sum_kernel(const int* __restrict__ hist,
                                                        int* __restrict__ csum, int N) {
    __shared__ int wpart[4];
    const int base = blockIdx.x * 1024 + threadIdx.x * 4;
    int s = 0;
    if (base + 3 < N) {
        int4 t = *(const int4*)(hist + base);
        if (PAD) s = ((t.x+15)&~15) + ((t.y+15)&~15) + ((t.z+15)&~15) + ((t.w+15)&~15);
        else     s = t.x + t.y + t.z + t.w;
    } else {
#pragma unroll
        for (int j = 0; j < 4; ++j)
            if (base + j < N) { int v = hist[base + j]; s += PAD ? ((v+15)&~15) : v; }
    }
    s = wtotal64_i(s);
    if ((threadIdx.x & 63) == 0) wpart[threadIdx.x >> 6] = s;
    __syncthreads();
    if (threadIdx.x == 0) csum[blockIdx.x] = wpart[0] + wpart[1] + wpart[2] + wpart[3];
}

__global__ void chunk_offsets_kernel(const int* __restrict__ csum, int* __restrict__ coff,
                                     int* __restrict__ rowptr, int nchunk, int N) {
    const int lane = threadIdx.x;
    int carry = 0;
    for (int base = 0; base < nchunk; base += 64) {
        const int i = base + lane;
        int val = (i < nchunk) ? csum[i] : 0;
        int incl = val;
#pragma unroll
        for (int off = 1; off < 64; off <<= 1) {
            int t = __shfl_up(incl, off, 64);
            if (lane >= off) incl += t;
        }
        if (i < nchunk) coff[i] = incl - val + carry;
        carry += __shfl(incl, 63, 64);
    }
    if (lane == 0) rowptr[N] = carry;
}

template <bool PAD>
__global__ __launch_bounds__(256) void chunk_apply_kernel(
        const int* __restrict__ hist, const int* __restrict__ coff,
        int* __restrict__ rowptr, int* __restrict__ cursor, int N) {
    __shared__ int wpart[4];
    const int wv = threadIdx.x >> 6;
    const int lane = threadIdx.x & 63;
    const int base = blockIdx.x * 1024 + threadIdx.x * 4;
    int v0 = 0, v1 = 0, v2 = 0, v3 = 0;
    if (base + 3 < N) {
        int4 t = *(const int4*)(hist + base);
        v0 = t.x; v1 = t.y; v2 = t.z; v3 = t.w;
    } else {
        if (base + 0 < N) v0 = hist[base + 0];
        if (base + 1 < N) v1 = hist[base + 1];
        if (base + 2 < N) v2 = hist[base + 2];
        if (base + 3 < N) v3 = hist[base + 3];
    }
    if (PAD) { v0 = (v0+15)&~15; v1 = (v1+15)&~15; v2 = (v2+15)&~15; v3 = (v3+15)&~15; }
    const int s = v0 + v1 + v2 + v3;
    int incl = s;
#pragma unroll
    for (int off = 1; off < 64; off <<= 1) {
        int t = __shfl_up(incl, off, 64);
        if (lane >= off) incl += t;
    }
    if (lane == 63) wpart[wv] = incl;
    __syncthreads();
    int excl = coff[blockIdx.x] + incl - s;
    for (int w = 0; w < wv; ++w) excl += wpart[w];
    if (base + 0 < N) { rowptr[base + 0] = excl; cursor[base + 0] = excl; excl += v0; }
    if (base + 1 < N) { rowptr[base + 1] = excl; cursor[base + 1] = excl; excl += v1; }
    if (base + 2 < N) { rowptr[base + 2] = excl; cursor[base + 2] = excl; excl += v2; }
    if (base + 3 < N) { rowptr[base + 3] = excl; cursor[base + 3] = excl; excl += v3; }
}

// XCD-bucketed scatter, ONE direction per launch (round-2 verified: each
// XCD's L2 holds one bucket's CSR region -> write combining).
template <int NDST>
__global__ __launch_bounds__(256) void scatter_dir_kernel(
        const int* __restrict__ dst, const int* __restrict__ src,
        const float* __restrict__ ef,
        int* __restrict__ cur, int2* __restrict__ ep, int E) {
    const int rep = blockIdx.x & 7;
    const int stride = (gridDim.x >> 3) * blockDim.x;
    int i = (blockIdx.x >> 3) * blockDim.x + threadIdx.x;
    for (; i < E; i += stride) {
        const int d = dst[i];
        const int b = (int)(((long long)d * 8) / NDST);
        if (b == rep) {
            const int slot = atomicAdd(&cur[d], 1);
            ep[slot] = make_int2(src[i], __float_as_int(ef[i]));
        }
    }
}

// ---------------- fused node linear via MFMA: Y = X @ W^T (+b) -> f16 ----------------
// Round-8: first MFMA kernel (MfmaUtil was 0 session-wide while every hot
// kernel is [N x 64] @ [64 x 64] shaped). One 16-node tile per wave:
//   A-frag  (16x32/step): lane l holds X[n0+(l&15)][kc*32+(l>>4)*8+j]
//   B-frag:               lane l holds W[ct*16+(l&15)][kc*32+(l>>4)*8+j]  (=W^T[k][o])
//   D (m89-verified):     lane l, reg r -> row (l>>4)*4+r, col l&15
// 8 MFMA replace ~16x40 dot2 chain insts. Also the layout-validation probe
// for migrating out_kernel (current top, latency-bound dot2 chains) to MFMA.

__global__ __launch_bounds__(256, 3) void lin2_kernel(
        const float* __restrict__ XR, const float* __restrict__ WR,
        const float* __restrict__ bR, _Float16* __restrict__ YR, int NR,
        const float* __restrict__ XL, const float* __restrict__ WL,
        _Float16* __restrict__ YL, int NL, int nbR) {
    const int wv   = threadIdx.x >> 6;
    const int lane = threadIdx.x & 63;
    const int col  = lane & 15;
    const int kgrp = lane >> 4;           // 0..3
    const bool isR = (int)blockIdx.x < nbR;
    const float* X = isR ? XR : XL;
    const float* W = isR ? WR : WL;
    _Float16* Y    = isR ? YR : YL;
    const int N    = isR ? NR : NL;
    const int b0   = isR ? 0 : nbR;
    const int nb   = isR ? nbR : (gridDim.x - nbR);

    f16x8 bf[4][2];
#pragma unroll
    for (int ct = 0; ct < 4; ++ct)
#pragma unroll
        for (int kc = 0; kc < 2; ++kc) {
            const float* wrow = W + (size_t)(ct * 16 + col) * EMB + kc * 32 + kgrp * 8;
            bf[ct][kc] = cvt8_f16(*(const float4*)wrow, *(const float4*)(wrow + 4));
        }
    float bias[4];
#pragma unroll
    for (int ct = 0; ct < 4; ++ct) bias[ct] = isR ? bR[ct * 16 + col] : 0.0f;

    const int ntile = (N + 15) >> 4;
    const int nW = nb * 4;
    for (int t = ((int)blockIdx.x - b0) * 4 + wv; t < ntile; t += nW) {
        const int n0 = t << 4;
        const int srow = min(n0 + col, N - 1);
        const float* xrow = X + (size_t)srow * EMB + kgrp * 8;
        const float4 x0 = *(const float4*)(xrow);
        const float4 x1 = *(const float4*)(xrow + 4);
        const float4 x2 = *(const float4*)(xrow + 32);
        const float4 x3 = *(const float4*)(xrow + 36);
        const f16x8 a0 = cvt8_f16(x0, x1);
        const f16x8 a1 = cvt8_f16(x2, x3);
        f32x4 acc[4];
#pragma unroll
        for (int ct = 0; ct < 4; ++ct) {
            acc[ct] = __builtin_amdgcn_mfma_f32_16x16x32_f16(
                a0, bf[ct][0], (f32x4){0.0f, 0.0f, 0.0f, 0.0f}, 0, 0, 0);
            acc[ct] = __builtin_amdgcn_mfma_f32_16x16x32_f16(
                a1, bf[ct][1], acc[ct], 0, 0, 0);
        }
#pragma unroll
        for (int r = 0; r < 4; ++r) {
            const int n = n0 + (kgrp << 2) + r;
            if (n < N) {
                _Float16* yrow = Y + (size_t)n * EMB + col;
#pragma unroll
                for (int ct = 0; ct < 4; ++ct)
                    yrow[ct * 16] = (_Float16)(acc[ct][r] + bias[ct]);
            }
        }
    }
}

// ---------------- edge stage: wave per node, abar accumulate ----------------
// Key identity: sum_e relu(LN(h_e)) @ Wf^T = (sum_e relu(LN(h_e))) @ Wf^T.
// Round-6 lesson: compiler VGPR budget ~256/(launch-bounds arg); this kernel
// needs <64 regs since round-7 moved the Wf matvec to out_kernel -> (256,4)
// spill-free. (a) LDS-transpose reduce replaces 128-VALU shuffle butterfly;
// (b) cross-node pipeline hides the gather chain at node boundaries.

__global__ __launch_bounds__(256, 4) void edge_abar_kernel(
        const int* __restrict__ rp16, const int* __restrict__ deg,
        const int2* __restrict__ ep,
        const _Float16* __restrict__ RL, const _Float16* __restrict__ LL,
        const float* __restrict__ We, const float* __restrict__ g1,
        const float* __restrict__ b1, _Float16* __restrict__ ABAR, int Nr) {
    __shared__ __align__(16) float tbuf[4][16][68];   // [wave][col][k] padded stride
    const int wv   = threadIdx.x >> 6;
    const int lane = threadIdx.x & 63;
    const int col  = lane & 15;
    const int quad = lane >> 4;
    const int kb   = quad * 8;

    half2_t weh[8], gkh[8], bkh[8];
#pragma unroll
    for (int j = 0; j < 4; ++j) {
        weh[j]     = half2_t{(_Float16)We[kb + 2*j],      (_Float16)We[kb + 2*j + 1]};
        weh[4 + j] = half2_t{(_Float16)We[kb + 32 + 2*j], (_Float16)We[kb + 32 + 2*j + 1]};
        gkh[j]     = half2_t{(_Float16)g1[kb + 2*j],      (_Float16)g1[kb + 2*j + 1]};
        gkh[4 + j] = half2_t{(_Float16)g1[kb + 32 + 2*j], (_Float16)g1[kb + 32 + 2*j + 1]};
        bkh[j]     = half2_t{(_Float16)b1[kb + 2*j],      (_Float16)b1[kb + 2*j + 1]};
        bkh[4 + j] = half2_t{(_Float16)b1[kb + 32 + 2*j], (_Float16)b1[kb + 32 + 2*j + 1]};
    }

    const int nW = gridDim.x * 4;
    int n = blockIdx.x * 4 + wv;          // Nr >= 50000 > grid*4, so n < Nr here
    int pg0 = rp16[n] >> 4;
    int pg1 = rp16[n + 1] >> 4;
    int pdn = deg[n];

    bool livN = false; float fN = 0.0f;
    f16x8 llaN = {}, llbN = {};
    auto issue_group = [&](int gbase, int cnt) {
        livN = col < cnt;
        int2 p = ep[(gbase << 4) + col];
        const int s2 = livN ? p.x : 0;
        fN = livN ? __int_as_float(p.y) : 0.0f;
        llaN = *(const f16x8*)(LL + (size_t)s2 * EMB + kb);
        llbN = *(const f16x8*)(LL + (size_t)s2 * EMB + kb + 32);
    };
    if (pg0 < pg1) issue_group(pg0, pdn);     // prime first node's first group

    while (true) {
        const int g0 = pg0, g1e = pg1, dn = pdn;
        const int nn = n + nW;
        const bool hasNext = nn < Nr;
        if (hasNext) {                         // issue next node's meta EARLY
            pg0 = rp16[nn] >> 4;
            pg1 = rp16[nn + 1] >> 4;
            pdn = deg[nn];
        }

        half2_t rl2[8];
        *(f16x8*)&rl2[0] = *(const f16x8*)(RL + (size_t)n * EMB + kb);
        *(f16x8*)&rl2[4] = *(const f16x8*)(RL + (size_t)n * EMB + kb + 32);

        f32x2 acc2[8];
#pragma unroll
        for (int j = 0; j < 8; ++j) acc2[j] = f32x2{0.0f, 0.0f};

        bool didNext = false;
        for (int g = g0; g < g1e; ++g) {
            const bool liv = livN;
            const float f = fN;
            half2_t h2[8];
            *(f16x8*)&h2[0] = llaN;
            *(f16x8*)&h2[4] = llbN;
            if (g + 1 < g1e) {
                issue_group(g + 1, dn - ((g + 1 - g0) << 4));   // in-node prefetch
            } else if (hasNext && pg0 < pg1) {
                issue_group(pg0, pdn);                           // next-node prefetch
                didNext = true;
            }
            const _Float16 fh = (_Float16)f;
            const half2_t f2 = half2_t{fh, fh};
            const half2_t one2 = half2_t{(_Float16)1.0f, (_Float16)1.0f};
            float ps = 0.0f, pq = 0.0f;
#pragma unroll
            for (int j = 0; j < 8; ++j) {
                h2[j] = (h2[j] + rl2[j]) + f2 * weh[j];
                ps = dot2f(h2[j], one2, ps);
                pq = dot2f(h2[j], h2[j], pq);
            }
            ps += __shfl_xor(ps, 16, 64); ps += __shfl_xor(ps, 32, 64);
            pq += __shfl_xor(pq, 16, 64); pq += __shfl_xor(pq, 32, 64);
            const float mean = ps * (1.0f / EMB);
            const float var  = pq * (1.0f / EMB) - mean * mean;
            const float rs   = rsqrtf(var + EPSLN);
            const _Float16 rsh = (_Float16)rs;
            const _Float16 mnh = (_Float16)mean;
            const half2_t rs2 = half2_t{rsh, rsh};
            const half2_t mn2 = half2_t{mnh, mnh};
            const half2_t z2  = half2_t{(_Float16)0.0f, (_Float16)0.0f};
            if (liv) {
#pragma unroll
                for (int j = 0; j < 8; ++j) {
                    const half2_t sc = gkh[j] * rs2;
                    half2_t a = (h2[j] - mn2) * sc + bkh[j];
                    a = hmax2(a, z2);
                    f32x2 cv; cv.x = (float)a.x; cv.y = (float)a.y;
                    acc2[j] += cv;
                }
            }
        }

        // ---- LDS-transpose reduce ----
        float* tb = &tbuf[wv][col][0];
        *(float4*)(tb + kb)      = make_float4(acc2[0].x, acc2[0].y, acc2[1].x, acc2[1].y);
        *(float4*)(tb + kb + 4)  = make_float4(acc2[2].x, acc2[2].y, acc2[3].x, acc2[3].y);
        *(float4*)(tb + kb + 32) = make_float4(acc2[4].x, acc2[4].y, acc2[5].x, acc2[5].y);
        *(float4*)(tb + kb + 36) = make_float4(acc2[6].x, acc2[6].y, acc2[7].x, acc2[7].y);
        float t0[16];
#pragma unroll
        for (int c2 = 0; c2 < 16; ++c2) t0[c2] = tbuf[wv][c2][lane];
        const float s01 = (t0[0] + t0[1]) + (t0[2] + t0[3]);
        const float s23 = (t0[4] + t0[5]) + (t0[6] + t0[7]);
        const float s45 = (t0[8] + t0[9]) + (t0[10] + t0[11]);
        const float s67 = (t0[12] + t0[13]) + (t0[14] + t0[15]);
        ABAR[(size_t)n * EMB + lane] = (_Float16)((s01 + s23) + (s45 + s67));

        if (!hasNext) break;
        if (!didNext && pg0 < pg1) issue_group(pg0, pdn);   // zero-group edge cases
        n = nn;
    }
}

// ---------------- fallback edge path (wave per node, abar accumulate) ----------------

__global__ __launch_bounds__(256, 4) void edge_csr_kernel(
        const int* __restrict__ rowptr, const int2* __restrict__ ep,
        const _Float16* __restrict__ RL, const _Float16* __restrict__ LL,
        const float* __restrict__ Wecol, const float* __restrict__ g1,
        const float* __restrict__ b1,
        _Float16* __restrict__ ABAR, int Nr) {
    const int lane = threadIdx.x & 63;
    const float we  = Wecol[lane];
    const float g   = g1[lane];
    const float bb  = b1[lane];
    const int nW = gridDim.x * 4;
    for (int n = blockIdx.x * 4 + (threadIdx.x >> 6); n < Nr; n += nW) {
        const int beg = rowptr[n];
        const int end = rowptr[n + 1];
        const float rl = (float)RL[(size_t)n * EMB + lane];
        float acc = 0.0f;
        for (int idx = beg; idx < end; ++idx) {
            const int2 p = ep[idx];
            const float f = __int_as_float(p.y);
            float h = rl + (float)LL[(size_t)p.x * EMB + lane] + f * we;
            const float s1 = wtotal64(h);
            const float s2 = wtotal64(h * h);
            const float m   = s1 * (1.0f / EMB);
            const float var = s2 * (1.0f / EMB) - m * m;
            acc += fmaxf((h - m) * rsqrtf(var + EPSLN) * g + bb, 0.0f);
        }
        ABAR[(size_t)n * EMB + lane] = (_Float16)acc;
    }
}

// ---------------- fused output MLP (applies Wf, then MLP) ----------------
// agg = abar @ Wf^T + deg*bf; z = LN(agg);
// o = relu(Wo1a@z + Wo1b@right + bo1); right += Wo2@o + bo2
// (256,1): ~128 weight regs; round-6 model (budget ~256/arg) says any
// tighter cap spills. MFMA migration planned once lin2 validates layouts.

__global__ __launch_bounds__(256, 1) void out_kernel(
        const _Float16* __restrict__ ABAR, const int* __restrict__ deg,
        float* __restrict__ right,
        const float* __restrict__ g2, const float* __restrict__ b2,
        const float* __restrict__ Wf, const float* __restrict__ bfp,
        const float* __restrict__ Wo1, const float* __restrict__ Wo2,
        const float* __restrict__ bo1, const float* __restrict__ bo2, int N) {
    __shared__ __align__(16) _Float16 abuf[4][EMB];
    __shared__ __align__(16) _Float16 zbuf[4][EMB];
    __shared__ __align__(16) _Float16 rbuf[4][EMB];
    __shared__ __align__(16) _Float16 obuf[4][EMB];
    const int wv = threadIdx.x >> 6;
    const int lane = threadIdx.x & 63;
    half2_t whF[32], wh1[32], whB[32], wh2[32];
    load_w_f16(Wf, EMB, lane, whF);
    load_w_f16(Wo1, 2 * EMB, lane, wh1);            // Wo1[:, 0:64]
    load_w_f16(Wo1 + EMB, 2 * EMB, lane, whB);      // Wo1[:, 64:128]
    load_w_f16(Wo2, EMB, lane, wh2);
    const float bfv  = bfp[lane];
    const float g    = g2[lane];
    const float bb   = b2[lane];
    const float bo1v = bo1[lane];
    const float bo2v = bo2[lane];
    const int nW = gridDim.x * 4;
    for (int n = blockIdx.x * 4 + wv; n < N; n += nW) {
        abuf[wv][lane] = ABAR[(size_t)n * EMB + lane];
        const int dn = deg[n];
        const float rf = right[(size_t)n * EMB + lane];
        // agg = abar @ Wf^T + deg*bf
        const float a = matvec_f16(abuf[wv], whF, (float)dn * bfv);
        const float s1 = wtotal64(a);
        const float s2 = wtotal64(a * a);
        const float m   = s1 * (1.0f / EMB);
        const float var = s2 * (1.0f / EMB) - m * m;
        const float z = (a - m) * rsqrtf(var + EPSLN) * g + bb;
        zbuf[wv][lane] = (_Float16)z;
        rbuf[wv][lane] = (_Float16)rf;
        float acc = matvec_f16(zbuf[wv], wh1, bo1v);
        acc = matvec_f16(rbuf[wv], whB, acc);
        obuf[wv][lane] = (_Float16)fmaxf(acc, 0.0f);
        float acc2 = matvec_f16(obuf[wv], wh2, bo2v);
        right[(size_t)n * EMB + lane] = rf + acc2;
    }
}

extern "C" void kernel_launch(void* const* d_in, const int* in_sizes, int n_in,
                              void* d_out, int out_size, void* d_ws, size_t ws_size,
                              hipStream_t stream) {
    const float* cf  = (const float*)d_in[0];
    const float* vfp = (const float*)d_in[1];
    const int*   ei  = (const int*)d_in[2];
    const float* ef  = (const float*)d_in[3];
    const float* Wl  = (const float*)d_in[4];
    const float* bl  = (const float*)d_in[5];
    const float* We  = (const float*)d_in[6];
    const float* Wr  = (const float*)d_in[7];
    const float* g1  = (const float*)d_in[8];
    const float* b1  = (const float*)d_in[9];
    const float* Wf  = (const float*)d_in[10];
    const float* bfp = (const float*)d_in[11];
    const float* g2  = (const float*)d_in[12];
    const float* b2  = (const float*)d_in[13];
    const float* Wo1 = (const float*)d_in[14];
    const float* bo1 = (const float*)d_in[15];
    const float* Wo2 = (const float*)d_in[16];
    const float* bo2 = (const float*)d_in[17];

    float* c = (float*)d_out;
    float* v = c + (size_t)NCON * EMB;
    (void)hipMemcpyAsync(c, cf,  (size_t)NCON * EMB * sizeof(float), hipMemcpyDeviceToDevice, stream);
    (void)hipMemcpyAsync(v, vfp, (size_t)NVAR * EMB * sizeof(float), hipMemcpyDeviceToDevice, stream);

    float* wsf = (float*)d_ws;
    size_t off = 0;
    _Float16* AGG = (_Float16*)(wsf + off); off += (size_t)NVAR * EMB / 2;  // f16 (abar)
    _Float16* RL  = (_Float16*)(wsf + off); off += (size_t)NVAR * EMB / 2;  // f16
    _Float16* LL  = (_Float16*)(wsf + off); off += (size_t)NVAR * EMB / 2;  // f16
    int* degC  = (int*)(wsf + off); off += NCON;
    int* degV  = (int*)(wsf + off); off += NVAR;
    int* rp16C = (int*)(wsf + off); off += NCON + 4;
    int* curC  = (int*)(wsf + off); off += NCON;
    int* rp16V = (int*)(wsf + off); off += NVAR + 4;
    int* curV  = (int*)(wsf + off); off += NVAR;
    int* csumC = (int*)(wsf + off); off += 128;
    int* coffC = (int*)(wsf + off); off += 128;
    int* csumV = (int*)(wsf + off); off += 128;
    int* coffV = (int*)(wsf + off); off += 128;
    size_t off_edges = off;
    int2* epC = (int2*)(wsf + off); off += (size_t)2 * PADEC;
    int2* epV = (int2*)(wsf + off); off += (size_t)2 * PADEV;
    const bool use_mfma = ws_size >= off * sizeof(float);
    // histogram partials (19.3 MB) after the edge arrays
    int* partC = (int*)(wsf + off); off += (size_t)HCHC * HSEG * HCHUNK;
    int* partV = (int*)(wsf + off); off += (size_t)HCHV * HSEG * HCHUNK;
    const bool use_ldshist = use_mfma && ws_size >= off * sizeof(float);
    if (!use_mfma) {
        off = off_edges;
        epC = (int2*)(wsf + off); off += (size_t)2 * NEDGE;
        epV = (int2*)(wsf + off); off += (size_t)2 * NEDGE;
    }

    const int* ci = ei;
    const int* vi = ei + NEDGE;

    const dim3 blk(256);
    const int NB = 2048;
    const int NBL = 1536;
    const int nchC = (NCON + 1023) / 1024;   // 49
    const int nchV = (NVAR + 1023) / 1024;   // 98

    if (use_ldshist) {
        hist_part_kernel<<<(HCHC + HCHV) * HSEG, blk, 0, stream>>>(ci, vi, partC, partV, NEDGE);
        hist_reduce_kernel<<<640, blk, 0, stream>>>(partC, partV, degC, degV);
    } else {
        (void)hipMemsetAsync(degC, 0, NCON * sizeof(int), stream);
        (void)hipMemsetAsync(degV, 0, NVAR * sizeof(int), stream);
        hist2_kernel<<<1024, blk, 0, stream>>>(ci, vi, degC, degV, NEDGE);
    }
    if (use_mfma) {
        chunk_sum_kernel<true><<<nchC, blk, 0, stream>>>(degC, csumC, NCON);
        chunk_sum_kernel<true><<<nchV, blk, 0, stream>>>(degV, csumV, NVAR);
        chunk_offsets_kernel<<<1, 64, 0, stream>>>(csumC, coffC, rp16C, nchC, NCON);
        chunk_offsets_kernel<<<1, 64, 0, stream>>>(csumV, coffV, rp16V, nchV, NVAR);
        chunk_apply_kernel<true><<<nchC, blk, 0, stream>>>(degC, coffC, rp16C, curC, NCON);
        chunk_apply_kernel<true><<<nchV, blk, 0, stream>>>(degV, coffV, rp16V, curV, NVAR);
    } else {
        chunk_sum_kernel<false><<<nchC, blk, 0, stream>>>(degC, csumC, NCON);
        chunk_sum_kernel<false><<<nchV, blk, 0, stream>>>(degV, csumV, NVAR);
        chunk_offsets_kernel<<<1, 64, 0, stream>>>(csumC, coffC, rp16C, nchC, NCON);
        chunk_offsets_kernel<<<1, 64, 0, stream>>>(csumV, coffV, rp16V, nchV, NVAR);
        chunk_apply_kernel<false><<<nchC, blk, 0, stream>>>(degC, coffC, rp16C, curC, NCON);
        chunk_apply_kernel<false><<<nchV, blk, 0, stream>>>(degV, coffV, rp16V, curV, NVAR);
    }
    // one direction per launch: hard temporal separation so each XCD's L2
    // holds only that direction's bucket region (C: 2.35 MB, V: 3.1 MB).
    scatter_dir_kernel<NCON><<<2048, blk, 0, stream>>>(ci, vi, ef, curC, epC, NEDGE);
    scatter_dir_kernel<NVAR><<<2048, blk, 0, stream>>>(vi, ci, ef, curV, epV, NEDGE);

    for (int k = 0; k < 4; ++k) {
        const bool v2c = ((k & 1) == 0);
        float* right   = v2c ? c : v;
        float* left    = v2c ? v : c;
        const int Nr   = v2c ? NCON : NVAR;
        const int Nl   = v2c ? NVAR : NCON;
        const int nbR  = v2c ? NBL / 3 : 2 * NBL / 3;   // split blocks ~ Nr : Nl
        const int* degR = v2c ? degC : degV;

        lin2_kernel<<<NBL, blk, 0, stream>>>(
            right, Wl + (size_t)k * EMB * EMB, bl + (size_t)k * EMB, RL, Nr,
            left,  Wr + (size_t)k * EMB * EMB, LL, Nl, nbR);

        if (use_mfma) {
            edge_abar_kernel<<<NB, blk, 0, stream>>>(
                v2c ? rp16C : rp16V, degR, v2c ? epC : epV,
                RL, LL, We + (size_t)k * EMB,
                g1 + (size_t)k * EMB, b1 + (size_t)k * EMB,
                AGG, Nr);
        } else {
            edge_csr_kernel<<<NB, blk, 0, stream>>>(
                v2c ? rp16C : rp16V, v2c ? epC : epV,
                RL, LL, We + (size_t)k * EMB,
                g1 + (size_t)k * EMB, b1 + (size_t)k * EMB,
                AGG, Nr);
        }
        out_kernel<<<NB, blk, 0, stream>>>(AGG, degR, right,
                                           g2 + (size_t)k * EMB, b2 + (size_t)k * EMB,
                                           Wf + (size_t)k * EMB * EMB,
                                           bfp + (size_t)k * EMB,
                                           Wo1 + (size_t)k * EMB * 2 * EMB,
                                           Wo2 + (size_t)k * EMB * EMB,
                                           bo1 + (size_t)k * EMB, bo2 + (size_t)k * EMB,
                                           Nr);
    }
}

// Round 9
// 980.652 us; speedup vs baseline: 2.0567x; 1.1448x over previous
//
#include <hip/hip_runtime.h>

#define EMB   64
#define NCON  50000
#define NVAR  100000
#define NEDGE 1600000
#define EPSLN 1e-5f

// padded-CSR capacities (worst case: every node pads +15)
#define PADEC (NEDGE + 15 * NCON)    // 2,350,000
#define PADEV (NEDGE + 15 * NVAR)    // 3,100,000

// LDS-chunked histogram: 12544 counters/chunk (50 KB LDS), C=4 chunks, V=8.
#define HCHUNK 12544
#define HSEG   32
#define HCHC   4
#define HCHV   8

typedef _Float16 half2_t __attribute__((ext_vector_type(2)));
typedef _Float16 f16x8  __attribute__((ext_vector_type(8)));
typedef float    f32x2  __attribute__((ext_vector_type(2)));
typedef float    f32x4  __attribute__((ext_vector_type(4)));

// ---- wave-total via DPP (no DS ops) ----
template <int CTRL, int RMASK>
__device__ __forceinline__ float dpp_add_f(float x) {
    int m = __builtin_amdgcn_update_dpp(0, __builtin_bit_cast(int, x), CTRL, RMASK, 0xf, true);
    return x + __builtin_bit_cast(float, m);
}
__device__ __forceinline__ float wtotal64(float x) {
    x = dpp_add_f<0x111, 0xf>(x);
    x = dpp_add_f<0x112, 0xf>(x);
    x = dpp_add_f<0x114, 0xf>(x);
    x = dpp_add_f<0x118, 0xf>(x);
    x = dpp_add_f<0x142, 0xa>(x);
    x = dpp_add_f<0x143, 0xc>(x);
    return __builtin_bit_cast(float, __builtin_amdgcn_readlane(__builtin_bit_cast(int, x), 63));
}
template <int CTRL, int RMASK>
__device__ __forceinline__ int dpp_add_i(int x) {
    return x + __builtin_amdgcn_update_dpp(0, x, CTRL, RMASK, 0xf, true);
}
__device__ __forceinline__ int wtotal64_i(int x) {
    x = dpp_add_i<0x111, 0xf>(x);
    x = dpp_add_i<0x112, 0xf>(x);
    x = dpp_add_i<0x114, 0xf>(x);
    x = dpp_add_i<0x118, 0xf>(x);
    x = dpp_add_i<0x142, 0xa>(x);
    x = dpp_add_i<0x143, 0xc>(x);
    return __builtin_amdgcn_readlane(x, 63);
}

__device__ __forceinline__ float dot2f(half2_t a, half2_t b, float c) {
    return __builtin_amdgcn_fdot2(a, b, c, false);
}

__device__ __forceinline__ half2_t hmax2(half2_t a, half2_t b) {
#if defined(__has_builtin) && __has_builtin(__builtin_elementwise_max)
    return __builtin_elementwise_max(a, b);
#else
    half2_t r;
    r.x = a.x > b.x ? a.x : b.x;
    r.y = a.y > b.y ? a.y : b.y;
    return r;
#endif
}

// 8 x ds_read_b128 + 32 x v_dot2 with 4 independent accumulator chains
__device__ __forceinline__ float matvec_f16(const _Float16* __restrict__ buf,
                                            const half2_t* __restrict__ wh, float acc) {
    const float4* hp4 = (const float4*)buf;
    float a0 = acc, a1 = 0.0f, a2 = 0.0f, a3 = 0.0f;
#pragma unroll
    for (int j4 = 0; j4 < 8; ++j4) {
        float4 t = hp4[j4];
        a0 = dot2f(wh[4 * j4 + 0], __builtin_bit_cast(half2_t, t.x), a0);
        a1 = dot2f(wh[4 * j4 + 1], __builtin_bit_cast(half2_t, t.y), a1);
        a2 = dot2f(wh[4 * j4 + 2], __builtin_bit_cast(half2_t, t.z), a2);
        a3 = dot2f(wh[4 * j4 + 3], __builtin_bit_cast(half2_t, t.w), a3);
    }
    return (a0 + a1) + (a2 + a3);
}

__device__ __forceinline__ void load_w_f16(const float* __restrict__ W, int stride,
                                           int lane, half2_t* wh) {
#pragma unroll
    for (int j4 = 0; j4 < 16; ++j4) {
        float4 t = *(const float4*)(W + (size_t)lane * stride + j4 * 4);
        wh[2 * j4 + 0] = half2_t{(_Float16)t.x, (_Float16)t.y};
        wh[2 * j4 + 1] = half2_t{(_Float16)t.z, (_Float16)t.w};
    }
}

__device__ __forceinline__ f16x8 cvt8_f16(float4 u, float4 v) {
    f16x8 r;
    r[0] = (_Float16)u.x; r[1] = (_Float16)u.y; r[2] = (_Float16)u.z; r[3] = (_Float16)u.w;
    r[4] = (_Float16)v.x; r[5] = (_Float16)v.y; r[6] = (_Float16)v.z; r[7] = (_Float16)v.w;
    return r;
}

// ---------------- CSR build ----------------

// LDS-chunked histogram, NO global atomics (round-2: 3.2M device atomicAdds
// = ~31B memory-side partial-sector writes each; 99.7 MB WRITE, 129 us).
__global__ __launch_bounds__(256) void hist_part_kernel(
        const int* __restrict__ ci, const int* __restrict__ vi,
        int* __restrict__ partC, int* __restrict__ partV, int E) {
    __shared__ int lh[HCHUNK];
    const int seg  = blockIdx.x % HSEG;
    const int cg   = blockIdx.x / HSEG;
    const bool isC = cg < HCHC;
    const int chunk = isC ? cg : cg - HCHC;
    const int base  = chunk * HCHUNK;
    const int* __restrict__ dst = isC ? ci : vi;
    int* __restrict__ part = (isC ? partC : partV) + (size_t)(chunk * HSEG + seg) * HCHUNK;

    int4* l4 = (int4*)lh;
    for (int i = threadIdx.x; i < HCHUNK / 4; i += 256) l4[i] = make_int4(0, 0, 0, 0);
    __syncthreads();

    const int s0 = (int)((long long)seg * E / HSEG);
    const int s1 = (int)((long long)(seg + 1) * E / HSEG);
    for (int i = s0 + threadIdx.x; i < s1; i += 256) {
        const unsigned rel = (unsigned)(dst[i] - base);
        if (rel < (unsigned)HCHUNK) atomicAdd(&lh[rel], 1);
    }
    __syncthreads();
    int4* p4 = (int4*)part;
    for (int i = threadIdx.x; i < HCHUNK / 4; i += 256) p4[i] = l4[i];
}

// sum the HSEG segment-partials per counter -> degC/degV (coalesced reads)
__global__ __launch_bounds__(256) void hist_reduce_kernel(
        const int* __restrict__ partC, const int* __restrict__ partV,
        int* __restrict__ degC, int* __restrict__ degV) {
    int j = blockIdx.x * blockDim.x + threadIdx.x;
    const int tot = NCON + NVAR;
    for (; j < tot; j += gridDim.x * blockDim.x) {
        if (j < NCON) {
            const int chunk = j / HCHUNK, off = j - chunk * HCHUNK;
            const int* p = partC + (size_t)chunk * HSEG * HCHUNK + off;
            int s = 0;
#pragma unroll
            for (int t = 0; t < HSEG; ++t) s += p[(size_t)t * HCHUNK];
            degC[j] = s;
        } else {
            const int jj = j - NCON;
            const int chunk = jj / HCHUNK, off = jj - chunk * HCHUNK;
            const int* p = partV + (size_t)chunk * HSEG * HCHUNK + off;
            int s = 0;
#pragma unroll
            for (int t = 0; t < HSEG; ++t) s += p[(size_t)t * HCHUNK];
            degV[jj] = s;
        }
    }
}

// fallback: atomic histogram (used only if ws can't fit the partials)
__global__ __launch_bounds__(256) void hist2_kernel(
        const int* __restrict__ ci, const int* __restrict__ vi,
        int* __restrict__ degC, int* __restrict__ degV, int E) {
    int i = blockIdx.x * blockDim.x + threadIdx.x;
    for (; i < E; i += gridDim.x * blockDim.x) {
        atomicAdd(&degC[ci[i]], 1);
        atomicAdd(&degV[vi[i]], 1);
    }
}

template <bool PAD>
__global__ __launch_bounds__(256) void chunk_sum_kernel(const int* __restrict__ hist,
                                                        int* __restrict__ csum, int N) {
    __shared__ int wpart[4];
    const int base = blockIdx.x * 1024 + threadIdx.x * 4;
    int s = 0;
    if (base + 3 < N) {
        int4 t = *(const int4*)(hist + base);
        if (PAD) s = ((t.x+15)&~15) + ((t.y+15)&~15) + ((t.z+15)&~15) + ((t.w+15)&~15);
        else     s = t.x + t.y + t.z + t.w;
    } else {
#pragma unroll
        for (int j = 0; j < 4; ++j)
            if (base + j < N) { int v = hist[base + j]; s += PAD ? ((v+15)&~15) : v; }
    }
    s = wtotal64_i(s);
    if ((threadIdx.x & 63) == 0) wpart[threadIdx.x >> 6] = s;
    __syncthreads();
    if (threadIdx.x == 0) csum[blockIdx.x] = wpart[0] + wpart[1] + wpart[2] + wpart[3];
}

__global__ void chunk_offsets_kernel(const int* __restrict__ csum, int* __restrict__ coff,
                                     int* __restrict__ rowptr, int nchunk, int N) {
    const int lane = threadIdx.x;
    int carry = 0;
    for (int base = 0; base < nchunk; base += 64) {
        const int i = base + lane;
        int val = (i < nchunk) ? csum[i] : 0;
        int incl = val;
#pragma unroll
        for (int off = 1; off < 64; off <<= 1) {
            int t = __shfl_up(incl, off, 64);
            if (lane >= off) incl += t;
        }
        if (i < nchunk) coff[i] = incl - val + carry;
        carry += __shfl(incl, 63, 64);
    }
    if (lane == 0) rowptr[N] = carry;
}

template <bool PAD>
__global__ __launch_bounds__(256) void chunk_apply_kernel(
        const int* __restrict__ hist, const int* __restrict__ coff,
        int* __restrict__ rowptr, int* __restrict__ cursor, int N) {
    __shared__ int wpart[4];
    const int wv = threadIdx.x >> 6;
    const int lane = threadIdx.x & 63;
    const int base = blockIdx.x * 1024 + threadIdx.x * 4;
    int v0 = 0, v1 = 0, v2 = 0, v3 = 0;
    if (base + 3 < N) {
        int4 t = *(const int4*)(hist + base);
        v0 = t.x; v1 = t.y; v2 = t.z; v3 = t.w;
    } else {
        if (base + 0 < N) v0 = hist[base + 0];
        if (base + 1 < N) v1 = hist[base + 1];
        if (base + 2 < N) v2 = hist[base + 2];
        if (base + 3 < N) v3 = hist[base + 3];
    }
    if (PAD) { v0 = (v0+15)&~15; v1 = (v1+15)&~15; v2 = (v2+15)&~15; v3 = (v3+15)&~15; }
    const int s = v0 + v1 + v2 + v3;
    int incl = s;
#pragma unroll
    for (int off = 1; off < 64; off <<= 1) {
        int t = __shfl_up(incl, off, 64);
        if (lane >= off) incl += t;
    }
    if (lane == 63) wpart[wv] = incl;
    __syncthreads();
    int excl = coff[blockIdx.x] + incl - s;
    for (int w = 0; w < wv; ++w) excl += wpart[w];
    if (base + 0 < N) { rowptr[base + 0] = excl; cursor[base + 0] = excl; excl += v0; }
    if (base + 1 < N) { rowptr[base + 1] = excl; cursor[base + 1] = excl; excl += v1; }
    if (base + 2 < N) { rowptr[base + 2] = excl; cursor[base + 2] = excl; excl += v2; }
    if (base + 3 < N) { rowptr[base + 3] = excl; cursor[base + 3] = excl; excl += v3; }
}

// XCD-bucketed scatter, ONE direction per launch (round-2 verified: each
// XCD's L2 holds one bucket's CSR region -> write combining).
template <int NDST>
__global__ __launch_bounds__(256) void scatter_dir_kernel(
        const int* __restrict__ dst, const int* __restrict__ src,
        const float* __restrict__ ef,
        int* __restrict__ cur, int2* __restrict__ ep, int E) {
    const int rep = blockIdx.x & 7;
    const int stride = (gridDim.x >> 3) * blockDim.x;
    int i = (blockIdx.x >> 3) * blockDim.x + threadIdx.x;
    for (; i < E; i += stride) {
        const int d = dst[i];
        const int b = (int)(((long long)d * 8) / NDST);
        if (b == rep) {
            const int slot = atomicAdd(&cur[d], 1);
            ep[slot] = make_int2(src[i], __float_as_int(ef[i]));
        }
    }
}

// ---------------- fused node linear via MFMA: Y = X @ W^T (+b) -> f16 ----------------
// Round-8 validated layouts on HW (absmax unchanged):
//   A-frag: lane l holds X[n0+(l&15)][kc*32+(l>>4)*8+j]
//   B-frag: lane l holds W[ct*16+(l&15)][kc*32+(l>>4)*8+j]
//   D:      lane l, reg r -> row (l>>4)*4+r, col l&15 (+16*ct)

__global__ __launch_bounds__(256, 3) void lin2_kernel(
        const float* __restrict__ XR, const float* __restrict__ WR,
        const float* __restrict__ bR, _Float16* __restrict__ YR, int NR,
        const float* __restrict__ XL, const float* __restrict__ WL,
        _Float16* __restrict__ YL, int NL, int nbR) {
    const int wv   = threadIdx.x >> 6;
    const int lane = threadIdx.x & 63;
    const int col  = lane & 15;
    const int kgrp = lane >> 4;           // 0..3
    const bool isR = (int)blockIdx.x < nbR;
    const float* X = isR ? XR : XL;
    const float* W = isR ? WR : WL;
    _Float16* Y    = isR ? YR : YL;
    const int N    = isR ? NR : NL;
    const int b0   = isR ? 0 : nbR;
    const int nb   = isR ? nbR : (gridDim.x - nbR);

    f16x8 bf[4][2];
#pragma unroll
    for (int ct = 0; ct < 4; ++ct)
#pragma unroll
        for (int kc = 0; kc < 2; ++kc) {
            const float* wrow = W + (size_t)(ct * 16 + col) * EMB + kc * 32 + kgrp * 8;
            bf[ct][kc] = cvt8_f16(*(const float4*)wrow, *(const float4*)(wrow + 4));
        }
    float bias[4];
#pragma unroll
    for (int ct = 0; ct < 4; ++ct) bias[ct] = isR ? bR[ct * 16 + col] : 0.0f;

    const int ntile = (N + 15) >> 4;
    const int nW = nb * 4;
    for (int t = ((int)blockIdx.x - b0) * 4 + wv; t < ntile; t += nW) {
        const int n0 = t << 4;
        const int srow = min(n0 + col, N - 1);
        const float* xrow = X + (size_t)srow * EMB + kgrp * 8;
        const float4 x0 = *(const float4*)(xrow);
        const float4 x1 = *(const float4*)(xrow + 4);
        const float4 x2 = *(const float4*)(xrow + 32);
        const float4 x3 = *(const float4*)(xrow + 36);
        const f16x8 a0 = cvt8_f16(x0, x1);
        const f16x8 a1 = cvt8_f16(x2, x3);
        f32x4 acc[4];
#pragma unroll
        for (int ct = 0; ct < 4; ++ct) {
            acc[ct] = __builtin_amdgcn_mfma_f32_16x16x32_f16(
                a0, bf[ct][0], (f32x4){0.0f, 0.0f, 0.0f, 0.0f}, 0, 0, 0);
            acc[ct] = __builtin_amdgcn_mfma_f32_16x16x32_f16(
                a1, bf[ct][1], acc[ct], 0, 0, 0);
        }
#pragma unroll
        for (int r = 0; r < 4; ++r) {
            const int n = n0 + (kgrp << 2) + r;
            if (n < N) {
                _Float16* yrow = Y + (size_t)n * EMB + col;
#pragma unroll
                for (int ct = 0; ct < 4; ++ct)
                    yrow[ct * 16] = (_Float16)(acc[ct][r] + bias[ct]);
            }
        }
    }
}

// ---------------- edge stage: wave per node, abar accumulate ----------------
// Key identity: sum_e relu(LN(h_e)) @ Wf^T = (sum_e relu(LN(h_e))) @ Wf^T.
// (256,4) spill-free since round-7 moved the Wf matvec out (round-6 model:
// VGPR budget ~256/arg). LDS-transpose reduce + cross-node pipeline.

__global__ __launch_bounds__(256, 4) void edge_abar_kernel(
        const int* __restrict__ rp16, const int* __restrict__ deg,
        const int2* __restrict__ ep,
        const _Float16* __restrict__ RL, const _Float16* __restrict__ LL,
        const float* __restrict__ We, const float* __restrict__ g1,
        const float* __restrict__ b1, _Float16* __restrict__ ABAR, int Nr) {
    __shared__ __align__(16) float tbuf[4][16][68];   // [wave][col][k] padded stride
    const int wv   = threadIdx.x >> 6;
    const int lane = threadIdx.x & 63;
    const int col  = lane & 15;
    const int quad = lane >> 4;
    const int kb   = quad * 8;

    half2_t weh[8], gkh[8], bkh[8];
#pragma unroll
    for (int j = 0; j < 4; ++j) {
        weh[j]     = half2_t{(_Float16)We[kb + 2*j],      (_Float16)We[kb + 2*j + 1]};
        weh[4 + j] = half2_t{(_Float16)We[kb + 32 + 2*j], (_Float16)We[kb + 32 + 2*j + 1]};
        gkh[j]     = half2_t{(_Float16)g1[kb + 2*j],      (_Float16)g1[kb + 2*j + 1]};
        gkh[4 + j] = half2_t{(_Float16)g1[kb + 32 + 2*j], (_Float16)g1[kb + 32 + 2*j + 1]};
        bkh[j]     = half2_t{(_Float16)b1[kb + 2*j],      (_Float16)b1[kb + 2*j + 1]};
        bkh[4 + j] = half2_t{(_Float16)b1[kb + 32 + 2*j], (_Float16)b1[kb + 32 + 2*j + 1]};
    }

    const int nW = gridDim.x * 4;
    int n = blockIdx.x * 4 + wv;          // Nr >= 50000 > grid*4, so n < Nr here
    int pg0 = rp16[n] >> 4;
    int pg1 = rp16[n + 1] >> 4;
    int pdn = deg[n];

    bool livN = false; float fN = 0.0f;
    f16x8 llaN = {}, llbN = {};
    auto issue_group = [&](int gbase, int cnt) {
        livN = col < cnt;
        int2 p = ep[(gbase << 4) + col];
        const int s2 = livN ? p.x : 0;
        fN = livN ? __int_as_float(p.y) : 0.0f;
        llaN = *(const f16x8*)(LL + (size_t)s2 * EMB + kb);
        llbN = *(const f16x8*)(LL + (size_t)s2 * EMB + kb + 32);
    };
    if (pg0 < pg1) issue_group(pg0, pdn);     // prime first node's first group

    while (true) {
        const int g0 = pg0, g1e = pg1, dn = pdn;
        const int nn = n + nW;
        const bool hasNext = nn < Nr;
        if (hasNext) {                         // issue next node's meta EARLY
            pg0 = rp16[nn] >> 4;
            pg1 = rp16[nn + 1] >> 4;
            pdn = deg[nn];
        }

        half2_t rl2[8];
        *(f16x8*)&rl2[0] = *(const f16x8*)(RL + (size_t)n * EMB + kb);
        *(f16x8*)&rl2[4] = *(const f16x8*)(RL + (size_t)n * EMB + kb + 32);

        f32x2 acc2[8];
#pragma unroll
        for (int j = 0; j < 8; ++j) acc2[j] = f32x2{0.0f, 0.0f};

        bool didNext = false;
        for (int g = g0; g < g1e; ++g) {
            const bool liv = livN;
            const float f = fN;
            half2_t h2[8];
            *(f16x8*)&h2[0] = llaN;
            *(f16x8*)&h2[4] = llbN;
            if (g + 1 < g1e) {
                issue_group(g + 1, dn - ((g + 1 - g0) << 4));   // in-node prefetch
            } else if (hasNext && pg0 < pg1) {
                issue_group(pg0, pdn);                           // next-node prefetch
                didNext = true;
            }
            const _Float16 fh = (_Float16)f;
            const half2_t f2 = half2_t{fh, fh};
            const half2_t one2 = half2_t{(_Float16)1.0f, (_Float16)1.0f};
            float ps = 0.0f, pq = 0.0f;
#pragma unroll
            for (int j = 0; j < 8; ++j) {
                h2[j] = (h2[j] + rl2[j]) + f2 * weh[j];
                ps = dot2f(h2[j], one2, ps);
                pq = dot2f(h2[j], h2[j], pq);
            }
            ps += __shfl_xor(ps, 16, 64); ps += __shfl_xor(ps, 32, 64);
            pq += __shfl_xor(pq, 16, 64); pq += __shfl_xor(pq, 32, 64);
            const float mean = ps * (1.0f / EMB);
            const float var  = pq * (1.0f / EMB) - mean * mean;
            const float rs   = rsqrtf(var + EPSLN);
            const _Float16 rsh = (_Float16)rs;
            const _Float16 mnh = (_Float16)mean;
            const half2_t rs2 = half2_t{rsh, rsh};
            const half2_t mn2 = half2_t{mnh, mnh};
            const half2_t z2  = half2_t{(_Float16)0.0f, (_Float16)0.0f};
            if (liv) {
#pragma unroll
                for (int j = 0; j < 8; ++j) {
                    const half2_t sc = gkh[j] * rs2;
                    half2_t a = (h2[j] - mn2) * sc + bkh[j];
                    a = hmax2(a, z2);
                    f32x2 cv; cv.x = (float)a.x; cv.y = (float)a.y;
                    acc2[j] += cv;
                }
            }
        }

        // ---- LDS-transpose reduce ----
        float* tb = &tbuf[wv][col][0];
        *(float4*)(tb + kb)      = make_float4(acc2[0].x, acc2[0].y, acc2[1].x, acc2[1].y);
        *(float4*)(tb + kb + 4)  = make_float4(acc2[2].x, acc2[2].y, acc2[3].x, acc2[3].y);
        *(float4*)(tb + kb + 32) = make_float4(acc2[4].x, acc2[4].y, acc2[5].x, acc2[5].y);
        *(float4*)(tb + kb + 36) = make_float4(acc2[6].x, acc2[6].y, acc2[7].x, acc2[7].y);
        float t0[16];
#pragma unroll
        for (int c2 = 0; c2 < 16; ++c2) t0[c2] = tbuf[wv][c2][lane];
        const float s01 = (t0[0] + t0[1]) + (t0[2] + t0[3]);
        const float s23 = (t0[4] + t0[5]) + (t0[6] + t0[7]);
        const float s45 = (t0[8] + t0[9]) + (t0[10] + t0[11]);
        const float s67 = (t0[12] + t0[13]) + (t0[14] + t0[15]);
        ABAR[(size_t)n * EMB + lane] = (_Float16)((s01 + s23) + (s45 + s67));

        if (!hasNext) break;
        if (!didNext && pg0 < pg1) issue_group(pg0, pdn);   // zero-group edge cases
        n = nn;
    }
}

// ---------------- fallback edge path (wave per node, abar accumulate) ----------------

__global__ __launch_bounds__(256, 4) void edge_csr_kernel(
        const int* __restrict__ rowptr, const int2* __restrict__ ep,
        const _Float16* __restrict__ RL, const _Float16* __restrict__ LL,
        const float* __restrict__ Wecol, const float* __restrict__ g1,
        const float* __restrict__ b1,
        _Float16* __restrict__ ABAR, int Nr) {
    const int lane = threadIdx.x & 63;
    const float we  = Wecol[lane];
    const float g   = g1[lane];
    const float bb  = b1[lane];
    const int nW = gridDim.x * 4;
    for (int n = blockIdx.x * 4 + (threadIdx.x >> 6); n < Nr; n += nW) {
        const int beg = rowptr[n];
        const int end = rowptr[n + 1];
        const float rl = (float)RL[(size_t)n * EMB + lane];
        float acc = 0.0f;
        for (int idx = beg; idx < end; ++idx) {
            const int2 p = ep[idx];
            const float f = __int_as_float(p.y);
            float h = rl + (float)LL[(size_t)p.x * EMB + lane] + f * we;
            const float s1 = wtotal64(h);
            const float s2 = wtotal64(h * h);
            const float m   = s1 * (1.0f / EMB);
            const float var = s2 * (1.0f / EMB) - m * m;
            acc += fmaxf((h - m) * rsqrtf(var + EPSLN) * g + bb, 0.0f);
        }
        ABAR[(size_t)n * EMB + lane] = (_Float16)acc;
    }
}

// ---------------- fused output MLP via MFMA ----------------
// Per 16-node tile, 3 chained GEMMs (24 MFMA):
//   1) agg = abar @ Wf^T + deg*bf        (A direct from f16 ABAR)
//   2) z = LN(agg) rowwise IN D-LAYOUT: row (l>>4)*4+r owned by the 16-lane
//      group sharing l>>4 -> stats = sum over 4 ct regs + 4-step shfl_xor(1,2,4,8)
//   3) o = relu(z@Wo1a^T + right@Wo1b^T + bo1)  (z via LDS D->A transpose;
//      right loaded direct into A-layout from f32)
//   4) right += o@Wo2^T + bo2            (o via LDS; final RMW in D positions)
// LDS tiles [16][72] f16: row stride 144B keeps ds_read_b128 16B-aligned;
// reads are 2-way bank aliased (free, m136). ~180 VGPR -> (256,1) cap 256,
// spill-free per round-6 model. NCON/NVAR both %16==0 -> no tail handling.

__global__ __launch_bounds__(256, 1) void out_kernel(
        const _Float16* __restrict__ ABAR, const int* __restrict__ deg,
        float* __restrict__ right,
        const float* __restrict__ g2, const float* __restrict__ b2,
        const float* __restrict__ Wf, const float* __restrict__ bfp,
        const float* __restrict__ Wo1, const float* __restrict__ Wo2,
        const float* __restrict__ bo1, const float* __restrict__ bo2, int N) {
    __shared__ __align__(16) _Float16 zt[4][16][72];
    __shared__ __align__(16) _Float16 ot[4][16][72];
    const int wv   = threadIdx.x >> 6;
    const int lane = threadIdx.x & 63;
    const int col  = lane & 15;
    const int kgrp = lane >> 4;

    f16x8 bF[4][2], b1a[4][2], b1b[4][2], b2f[4][2];
#pragma unroll
    for (int ct = 0; ct < 4; ++ct)
#pragma unroll
        for (int kc = 0; kc < 2; ++kc) {
            const int row = ct * 16 + col;
            const int ko  = kc * 32 + kgrp * 8;
            const float* wf = Wf  + (size_t)row * EMB + ko;
            const float* w1 = Wo1 + (size_t)row * 2 * EMB + ko;
            const float* w2 = Wo2 + (size_t)row * EMB + ko;
            bF[ct][kc]  = cvt8_f16(*(const float4*)wf, *(const float4*)(wf + 4));
            b1a[ct][kc] = cvt8_f16(*(const float4*)w1, *(const float4*)(w1 + 4));
            b1b[ct][kc] = cvt8_f16(*(const float4*)(w1 + EMB), *(const float4*)(w1 + EMB + 4));
            b2f[ct][kc] = cvt8_f16(*(const float4*)w2, *(const float4*)(w2 + 4));
        }
    float bfc[4], gc[4], bbc[4], bo1c[4], bo2c[4];
#pragma unroll
    for (int ct = 0; ct < 4; ++ct) {
        const int cd = ct * 16 + col;
        bfc[ct]  = bfp[cd];
        gc[ct]   = g2[cd];
        bbc[ct]  = b2[cd];
        bo1c[ct] = bo1[cd];
        bo2c[ct] = bo2[cd];
    }

    const int ntile = N >> 4;          // N % 16 == 0
    const int nW = gridDim.x * 4;
    for (int t = blockIdx.x * 4 + wv; t < ntile; t += nW) {
        const int n0 = t << 4;
        // ---- GEMM1: agg = abar @ Wf^T ----
        const _Float16* arow = ABAR + (size_t)(n0 + col) * EMB + kgrp * 8;
        const f16x8 aA0 = *(const f16x8*)(arow);
        const f16x8 aA1 = *(const f16x8*)(arow + 32);
        f32x4 acc[4];
#pragma unroll
        for (int ct = 0; ct < 4; ++ct) {
            acc[ct] = __builtin_amdgcn_mfma_f32_16x16x32_f16(
                aA0, bF[ct][0], (f32x4){0.0f, 0.0f, 0.0f, 0.0f}, 0, 0, 0);
            acc[ct] = __builtin_amdgcn_mfma_f32_16x16x32_f16(
                aA1, bF[ct][1], acc[ct], 0, 0, 0);
        }
        // deg for my 4 rows
        float dnr[4];
#pragma unroll
        for (int r = 0; r < 4; ++r) dnr[r] = (float)deg[n0 + (kgrp << 2) + r];
        // ---- rowwise LN in D-layout ----
#pragma unroll
        for (int r = 0; r < 4; ++r) {
            float s1 = 0.0f, s2 = 0.0f;
#pragma unroll
            for (int ct = 0; ct < 4; ++ct) {
                const float a = acc[ct][r] + dnr[r] * bfc[ct];
                acc[ct][r] = a;
                s1 += a; s2 += a * a;
            }
            s1 += __shfl_xor(s1, 1, 64); s2 += __shfl_xor(s2, 1, 64);
            s1 += __shfl_xor(s1, 2, 64); s2 += __shfl_xor(s2, 2, 64);
            s1 += __shfl_xor(s1, 4, 64); s2 += __shfl_xor(s2, 4, 64);
            s1 += __shfl_xor(s1, 8, 64); s2 += __shfl_xor(s2, 8, 64);
            const float mean = s1 * (1.0f / EMB);
            const float var  = s2 * (1.0f / EMB) - mean * mean;
            const float rs   = rsqrtf(var + EPSLN);
            const int zr = (kgrp << 2) + r;
#pragma unroll
            for (int ct = 0; ct < 4; ++ct)
                zt[wv][zr][ct * 16 + col] =
                    (_Float16)((acc[ct][r] - mean) * rs * gc[ct] + bbc[ct]);
        }
        // ---- GEMM3: o = relu(z@Wo1a^T + right@Wo1b^T + bo1) ----
        const _Float16* zrow = &zt[wv][col][kgrp * 8];
        const f16x8 zA0 = *(const f16x8*)(zrow);
        const f16x8 zA1 = *(const f16x8*)(zrow + 32);
        const float* rrow = right + (size_t)(n0 + col) * EMB + kgrp * 8;
        const f16x8 rA0 = cvt8_f16(*(const float4*)(rrow), *(const float4*)(rrow + 4));
        const f16x8 rA1 = cvt8_f16(*(const float4*)(rrow + 32), *(const float4*)(rrow + 36));
        f32x4 acc3[4];
#pragma unroll
        for (int ct = 0; ct < 4; ++ct) {
            acc3[ct] = __builtin_amdgcn_mfma_f32_16x16x32_f16(
                zA0, b1a[ct][0], (f32x4){0.0f, 0.0f, 0.0f, 0.0f}, 0, 0, 0);
            acc3[ct] = __builtin_amdgcn_mfma_f32_16x16x32_f16(
                zA1, b1a[ct][1], acc3[ct], 0, 0, 0);
            acc3[ct] = __builtin_amdgcn_mfma_f32_16x16x32_f16(
                rA0, b1b[ct][0], acc3[ct], 0, 0, 0);
            acc3[ct] = __builtin_amdgcn_mfma_f32_16x16x32_f16(
                rA1, b1b[ct][1], acc3[ct], 0, 0, 0);
        }
#pragma unroll
        for (int r = 0; r < 4; ++r) {
            const int orr = (kgrp << 2) + r;
#pragma unroll
            for (int ct = 0; ct < 4; ++ct)
                ot[wv][orr][ct * 16 + col] =
                    (_Float16)fmaxf(acc3[ct][r] + bo1c[ct], 0.0f);
        }
        // ---- GEMM4: right += o@Wo2^T + bo2 ----
        const _Float16* orow = &ot[wv][col][kgrp * 8];
        const f16x8 oA0 = *(const f16x8*)(orow);
        const f16x8 oA1 = *(const f16x8*)(orow + 32);
        f32x4 acc4[4];
#pragma unroll
        for (int ct = 0; ct < 4; ++ct) {
            acc4[ct] = __builtin_amdgcn_mfma_f32_16x16x32_f16(
                oA0, b2f[ct][0], (f32x4){0.0f, 0.0f, 0.0f, 0.0f}, 0, 0, 0);
            acc4[ct] = __builtin_amdgcn_mfma_f32_16x16x32_f16(
                oA1, b2f[ct][1], acc4[ct], 0, 0, 0);
        }
#pragma unroll
        for (int r = 0; r < 4; ++r) {
            float* rr = right + (size_t)(n0 + (kgrp << 2) + r) * EMB + col;
#pragma unroll
            for (int ct = 0; ct < 4; ++ct)
                rr[ct * 16] += acc4[ct][r] + bo2c[ct];
        }
    }
}

extern "C" void kernel_launch(void* const* d_in, const int* in_sizes, int n_in,
                              void* d_out, int out_size, void* d_ws, size_t ws_size,
                              hipStream_t stream) {
    const float* cf  = (const float*)d_in[0];
    const float* vfp = (const float*)d_in[1];
    const int*   ei  = (const int*)d_in[2];
    const float* ef  = (const float*)d_in[3];
    const float* Wl  = (const float*)d_in[4];
    const float* bl  = (const float*)d_in[5];
    const float* We  = (const float*)d_in[6];
    const float* Wr  = (const float*)d_in[7];
    const float* g1  = (const float*)d_in[8];
    const float* b1  = (const float*)d_in[9];
    const float* Wf  = (const float*)d_in[10];
    const float* bfp = (const float*)d_in[11];
    const float* g2  = (const float*)d_in[12];
    const float* b2  = (const float*)d_in[13];
    const float* Wo1 = (const float*)d_in[14];
    const float* bo1 = (const float*)d_in[15];
    const float* Wo2 = (const float*)d_in[16];
    const float* bo2 = (const float*)d_in[17];

    float* c = (float*)d_out;
    float* v = c + (size_t)NCON * EMB;
    (void)hipMemcpyAsync(c, cf,  (size_t)NCON * EMB * sizeof(float), hipMemcpyDeviceToDevice, stream);
    (void)hipMemcpyAsync(v, vfp, (size_t)NVAR * EMB * sizeof(float), hipMemcpyDeviceToDevice, stream);

    float* wsf = (float*)d_ws;
    size_t off = 0;
    _Float16* AGG = (_Float16*)(wsf + off); off += (size_t)NVAR * EMB / 2;  // f16 (abar)
    _Float16* RL  = (_Float16*)(wsf + off); off += (size_t)NVAR * EMB / 2;  // f16
    _Float16* LL  = (_Float16*)(wsf + off); off += (size_t)NVAR * EMB / 2;  // f16
    int* degC  = (int*)(wsf + off); off += NCON;
    int* degV  = (int*)(wsf + off); off += NVAR;
    int* rp16C = (int*)(wsf + off); off += NCON + 4;
    int* curC  = (int*)(wsf + off); off += NCON;
    int* rp16V = (int*)(wsf + off); off += NVAR + 4;
    int* curV  = (int*)(wsf + off); off += NVAR;
    int* csumC = (int*)(wsf + off); off += 128;
    int* coffC = (int*)(wsf + off); off += 128;
    int* csumV = (int*)(wsf + off); off += 128;
    int* coffV = (int*)(wsf + off); off += 128;
    size_t off_edges = off;
    int2* epC = (int2*)(wsf + off); off += (size_t)2 * PADEC;
    int2* epV = (int2*)(wsf + off); off += (size_t)2 * PADEV;
    const bool use_mfma = ws_size >= off * sizeof(float);
    // histogram partials (19.3 MB) after the edge arrays
    int* partC = (int*)(wsf + off); off += (size_t)HCHC * HSEG * HCHUNK;
    int* partV = (int*)(wsf + off); off += (size_t)HCHV * HSEG * HCHUNK;
    const bool use_ldshist = use_mfma && ws_size >= off * sizeof(float);
    if (!use_mfma) {
        off = off_edges;
        epC = (int2*)(wsf + off); off += (size_t)2 * NEDGE;
        epV = (int2*)(wsf + off); off += (size_t)2 * NEDGE;
    }

    const int* ci = ei;
    const int* vi = ei + NEDGE;

    const dim3 blk(256);
    const int NB = 2048;
    const int NBL = 1536;
    const int nchC = (NCON + 1023) / 1024;   // 49
    const int nchV = (NVAR + 1023) / 1024;   // 98

    if (use_ldshist) {
        hist_part_kernel<<<(HCHC + HCHV) * HSEG, blk, 0, stream>>>(ci, vi, partC, partV, NEDGE);
        hist_reduce_kernel<<<640, blk, 0, stream>>>(partC, partV, degC, degV);
    } else {
        (void)hipMemsetAsync(degC, 0, NCON * sizeof(int), stream);
        (void)hipMemsetAsync(degV, 0, NVAR * sizeof(int), stream);
        hist2_kernel<<<1024, blk, 0, stream>>>(ci, vi, degC, degV, NEDGE);
    }
    if (use_mfma) {
        chunk_sum_kernel<true><<<nchC, blk, 0, stream>>>(degC, csumC, NCON);
        chunk_sum_kernel<true><<<nchV, blk, 0, stream>>>(degV, csumV, NVAR);
        chunk_offsets_kernel<<<1, 64, 0, stream>>>(csumC, coffC, rp16C, nchC, NCON);
        chunk_offsets_kernel<<<1, 64, 0, stream>>>(csumV, coffV, rp16V, nchV, NVAR);
        chunk_apply_kernel<true><<<nchC, blk, 0, stream>>>(degC, coffC, rp16C, curC, NCON);
        chunk_apply_kernel<true><<<nchV, blk, 0, stream>>>(degV, coffV, rp16V, curV, NVAR);
    } else {
        chunk_sum_kernel<false><<<nchC, blk, 0, stream>>>(degC, csumC, NCON);
        chunk_sum_kernel<false><<<nchV, blk, 0, stream>>>(degV, csumV, NVAR);
        chunk_offsets_kernel<<<1, 64, 0, stream>>>(csumC, coffC, rp16C, nchC, NCON);
        chunk_offsets_kernel<<<1, 64, 0, stream>>>(csumV, coffV, rp16V, nchV, NVAR);
        chunk_apply_kernel<false><<<nchC, blk, 0, stream>>>(degC, coffC, rp16C, curC, NCON);
        chunk_apply_kernel<false><<<nchV, blk, 0, stream>>>(degV, coffV, rp16V, curV, NVAR);
    }
    // one direction per launch: hard temporal separation so each XCD's L2
    // holds only that direction's bucket region (C: 2.35 MB, V: 3.1 MB).
    scatter_dir_kernel<NCON><<<2048, blk, 0, stream>>>(ci, vi, ef, curC, epC, NEDGE);
    scatter_dir_kernel<NVAR><<<2048, blk, 0, stream>>>(vi, ci, ef, curV, epV, NEDGE);

    for (int k = 0; k < 4; ++k) {
        const bool v2c = ((k & 1) == 0);
        float* right   = v2c ? c : v;
        float* left    = v2c ? v : c;
        const int Nr   = v2c ? NCON : NVAR;
        const int Nl   = v2c ? NVAR : NCON;
        const int nbR  = v2c ? NBL / 3 : 2 * NBL / 3;   // split blocks ~ Nr : Nl
        const int* degR = v2c ? degC : degV;

        lin2_kernel<<<NBL, blk, 0, stream>>>(
            right, Wl + (size_t)k * EMB * EMB, bl + (size_t)k * EMB, RL, Nr,
            left,  Wr + (size_t)k * EMB * EMB, LL, Nl, nbR);

        if (use_mfma) {
            edge_abar_kernel<<<NB, blk, 0, stream>>>(
                v2c ? rp16C : rp16V, degR, v2c ? epC : epV,
                RL, LL, We + (size_t)k * EMB,
                g1 + (size_t)k * EMB, b1 + (size_t)k * EMB,
                AGG, Nr);
        } else {
            edge_csr_kernel<<<NB, blk, 0, stream>>>(
                v2c ? rp16C : rp16V, v2c ? epC : epV,
                RL, LL, We + (size_t)k * EMB,
                g1 + (size_t)k * EMB, b1 + (size_t)k * EMB,
                AGG, Nr);
        }
        out_kernel<<<NB, blk, 0, stream>>>(AGG, degR, right,
                                           g2 + (size_t)k * EMB, b2 + (size_t)k * EMB,
                                           Wf + (size_t)k * EMB * EMB,
                                           bfp + (size_t)k * EMB,
                                           Wo1 + (size_t)k * EMB * 2 * EMB,
                                           Wo2 + (size_t)k * EMB * EMB,
                                           bo1 + (size_t)k * EMB, bo2 + (size_t)k * EMB,
                                           Nr);
    }
}

// Round 10
// 916.070 us; speedup vs baseline: 2.2017x; 1.0705x over previous
//
#include <hip/hip_runtime.h>

#define EMB   64
#define NCON  50000
#define NVAR  100000
#define NEDGE 1600000
#define EPSLN 1e-5f

// padded-CSR capacities (worst case: every node pads +15)
#define PADEC (NEDGE + 15 * NCON)    // 2,350,000
#define PADEV (NEDGE + 15 * NVAR)    // 3,100,000

// LDS-chunked histogram: 12544 counters/chunk (50 KB LDS), C=4 chunks, V=8.
#define HCHUNK 12544
#define HSEG   32
#define HCHC   4
#define HCHV   8

typedef _Float16 half2_t __attribute__((ext_vector_type(2)));
typedef _Float16 f16x8  __attribute__((ext_vector_type(8)));
typedef float    f32x2  __attribute__((ext_vector_type(2)));
typedef float    f32x4  __attribute__((ext_vector_type(4)));

// ---- wave-total via DPP (no DS ops) ----
template <int CTRL, int RMASK>
__device__ __forceinline__ float dpp_add_f(float x) {
    int m = __builtin_amdgcn_update_dpp(0, __builtin_bit_cast(int, x), CTRL, RMASK, 0xf, true);
    return x + __builtin_bit_cast(float, m);
}
__device__ __forceinline__ float wtotal64(float x) {
    x = dpp_add_f<0x111, 0xf>(x);
    x = dpp_add_f<0x112, 0xf>(x);
    x = dpp_add_f<0x114, 0xf>(x);
    x = dpp_add_f<0x118, 0xf>(x);
    x = dpp_add_f<0x142, 0xa>(x);
    x = dpp_add_f<0x143, 0xc>(x);
    return __builtin_bit_cast(float, __builtin_amdgcn_readlane(__builtin_bit_cast(int, x), 63));
}
template <int CTRL, int RMASK>
__device__ __forceinline__ int dpp_add_i(int x) {
    return x + __builtin_amdgcn_update_dpp(0, x, CTRL, RMASK, 0xf, true);
}
__device__ __forceinline__ int wtotal64_i(int x) {
    x = dpp_add_i<0x111, 0xf>(x);
    x = dpp_add_i<0x112, 0xf>(x);
    x = dpp_add_i<0x114, 0xf>(x);
    x = dpp_add_i<0x118, 0xf>(x);
    x = dpp_add_i<0x142, 0xa>(x);
    x = dpp_add_i<0x143, 0xc>(x);
    return __builtin_amdgcn_readlane(x, 63);
}

__device__ __forceinline__ float dot2f(half2_t a, half2_t b, float c) {
    return __builtin_amdgcn_fdot2(a, b, c, false);
}

__device__ __forceinline__ half2_t hmax2(half2_t a, half2_t b) {
#if defined(__has_builtin) && __has_builtin(__builtin_elementwise_max)
    return __builtin_elementwise_max(a, b);
#else
    half2_t r;
    r.x = a.x > b.x ? a.x : b.x;
    r.y = a.y > b.y ? a.y : b.y;
    return r;
#endif
}

// 8 x ds_read_b128 + 32 x v_dot2 with 4 independent accumulator chains
__device__ __forceinline__ float matvec_f16(const _Float16* __restrict__ buf,
                                            const half2_t* __restrict__ wh, float acc) {
    const float4* hp4 = (const float4*)buf;
    float a0 = acc, a1 = 0.0f, a2 = 0.0f, a3 = 0.0f;
#pragma unroll
    for (int j4 = 0; j4 < 8; ++j4) {
        float4 t = hp4[j4];
        a0 = dot2f(wh[4 * j4 + 0], __builtin_bit_cast(half2_t, t.x), a0);
        a1 = dot2f(wh[4 * j4 + 1], __builtin_bit_cast(half2_t, t.y), a1);
        a2 = dot2f(wh[4 * j4 + 2], __builtin_bit_cast(half2_t, t.z), a2);
        a3 = dot2f(wh[4 * j4 + 3], __builtin_bit_cast(half2_t, t.w), a3);
    }
    return (a0 + a1) + (a2 + a3);
}

__device__ __forceinline__ void load_w_f16(const float* __restrict__ W, int stride,
                                           int lane, half2_t* wh) {
#pragma unroll
    for (int j4 = 0; j4 < 16; ++j4) {
        float4 t = *(const float4*)(W + (size_t)lane * stride + j4 * 4);
        wh[2 * j4 + 0] = half2_t{(_Float16)t.x, (_Float16)t.y};
        wh[2 * j4 + 1] = half2_t{(_Float16)t.z, (_Float16)t.w};
    }
}

__device__ __forceinline__ f16x8 cvt8_f16(float4 u, float4 v) {
    f16x8 r;
    r[0] = (_Float16)u.x; r[1] = (_Float16)u.y; r[2] = (_Float16)u.z; r[3] = (_Float16)u.w;
    r[4] = (_Float16)v.x; r[5] = (_Float16)v.y; r[6] = (_Float16)v.z; r[7] = (_Float16)v.w;
    return r;
}

// ---------------- CSR build ----------------

// LDS-chunked histogram, NO global atomics (round-2: 3.2M device atomicAdds
// = ~31B memory-side partial-sector writes each; 99.7 MB WRITE, 129 us).
// Round-9 counters (92us, VALUBusy 3%, occ 15%): latency-bound — 1.5 blocks/CU
// and one dependent scalar load per ~10cyc of work. Fix: int4 edge loads
// (4 edges/load, 4x work per exposed latency). Segment bounds are multiples
// of 50000 (E%HSEG==0) -> s0%4==0 -> aligned; scalar tail kept for safety.
__global__ __launch_bounds__(256) void hist_part_kernel(
        const int* __restrict__ ci, const int* __restrict__ vi,
        int* __restrict__ partC, int* __restrict__ partV, int E) {
    __shared__ int lh[HCHUNK];
    const int seg  = blockIdx.x % HSEG;
    const int cg   = blockIdx.x / HSEG;
    const bool isC = cg < HCHC;
    const int chunk = isC ? cg : cg - HCHC;
    const int base  = chunk * HCHUNK;
    const int* __restrict__ dst = isC ? ci : vi;
    int* __restrict__ part = (isC ? partC : partV) + (size_t)(chunk * HSEG + seg) * HCHUNK;

    int4* l4 = (int4*)lh;
    for (int i = threadIdx.x; i < HCHUNK / 4; i += 256) l4[i] = make_int4(0, 0, 0, 0);
    __syncthreads();

    const int s0 = (int)((long long)seg * E / HSEG);
    const int s1 = (int)((long long)(seg + 1) * E / HSEG);
    const int nvec = (s1 - s0) >> 2;               // int4 count
    const int4* d4 = (const int4*)(dst + s0);      // s0 % 4 == 0 (E % (4*HSEG) == 0)
    for (int i = threadIdx.x; i < nvec; i += 256) {
        const int4 t = d4[i];
        const unsigned r0 = (unsigned)(t.x - base);
        const unsigned r1 = (unsigned)(t.y - base);
        const unsigned r2 = (unsigned)(t.z - base);
        const unsigned r3 = (unsigned)(t.w - base);
        if (r0 < (unsigned)HCHUNK) atomicAdd(&lh[r0], 1);
        if (r1 < (unsigned)HCHUNK) atomicAdd(&lh[r1], 1);
        if (r2 < (unsigned)HCHUNK) atomicAdd(&lh[r2], 1);
        if (r3 < (unsigned)HCHUNK) atomicAdd(&lh[r3], 1);
    }
    for (int i = s0 + (nvec << 2) + threadIdx.x; i < s1; i += 256) {   // tail (empty when E%128==0)
        const unsigned rel = (unsigned)(dst[i] - base);
        if (rel < (unsigned)HCHUNK) atomicAdd(&lh[rel], 1);
    }
    __syncthreads();
    int4* p4 = (int4*)part;
    for (int i = threadIdx.x; i < HCHUNK / 4; i += 256) p4[i] = l4[i];
}

// sum the HSEG segment-partials per counter -> degC/degV (coalesced reads)
__global__ __launch_bounds__(256) void hist_reduce_kernel(
        const int* __restrict__ partC, const int* __restrict__ partV,
        int* __restrict__ degC, int* __restrict__ degV) {
    int j = blockIdx.x * blockDim.x + threadIdx.x;
    const int tot = NCON + NVAR;
    for (; j < tot; j += gridDim.x * blockDim.x) {
        if (j < NCON) {
            const int chunk = j / HCHUNK, off = j - chunk * HCHUNK;
            const int* p = partC + (size_t)chunk * HSEG * HCHUNK + off;
            int s = 0;
#pragma unroll
            for (int t = 0; t < HSEG; ++t) s += p[(size_t)t * HCHUNK];
            degC[j] = s;
        } else {
            const int jj = j - NCON;
            const int chunk = jj / HCHUNK, off = jj - chunk * HCHUNK;
            const int* p = partV + (size_t)chunk * HSEG * HCHUNK + off;
            int s = 0;
#pragma unroll
            for (int t = 0; t < HSEG; ++t) s += p[(size_t)t * HCHUNK];
            degV[jj] = s;
        }
    }
}

// fallback: atomic histogram (used only if ws can't fit the partials)
__global__ __launch_bounds__(256) void hist2_kernel(
        const int* __restrict__ ci, const int* __restrict__ vi,
        int* __restrict__ degC, int* __restrict__ degV, int E) {
    int i = blockIdx.x * blockDim.x + threadIdx.x;
    for (; i < E; i += gridDim.x * blockDim.x) {
        atomicAdd(&degC[ci[i]], 1);
        atomicAdd(&degV[vi[i]], 1);
    }
}

template <bool PAD>
__global__ __launch_bounds__(256) void chunk_sum_kernel(const int* __restrict__ hist,
                                                        int* __restrict__ csum, int N) {
    __shared__ int wpart[4];
    const int base = blockIdx.x * 1024 + threadIdx.x * 4;
    int s = 0;
    if (base + 3 < N) {
        int4 t = *(const int4*)(hist + base);
        if (PAD) s = ((t.x+15)&~15) + ((t.y+15)&~15) + ((t.z+15)&~15) + ((t.w+15)&~15);
        else     s = t.x + t.y + t.z + t.w;
    } else {
#pragma unroll
        for (int j = 0; j < 4; ++j)
            if (base + j < N) { int v = hist[base + j]; s += PAD ? ((v+15)&~15) : v; }
    }
    s = wtotal64_i(s);
    if ((threadIdx.x & 63) == 0) wpart[threadIdx.x >> 6] = s;
    __syncthreads();
    if (threadIdx.x == 0) csum[blockIdx.x] = wpart[0] + wpart[1] + wpart[2] + wpart[3];
}

__global__ void chunk_offsets_kernel(const int* __restrict__ csum, int* __restrict__ coff,
                                     int* __restrict__ rowptr, int nchunk, int N) {
    const int lane = threadIdx.x;
    int carry = 0;
    for (int base = 0; base < nchunk; base += 64) {
        const int i = base + lane;
        int val = (i < nchunk) ? csum[i] : 0;
        int incl = val;
#pragma unroll
        for (int off = 1; off < 64; off <<= 1) {
            int t = __shfl_up(incl, off, 64);
            if (lane >= off) incl += t;
        }
        if (i < nchunk) coff[i] = incl - val + carry;
        carry += __shfl(incl, 63, 64);
    }
    if (lane == 0) rowptr[N] = carry;
}

template <bool PAD>
__global__ __launch_bounds__(256) void chunk_apply_kernel(
        const int* __restrict__ hist, const int* __restrict__ coff,
        int* __restrict__ rowptr, int* __restrict__ cursor, int N) {
    __shared__ int wpart[4];
    const int wv = threadIdx.x >> 6;
    const int lane = threadIdx.x & 63;
    const int base = blockIdx.x * 1024 + threadIdx.x * 4;
    int v0 = 0, v1 = 0, v2 = 0, v3 = 0;
    if (base + 3 < N) {
        int4 t = *(const int4*)(hist + base);
        v0 = t.x; v1 = t.y; v2 = t.z; v3 = t.w;
    } else {
        if (base + 0 < N) v0 = hist[base + 0];
        if (base + 1 < N) v1 = hist[base + 1];
        if (base + 2 < N) v2 = hist[base + 2];
        if (base + 3 < N) v3 = hist[base + 3];
    }
    if (PAD) { v0 = (v0+15)&~15; v1 = (v1+15)&~15; v2 = (v2+15)&~15; v3 = (v3+15)&~15; }
    const int s = v0 + v1 + v2 + v3;
    int incl = s;
#pragma unroll
    for (int off = 1; off < 64; off <<= 1) {
        int t = __shfl_up(incl, off, 64);
        if (lane >= off) incl += t;
    }
    if (lane == 63) wpart[wv] = incl;
    __syncthreads();
    int excl = coff[blockIdx.x] + incl - s;
    for (int w = 0; w < wv; ++w) excl += wpart[w];
    if (base + 0 < N) { rowptr[base + 0] = excl; cursor[base + 0] = excl; excl += v0; }
    if (base + 1 < N) { rowptr[base + 1] = excl; cursor[base + 1] = excl; excl += v1; }
    if (base + 2 < N) { rowptr[base + 2] = excl; cursor[base + 2] = excl; excl += v2; }
    if (base + 3 < N) { rowptr[base + 3] = excl; cursor[base + 3] = excl; excl += v3; }
}

// XCD-bucketed scatter, ONE direction per launch (round-2 verified: each
// XCD's L2 holds one bucket's CSR region -> write combining).
template <int NDST>
__global__ __launch_bounds__(256) void scatter_dir_kernel(
        const int* __restrict__ dst, const int* __restrict__ src,
        const float* __restrict__ ef,
        int* __restrict__ cur, int2* __restrict__ ep, int E) {
    const int rep = blockIdx.x & 7;
    const int stride = (gridDim.x >> 3) * blockDim.x;
    int i = (blockIdx.x >> 3) * blockDim.x + threadIdx.x;
    for (; i < E; i += stride) {
        const int d = dst[i];
        const int b = (int)(((long long)d * 8) / NDST);
        if (b == rep) {
            const int slot = atomicAdd(&cur[d], 1);
            ep[slot] = make_int2(src[i], __float_as_int(ef[i]));
        }
    }
}

// ---------------- fused node linear via MFMA: Y = X @ W^T (+b) -> f16 ----------------
// Round-8 validated layouts on HW (absmax unchanged):
//   A-frag: lane l holds X[n0+(l&15)][kc*32+(l>>4)*8+j]
//   B-frag: lane l holds W[ct*16+(l&15)][kc*32+(l>>4)*8+j]
//   D:      lane l, reg r -> row (l>>4)*4+r, col l&15 (+16*ct)

__global__ __launch_bounds__(256, 3) void lin2_kernel(
        const float* __restrict__ XR, const float* __restrict__ WR,
        const float* __restrict__ bR, _Float16* __restrict__ YR, int NR,
        const float* __restrict__ XL, const float* __restrict__ WL,
        _Float16* __restrict__ YL, int NL, int nbR) {
    const int wv   = threadIdx.x >> 6;
    const int lane = threadIdx.x & 63;
    const int col  = lane & 15;
    const int kgrp = lane >> 4;           // 0..3
    const bool isR = (int)blockIdx.x < nbR;
    const float* X = isR ? XR : XL;
    const float* W = isR ? WR : WL;
    _Float16* Y    = isR ? YR : YL;
    const int N    = isR ? NR : NL;
    const int b0   = isR ? 0 : nbR;
    const int nb   = isR ? nbR : (gridDim.x - nbR);

    f16x8 bf[4][2];
#pragma unroll
    for (int ct = 0; ct < 4; ++ct)
#pragma unroll
        for (int kc = 0; kc < 2; ++kc) {
            const float* wrow = W + (size_t)(ct * 16 + col) * EMB + kc * 32 + kgrp * 8;
            bf[ct][kc] = cvt8_f16(*(const float4*)wrow, *(const float4*)(wrow + 4));
        }
    float bias[4];
#pragma unroll
    for (int ct = 0; ct < 4; ++ct) bias[ct] = isR ? bR[ct * 16 + col] : 0.0f;

    const int ntile = (N + 15) >> 4;
    const int nW = nb * 4;
    for (int t = ((int)blockIdx.x - b0) * 4 + wv; t < ntile; t += nW) {
        const int n0 = t << 4;
        const int srow = min(n0 + col, N - 1);
        const float* xrow = X + (size_t)srow * EMB + kgrp * 8;
        const float4 x0 = *(const float4*)(xrow);
        const float4 x1 = *(const float4*)(xrow + 4);
        const float4 x2 = *(const float4*)(xrow + 32);
        const float4 x3 = *(const float4*)(xrow + 36);
        const f16x8 a0 = cvt8_f16(x0, x1);
        const f16x8 a1 = cvt8_f16(x2, x3);
        f32x4 acc[4];
#pragma unroll
        for (int ct = 0; ct < 4; ++ct) {
            acc[ct] = __builtin_amdgcn_mfma_f32_16x16x32_f16(
                a0, bf[ct][0], (f32x4){0.0f, 0.0f, 0.0f, 0.0f}, 0, 0, 0);
            acc[ct] = __builtin_amdgcn_mfma_f32_16x16x32_f16(
                a1, bf[ct][1], acc[ct], 0, 0, 0);
        }
#pragma unroll
        for (int r = 0; r < 4; ++r) {
            const int n = n0 + (kgrp << 2) + r;
            if (n < N) {
                _Float16* yrow = Y + (size_t)n * EMB + col;
#pragma unroll
                for (int ct = 0; ct < 4; ++ct)
                    yrow[ct * 16] = (_Float16)(acc[ct][r] + bias[ct]);
            }
        }
    }
}

// ---------------- edge stage: wave per node, abar accumulate ----------------
// Key identity: sum_e relu(LN(h_e)) @ Wf^T = (sum_e relu(LN(h_e))) @ Wf^T.
// (256,4) spill-free since round-7 moved the Wf matvec out (round-6 model:
// VGPR budget ~256/arg). LDS-transpose reduce + cross-node pipeline.

__global__ __launch_bounds__(256, 4) void edge_abar_kernel(
        const int* __restrict__ rp16, const int* __restrict__ deg,
        const int2* __restrict__ ep,
        const _Float16* __restrict__ RL, const _Float16* __restrict__ LL,
        const float* __restrict__ We, const float* __restrict__ g1,
        const float* __restrict__ b1, _Float16* __restrict__ ABAR, int Nr) {
    __shared__ __align__(16) float tbuf[4][16][68];   // [wave][col][k] padded stride
    const int wv   = threadIdx.x >> 6;
    const int lane = threadIdx.x & 63;
    const int col  = lane & 15;
    const int quad = lane >> 4;
    const int kb   = quad * 8;

    half2_t weh[8], gkh[8], bkh[8];
#pragma unroll
    for (int j = 0; j < 4; ++j) {
        weh[j]     = half2_t{(_Float16)We[kb + 2*j],      (_Float16)We[kb + 2*j + 1]};
        weh[4 + j] = half2_t{(_Float16)We[kb + 32 + 2*j], (_Float16)We[kb + 32 + 2*j + 1]};
        gkh[j]     = half2_t{(_Float16)g1[kb + 2*j],      (_Float16)g1[kb + 2*j + 1]};
        gkh[4 + j] = half2_t{(_Float16)g1[kb + 32 + 2*j], (_Float16)g1[kb + 32 + 2*j + 1]};
        bkh[j]     = half2_t{(_Float16)b1[kb + 2*j],      (_Float16)b1[kb + 2*j + 1]};
        bkh[4 + j] = half2_t{(_Float16)b1[kb + 32 + 2*j], (_Float16)b1[kb + 32 + 2*j + 1]};
    }

    const int nW = gridDim.x * 4;
    int n = blockIdx.x * 4 + wv;          // Nr >= 50000 > grid*4, so n < Nr here
    int pg0 = rp16[n] >> 4;
    int pg1 = rp16[n + 1] >> 4;
    int pdn = deg[n];

    bool livN = false; float fN = 0.0f;
    f16x8 llaN = {}, llbN = {};
    auto issue_group = [&](int gbase, int cnt) {
        livN = col < cnt;
        int2 p = ep[(gbase << 4) + col];
        const int s2 = livN ? p.x : 0;
        fN = livN ? __int_as_float(p.y) : 0.0f;
        llaN = *(const f16x8*)(LL + (size_t)s2 * EMB + kb);
        llbN = *(const f16x8*)(LL + (size_t)s2 * EMB + kb + 32);
    };
    if (pg0 < pg1) issue_group(pg0, pdn);     // prime first node's first group

    while (true) {
        const int g0 = pg0, g1e = pg1, dn = pdn;
        const int nn = n + nW;
        const bool hasNext = nn < Nr;
        if (hasNext) {                         // issue next node's meta EARLY
            pg0 = rp16[nn] >> 4;
            pg1 = rp16[nn + 1] >> 4;
            pdn = deg[nn];
        }

        half2_t rl2[8];
        *(f16x8*)&rl2[0] = *(const f16x8*)(RL + (size_t)n * EMB + kb);
        *(f16x8*)&rl2[4] = *(const f16x8*)(RL + (size_t)n * EMB + kb + 32);

        f32x2 acc2[8];
#pragma unroll
        for (int j = 0; j < 8; ++j) acc2[j] = f32x2{0.0f, 0.0f};

        bool didNext = false;
        for (int g = g0; g < g1e; ++g) {
            const bool liv = livN;
            const float f = fN;
            half2_t h2[8];
            *(f16x8*)&h2[0] = llaN;
            *(f16x8*)&h2[4] = llbN;
            if (g + 1 < g1e) {
                issue_group(g + 1, dn - ((g + 1 - g0) << 4));   // in-node prefetch
            } else if (hasNext && pg0 < pg1) {
                issue_group(pg0, pdn);                           // next-node prefetch
                didNext = true;
            }
            const _Float16 fh = (_Float16)f;
            const half2_t f2 = half2_t{fh, fh};
            const half2_t one2 = half2_t{(_Float16)1.0f, (_Float16)1.0f};
            float ps = 0.0f, pq = 0.0f;
#pragma unroll
            for (int j = 0; j < 8; ++j) {
                h2[j] = (h2[j] + rl2[j]) + f2 * weh[j];
                ps = dot2f(h2[j], one2, ps);
                pq = dot2f(h2[j], h2[j], pq);
            }
            ps += __shfl_xor(ps, 16, 64); ps += __shfl_xor(ps, 32, 64);
            pq += __shfl_xor(pq, 16, 64); pq += __shfl_xor(pq, 32, 64);
            const float mean = ps * (1.0f / EMB);
            const float var  = pq * (1.0f / EMB) - mean * mean;
            const float rs   = rsqrtf(var + EPSLN);
            const _Float16 rsh = (_Float16)rs;
            const _Float16 mnh = (_Float16)mean;
            const half2_t rs2 = half2_t{rsh, rsh};
            const half2_t mn2 = half2_t{mnh, mnh};
            const half2_t z2  = half2_t{(_Float16)0.0f, (_Float16)0.0f};
            if (liv) {
#pragma unroll
                for (int j = 0; j < 8; ++j) {
                    const half2_t sc = gkh[j] * rs2;
                    half2_t a = (h2[j] - mn2) * sc + bkh[j];
                    a = hmax2(a, z2);
                    f32x2 cv; cv.x = (float)a.x; cv.y = (float)a.y;
                    acc2[j] += cv;
                }
            }
        }

        // ---- LDS-transpose reduce ----
        float* tb = &tbuf[wv][col][0];
        *(float4*)(tb + kb)      = make_float4(acc2[0].x, acc2[0].y, acc2[1].x, acc2[1].y);
        *(float4*)(tb + kb + 4)  = make_float4(acc2[2].x, acc2[2].y, acc2[3].x, acc2[3].y);
        *(float4*)(tb + kb + 32) = make_float4(acc2[4].x, acc2[4].y, acc2[5].x, acc2[5].y);
        *(float4*)(tb + kb + 36) = make_float4(acc2[6].x, acc2[6].y, acc2[7].x, acc2[7].y);
        float t0[16];
#pragma unroll
        for (int c2 = 0; c2 < 16; ++c2) t0[c2] = tbuf[wv][c2][lane];
        const float s01 = (t0[0] + t0[1]) + (t0[2] + t0[3]);
        const float s23 = (t0[4] + t0[5]) + (t0[6] + t0[7]);
        const float s45 = (t0[8] + t0[9]) + (t0[10] + t0[11]);
        const float s67 = (t0[12] + t0[13]) + (t0[14] + t0[15]);
        ABAR[(size_t)n * EMB + lane] = (_Float16)((s01 + s23) + (s45 + s67));

        if (!hasNext) break;
        if (!didNext && pg0 < pg1) issue_group(pg0, pdn);   // zero-group edge cases
        n = nn;
    }
}

// ---------------- fallback edge path (wave per node, abar accumulate) ----------------

__global__ __launch_bounds__(256, 4) void edge_csr_kernel(
        const int* __restrict__ rowptr, const int2* __restrict__ ep,
        const _Float16* __restrict__ RL, const _Float16* __restrict__ LL,
        const float* __restrict__ Wecol, const float* __restrict__ g1,
        const float* __restrict__ b1,
        _Float16* __restrict__ ABAR, int Nr) {
    const int lane = threadIdx.x & 63;
    const float we  = Wecol[lane];
    const float g   = g1[lane];
    const float bb  = b1[lane];
    const int nW = gridDim.x * 4;
    for (int n = blockIdx.x * 4 + (threadIdx.x >> 6); n < Nr; n += nW) {
        const int beg = rowptr[n];
        const int end = rowptr[n + 1];
        const float rl = (float)RL[(size_t)n * EMB + lane];
        float acc = 0.0f;
        for (int idx = beg; idx < end; ++idx) {
            const int2 p = ep[idx];
            const float f = __int_as_float(p.y);
            float h = rl + (float)LL[(size_t)p.x * EMB + lane] + f * we;
            const float s1 = wtotal64(h);
            const float s2 = wtotal64(h * h);
            const float m   = s1 * (1.0f / EMB);
            const float var = s2 * (1.0f / EMB) - m * m;
            acc += fmaxf((h - m) * rsqrtf(var + EPSLN) * g + bb, 0.0f);
        }
        ABAR[(size_t)n * EMB + lane] = (_Float16)acc;
    }
}

// ---------------- fused output MLP via MFMA ----------------
// Per 16-node tile, 3 chained GEMMs (24 MFMA): agg=abar@Wf^T+deg*bf ->
// rowwise LN in D-layout (4-step shfl_xor over the 16-lane row group) ->
// o=relu(z@Wo1a^T+right@Wo1b^T+bo1) (z via LDS D->A transpose) ->
// right+=o@Wo2^T+bo2. LDS [16][72] f16 keeps 16B alignment, 2-way bank
// aliasing (free). ~180 VGPR -> (256,1), spill-free per round-6 model.

__global__ __launch_bounds__(256, 1) void out_kernel(
        const _Float16* __restrict__ ABAR, const int* __restrict__ deg,
        float* __restrict__ right,
        const float* __restrict__ g2, const float* __restrict__ b2,
        const float* __restrict__ Wf, const float* __restrict__ bfp,
        const float* __restrict__ Wo1, const float* __restrict__ Wo2,
        const float* __restrict__ bo1, const float* __restrict__ bo2, int N) {
    __shared__ __align__(16) _Float16 zt[4][16][72];
    __shared__ __align__(16) _Float16 ot[4][16][72];
    const int wv   = threadIdx.x >> 6;
    const int lane = threadIdx.x & 63;
    const int col  = lane & 15;
    const int kgrp = lane >> 4;

    f16x8 bF[4][2], b1a[4][2], b1b[4][2], b2f[4][2];
#pragma unroll
    for (int ct = 0; ct < 4; ++ct)
#pragma unroll
        for (int kc = 0; kc < 2; ++kc) {
            const int row = ct * 16 + col;
            const int ko  = kc * 32 + kgrp * 8;
            const float* wf = Wf  + (size_t)row * EMB + ko;
            const float* w1 = Wo1 + (size_t)row * 2 * EMB + ko;
            const float* w2 = Wo2 + (size_t)row * EMB + ko;
            bF[ct][kc]  = cvt8_f16(*(const float4*)wf, *(const float4*)(wf + 4));
            b1a[ct][kc] = cvt8_f16(*(const float4*)w1, *(const float4*)(w1 + 4));
            b1b[ct][kc] = cvt8_f16(*(const float4*)(w1 + EMB), *(const float4*)(w1 + EMB + 4));
            b2f[ct][kc] = cvt8_f16(*(const float4*)w2, *(const float4*)(w2 + 4));
        }
    float bfc[4], gc[4], bbc[4], bo1c[4], bo2c[4];
#pragma unroll
    for (int ct = 0; ct < 4; ++ct) {
        const int cd = ct * 16 + col;
        bfc[ct]  = bfp[cd];
        gc[ct]   = g2[cd];
        bbc[ct]  = b2[cd];
        bo1c[ct] = bo1[cd];
        bo2c[ct] = bo2[cd];
    }

    const int ntile = N >> 4;          // N % 16 == 0
    const int nW = gridDim.x * 4;
    for (int t = blockIdx.x * 4 + wv; t < ntile; t += nW) {
        const int n0 = t << 4;
        // ---- GEMM1: agg = abar @ Wf^T ----
        const _Float16* arow = ABAR + (size_t)(n0 + col) * EMB + kgrp * 8;
        const f16x8 aA0 = *(const f16x8*)(arow);
        const f16x8 aA1 = *(const f16x8*)(arow + 32);
        f32x4 acc[4];
#pragma unroll
        for (int ct = 0; ct < 4; ++ct) {
            acc[ct] = __builtin_amdgcn_mfma_f32_16x16x32_f16(
                aA0, bF[ct][0], (f32x4){0.0f, 0.0f, 0.0f, 0.0f}, 0, 0, 0);
            acc[ct] = __builtin_amdgcn_mfma_f32_16x16x32_f16(
                aA1, bF[ct][1], acc[ct], 0, 0, 0);
        }
        // deg for my 4 rows
        float dnr[4];
#pragma unroll
        for (int r = 0; r < 4; ++r) dnr[r] = (float)deg[n0 + (kgrp << 2) + r];
        // ---- rowwise LN in D-layout ----
#pragma unroll
        for (int r = 0; r < 4; ++r) {
            float s1 = 0.0f, s2 = 0.0f;
#pragma unroll
            for (int ct = 0; ct < 4; ++ct) {
                const float a = acc[ct][r] + dnr[r] * bfc[ct];
                acc[ct][r] = a;
                s1 += a; s2 += a * a;
            }
            s1 += __shfl_xor(s1, 1, 64); s2 += __shfl_xor(s2, 1, 64);
            s1 += __shfl_xor(s1, 2, 64); s2 += __shfl_xor(s2, 2, 64);
            s1 += __shfl_xor(s1, 4, 64); s2 += __shfl_xor(s2, 4, 64);
            s1 += __shfl_xor(s1, 8, 64); s2 += __shfl_xor(s2, 8, 64);
            const float mean = s1 * (1.0f / EMB);
            const float var  = s2 * (1.0f / EMB) - mean * mean;
            const float rs   = rsqrtf(var + EPSLN);
            const int zr = (kgrp << 2) + r;
#pragma unroll
            for (int ct = 0; ct < 4; ++ct)
                zt[wv][zr][ct * 16 + col] =
                    (_Float16)((acc[ct][r] - mean) * rs * gc[ct] + bbc[ct]);
        }
        // ---- GEMM3: o = relu(z@Wo1a^T + right@Wo1b^T + bo1) ----
        const _Float16* zrow = &zt[wv][col][kgrp * 8];
        const f16x8 zA0 = *(const f16x8*)(zrow);
        const f16x8 zA1 = *(const f16x8*)(zrow + 32);
        const float* rrow = right + (size_t)(n0 + col) * EMB + kgrp * 8;
        const f16x8 rA0 = cvt8_f16(*(const float4*)(rrow), *(const float4*)(rrow + 4));
        const f16x8 rA1 = cvt8_f16(*(const float4*)(rrow + 32), *(const float4*)(rrow + 36));
        f32x4 acc3[4];
#pragma unroll
        for (int ct = 0; ct < 4; ++ct) {
            acc3[ct] = __builtin_amdgcn_mfma_f32_16x16x32_f16(
                zA0, b1a[ct][0], (f32x4){0.0f, 0.0f, 0.0f, 0.0f}, 0, 0, 0);
            acc3[ct] = __builtin_amdgcn_mfma_f32_16x16x32_f16(
                zA1, b1a[ct][1], acc3[ct], 0, 0, 0);
            acc3[ct] = __builtin_amdgcn_mfma_f32_16x16x32_f16(
                rA0, b1b[ct][0], acc3[ct], 0, 0, 0);
            acc3[ct] = __builtin_amdgcn_mfma_f32_16x16x32_f16(
                rA1, b1b[ct][1], acc3[ct], 0, 0, 0);
        }
#pragma unroll
        for (int r = 0; r < 4; ++r) {
            const int orr = (kgrp << 2) + r;
#pragma unroll
            for (int ct = 0; ct < 4; ++ct)
                ot[wv][orr][ct * 16 + col] =
                    (_Float16)fmaxf(acc3[ct][r] + bo1c[ct], 0.0f);
        }
        // ---- GEMM4: right += o@Wo2^T + bo2 ----
        const _Float16* orow = &ot[wv][col][kgrp * 8];
        const f16x8 oA0 = *(const f16x8*)(orow);
        const f16x8 oA1 = *(const f16x8*)(orow + 32);
        f32x4 acc4[4];
#pragma unroll
        for (int ct = 0; ct < 4; ++ct) {
            acc4[ct] = __builtin_amdgcn_mfma_f32_16x16x32_f16(
                oA0, b2f[ct][0], (f32x4){0.0f, 0.0f, 0.0f, 0.0f}, 0, 0, 0);
            acc4[ct] = __builtin_amdgcn_mfma_f32_16x16x32_f16(
                oA1, b2f[ct][1], acc4[ct], 0, 0, 0);
        }
#pragma unroll
        for (int r = 0; r < 4; ++r) {
            float* rr = right + (size_t)(n0 + (kgrp << 2) + r) * EMB + col;
#pragma unroll
            for (int ct = 0; ct < 4; ++ct)
                rr[ct * 16] += acc4[ct][r] + bo2c[ct];
        }
    }
}

extern "C" void kernel_launch(void* const* d_in, const int* in_sizes, int n_in,
                              void* d_out, int out_size, void* d_ws, size_t ws_size,
                              hipStream_t stream) {
    const float* cf  = (const float*)d_in[0];
    const float* vfp = (const float*)d_in[1];
    const int*   ei  = (const int*)d_in[2];
    const float* ef  = (const float*)d_in[3];
    const float* Wl  = (const float*)d_in[4];
    const float* bl  = (const float*)d_in[5];
    const float* We  = (const float*)d_in[6];
    const float* Wr  = (const float*)d_in[7];
    const float* g1  = (const float*)d_in[8];
    const float* b1  = (const float*)d_in[9];
    const float* Wf  = (const float*)d_in[10];
    const float* bfp = (const float*)d_in[11];
    const float* g2  = (const float*)d_in[12];
    const float* b2  = (const float*)d_in[13];
    const float* Wo1 = (const float*)d_in[14];
    const float* bo1 = (const float*)d_in[15];
    const float* Wo2 = (const float*)d_in[16];
    const float* bo2 = (const float*)d_in[17];

    float* c = (float*)d_out;
    float* v = c + (size_t)NCON * EMB;
    (void)hipMemcpyAsync(c, cf,  (size_t)NCON * EMB * sizeof(float), hipMemcpyDeviceToDevice, stream);
    (void)hipMemcpyAsync(v, vfp, (size_t)NVAR * EMB * sizeof(float), hipMemcpyDeviceToDevice, stream);

    float* wsf = (float*)d_ws;
    size_t off = 0;
    _Float16* AGG = (_Float16*)(wsf + off); off += (size_t)NVAR * EMB / 2;  // f16 (abar)
    _Float16* RL  = (_Float16*)(wsf + off); off += (size_t)NVAR * EMB / 2;  // f16
    _Float16* LL  = (_Float16*)(wsf + off); off += (size_t)NVAR * EMB / 2;  // f16
    int* degC  = (int*)(wsf + off); off += NCON;
    int* degV  = (int*)(wsf + off); off += NVAR;
    int* rp16C = (int*)(wsf + off); off += NCON + 4;
    int* curC  = (int*)(wsf + off); off += NCON;
    int* rp16V = (int*)(wsf + off); off += NVAR + 4;
    int* curV  = (int*)(wsf + off); off += NVAR;
    int* csumC = (int*)(wsf + off); off += 128;
    int* coffC = (int*)(wsf + off); off += 128;
    int* csumV = (int*)(wsf + off); off += 128;
    int* coffV = (int*)(wsf + off); off += 128;
    size_t off_edges = off;
    int2* epC = (int2*)(wsf + off); off += (size_t)2 * PADEC;
    int2* epV = (int2*)(wsf + off); off += (size_t)2 * PADEV;
    const bool use_mfma = ws_size >= off * sizeof(float);
    // histogram partials (19.3 MB) after the edge arrays
    int* partC = (int*)(wsf + off); off += (size_t)HCHC * HSEG * HCHUNK;
    int* partV = (int*)(wsf + off); off += (size_t)HCHV * HSEG * HCHUNK;
    const bool use_ldshist = use_mfma && ws_size >= off * sizeof(float);
    if (!use_mfma) {
        off = off_edges;
        epC = (int2*)(wsf + off); off += (size_t)2 * NEDGE;
        epV = (int2*)(wsf + off); off += (size_t)2 * NEDGE;
    }

    const int* ci = ei;
    const int* vi = ei + NEDGE;

    const dim3 blk(256);
    const int NB = 2048;
    const int NBL = 1536;
    const int nchC = (NCON + 1023) / 1024;   // 49
    const int nchV = (NVAR + 1023) / 1024;   // 98

    if (use_ldshist) {
        hist_part_kernel<<<(HCHC + HCHV) * HSEG, blk, 0, stream>>>(ci, vi, partC, partV, NEDGE);
        hist_reduce_kernel<<<640, blk, 0, stream>>>(partC, partV, degC, degV);
    } else {
        (void)hipMemsetAsync(degC, 0, NCON * sizeof(int), stream);
        (void)hipMemsetAsync(degV, 0, NVAR * sizeof(int), stream);
        hist2_kernel<<<1024, blk, 0, stream>>>(ci, vi, degC, degV, NEDGE);
    }
    if (use_mfma) {
        chunk_sum_kernel<true><<<nchC, blk, 0, stream>>>(degC, csumC, NCON);
        chunk_sum_kernel<true><<<nchV, blk, 0, stream>>>(degV, csumV, NVAR);
        chunk_offsets_kernel<<<1, 64, 0, stream>>>(csumC, coffC, rp16C, nchC, NCON);
        chunk_offsets_kernel<<<1, 64, 0, stream>>>(csumV, coffV, rp16V, nchV, NVAR);
        chunk_apply_kernel<true><<<nchC, blk, 0, stream>>>(degC, coffC, rp16C, curC, NCON);
        chunk_apply_kernel<true><<<nchV, blk, 0, stream>>>(degV, coffV, rp16V, curV, NVAR);
    } else {
        chunk_sum_kernel<false><<<nchC, blk, 0, stream>>>(degC, csumC, NCON);
        chunk_sum_kernel<false><<<nchV, blk, 0, stream>>>(degV, csumV, NVAR);
        chunk_offsets_kernel<<<1, 64, 0, stream>>>(csumC, coffC, rp16C, nchC, NCON);
        chunk_offsets_kernel<<<1, 64, 0, stream>>>(csumV, coffV, rp16V, nchV, NVAR);
        chunk_apply_kernel<false><<<nchC, blk, 0, stream>>>(degC, coffC, rp16C, curC, NCON);
        chunk_apply_kernel<false><<<nchV, blk, 0, stream>>>(degV, coffV, rp16V, curV, NVAR);
    }
    // one direction per launch: hard temporal separation so each XCD's L2
    // holds only that direction's bucket region (C: 2.35 MB, V: 3.1 MB).
    scatter_dir_kernel<NCON><<<2048, blk, 0, stream>>>(ci, vi, ef, curC, epC, NEDGE);
    scatter_dir_kernel<NVAR><<<2048, blk, 0, stream>>>(vi, ci, ef, curV, epV, NEDGE);

    for (int k = 0; k < 4; ++k) {
        const bool v2c = ((k & 1) == 0);
        float* right   = v2c ? c : v;
        float* left    = v2c ? v : c;
        const int Nr   = v2c ? NCON : NVAR;
        const int Nl   = v2c ? NVAR : NCON;
        const int nbR  = v2c ? NBL / 3 : 2 * NBL / 3;   // split blocks ~ Nr : Nl
        const int* degR = v2c ? degC : degV;

        lin2_kernel<<<NBL, blk, 0, stream>>>(
            right, Wl + (size_t)k * EMB * EMB, bl + (size_t)k * EMB, RL, Nr,
            left,  Wr + (size_t)k * EMB * EMB, LL, Nl, nbR);

        if (use_mfma) {
            edge_abar_kernel<<<NB, blk, 0, stream>>>(
                v2c ? rp16C : rp16V, degR, v2c ? epC : epV,
                RL, LL, We + (size_t)k * EMB,
                g1 + (size_t)k * EMB, b1 + (size_t)k * EMB,
                AGG, Nr);
        } else {
            edge_csr_kernel<<<NB, blk, 0, stream>>>(
                v2c ? rp16C : rp16V, v2c ? epC : epV,
                RL, LL, We + (size_t)k * EMB,
                g1 + (size_t)k * EMB, b1 + (size_t)k * EMB,
                AGG, Nr);
        }
        out_kernel<<<NB, blk, 0, stream>>>(AGG, degR, right,
                                           g2 + (size_t)k * EMB, b2 + (size_t)k * EMB,
                                           Wf + (size_t)k * EMB * EMB,
                                           bfp + (size_t)k * EMB,
                                           Wo1 + (size_t)k * EMB * 2 * EMB,
                                           Wo2 + (size_t)k * EMB * EMB,
                                           bo1 + (size_t)k * EMB, bo2 + (size_t)k * EMB,
                                           Nr);
    }
}

// Round 11
// 907.368 us; speedup vs baseline: 2.2228x; 1.0096x over previous
//
#include <hip/hip_runtime.h>

#define EMB   64
#define NCON  50000
#define NVAR  100000
#define NEDGE 1600000
#define EPSLN 1e-5f

// padded-CSR capacities (worst case: every node pads +15)
#define PADEC (NEDGE + 15 * NCON)    // 2,350,000
#define PADEV (NEDGE + 15 * NVAR)    // 3,100,000

// chunked histogram / scatter: 20 C-chunks x 2500 nodes, 20 V-chunks x 5000,
// 32 edge-segments. 40 chunk-groups x 32 segs = 1280 blocks; 40%8==0 so
// chunk cg always lands on XCD cg&7 (all segs of a chunk share one L2).
#define HSEG 32
#define NCHC 20
#define CHNC 2500
#define NCHV 20
#define CHNV 5000

typedef _Float16 half2_t __attribute__((ext_vector_type(2)));
typedef _Float16 f16x8  __attribute__((ext_vector_type(8)));
typedef float    f32x2  __attribute__((ext_vector_type(2)));
typedef float    f32x4  __attribute__((ext_vector_type(4)));

// ---- wave-total via DPP (no DS ops) ----
template <int CTRL, int RMASK>
__device__ __forceinline__ float dpp_add_f(float x) {
    int m = __builtin_amdgcn_update_dpp(0, __builtin_bit_cast(int, x), CTRL, RMASK, 0xf, true);
    return x + __builtin_bit_cast(float, m);
}
__device__ __forceinline__ float wtotal64(float x) {
    x = dpp_add_f<0x111, 0xf>(x);
    x = dpp_add_f<0x112, 0xf>(x);
    x = dpp_add_f<0x114, 0xf>(x);
    x = dpp_add_f<0x118, 0xf>(x);
    x = dpp_add_f<0x142, 0xa>(x);
    x = dpp_add_f<0x143, 0xc>(x);
    return __builtin_bit_cast(float, __builtin_amdgcn_readlane(__builtin_bit_cast(int, x), 63));
}
template <int CTRL, int RMASK>
__device__ __forceinline__ int dpp_add_i(int x) {
    return x + __builtin_amdgcn_update_dpp(0, x, CTRL, RMASK, 0xf, true);
}
__device__ __forceinline__ int wtotal64_i(int x) {
    x = dpp_add_i<0x111, 0xf>(x);
    x = dpp_add_i<0x112, 0xf>(x);
    x = dpp_add_i<0x114, 0xf>(x);
    x = dpp_add_i<0x118, 0xf>(x);
    x = dpp_add_i<0x142, 0xa>(x);
    x = dpp_add_i<0x143, 0xc>(x);
    return __builtin_amdgcn_readlane(x, 63);
}

__device__ __forceinline__ float dot2f(half2_t a, half2_t b, float c) {
    return __builtin_amdgcn_fdot2(a, b, c, false);
}

__device__ __forceinline__ half2_t hmax2(half2_t a, half2_t b) {
#if defined(__has_builtin) && __has_builtin(__builtin_elementwise_max)
    return __builtin_elementwise_max(a, b);
#else
    half2_t r;
    r.x = a.x > b.x ? a.x : b.x;
    r.y = a.y > b.y ? a.y : b.y;
    return r;
#endif
}

// 8 x ds_read_b128 + 32 x v_dot2 with 4 independent accumulator chains
__device__ __forceinline__ float matvec_f16(const _Float16* __restrict__ buf,
                                            const half2_t* __restrict__ wh, float acc) {
    const float4* hp4 = (const float4*)buf;
    float a0 = acc, a1 = 0.0f, a2 = 0.0f, a3 = 0.0f;
#pragma unroll
    for (int j4 = 0; j4 < 8; ++j4) {
        float4 t = hp4[j4];
        a0 = dot2f(wh[4 * j4 + 0], __builtin_bit_cast(half2_t, t.x), a0);
        a1 = dot2f(wh[4 * j4 + 1], __builtin_bit_cast(half2_t, t.y), a1);
        a2 = dot2f(wh[4 * j4 + 2], __builtin_bit_cast(half2_t, t.z), a2);
        a3 = dot2f(wh[4 * j4 + 3], __builtin_bit_cast(half2_t, t.w), a3);
    }
    return (a0 + a1) + (a2 + a3);
}

__device__ __forceinline__ void load_w_f16(const float* __restrict__ W, int stride,
                                           int lane, half2_t* wh) {
#pragma unroll
    for (int j4 = 0; j4 < 16; ++j4) {
        float4 t = *(const float4*)(W + (size_t)lane * stride + j4 * 4);
        wh[2 * j4 + 0] = half2_t{(_Float16)t.x, (_Float16)t.y};
        wh[2 * j4 + 1] = half2_t{(_Float16)t.z, (_Float16)t.w};
    }
}

__device__ __forceinline__ f16x8 cvt8_f16(float4 u, float4 v) {
    f16x8 r;
    r[0] = (_Float16)u.x; r[1] = (_Float16)u.y; r[2] = (_Float16)u.z; r[3] = (_Float16)u.w;
    r[4] = (_Float16)v.x; r[5] = (_Float16)v.y; r[6] = (_Float16)v.z; r[7] = (_Float16)v.w;
    return r;
}

// ---------------- CSR build ----------------

// LDS-chunked histogram, NO global atomics (round-2: device atomics cost
// ~31B memory-side write each at ~25G/s). Round-10 falsifier resolved:
// 1280 blocks (was 384) + 20KB LDS (was 50KB) for occupancy; int4 scans.
__global__ __launch_bounds__(256) void hist_part_kernel(
        const int* __restrict__ ci, const int* __restrict__ vi,
        int* __restrict__ partC, int* __restrict__ partV, int E) {
    __shared__ int lh[CHNV];
    const int cg  = blockIdx.x % (NCHC + NCHV);
    const int seg = blockIdx.x / (NCHC + NCHV);
    const bool isC = cg < NCHC;
    const int chunk  = isC ? cg : cg - NCHC;
    const int chunkN = isC ? CHNC : CHNV;
    const int base   = chunk * chunkN;
    const int* __restrict__ dst = isC ? ci : vi;
    int* __restrict__ part = (isC ? partC : partV) + (size_t)(chunk * HSEG + seg) * chunkN;

    int4* l4 = (int4*)lh;
    for (int i = threadIdx.x; i < chunkN / 4; i += 256) l4[i] = make_int4(0, 0, 0, 0);
    __syncthreads();

    const int s0 = (int)((long long)seg * E / HSEG);
    const int s1 = (int)((long long)(seg + 1) * E / HSEG);
    const int nvec = (s1 - s0) >> 2;
    const int4* d4 = (const int4*)(dst + s0);      // s0 % 4 == 0
    for (int i = threadIdx.x; i < nvec; i += 256) {
        const int4 t = d4[i];
        const unsigned r0 = (unsigned)(t.x - base);
        const unsigned r1 = (unsigned)(t.y - base);
        const unsigned r2 = (unsigned)(t.z - base);
        const unsigned r3 = (unsigned)(t.w - base);
        if (r0 < (unsigned)chunkN) atomicAdd(&lh[r0], 1);
        if (r1 < (unsigned)chunkN) atomicAdd(&lh[r1], 1);
        if (r2 < (unsigned)chunkN) atomicAdd(&lh[r2], 1);
        if (r3 < (unsigned)chunkN) atomicAdd(&lh[r3], 1);
    }
    for (int i = s0 + (nvec << 2) + threadIdx.x; i < s1; i += 256) {
        const unsigned rel = (unsigned)(dst[i] - base);
        if (rel < (unsigned)chunkN) atomicAdd(&lh[rel], 1);
    }
    __syncthreads();
    int4* p4 = (int4*)part;
    for (int i = threadIdx.x; i < chunkN / 4; i += 256) p4[i] = l4[i];
}

// sum the HSEG segment-partials per counter -> degC/degV (coalesced reads)
__global__ __launch_bounds__(256) void hist_reduce_kernel(
        const int* __restrict__ partC, const int* __restrict__ partV,
        int* __restrict__ degC, int* __restrict__ degV) {
    int j = blockIdx.x * blockDim.x + threadIdx.x;
    const int tot = NCON + NVAR;
    for (; j < tot; j += gridDim.x * blockDim.x) {
        if (j < NCON) {
            const int chunk = j / CHNC, off = j - chunk * CHNC;
            const int* p = partC + (size_t)chunk * HSEG * CHNC + off;
            int s = 0;
#pragma unroll
            for (int t = 0; t < HSEG; ++t) s += p[(size_t)t * CHNC];
            degC[j] = s;
        } else {
            const int jj = j - NCON;
            const int chunk = jj / CHNV, off = jj - chunk * CHNV;
            const int* p = partV + (size_t)chunk * HSEG * CHNV + off;
            int s = 0;
#pragma unroll
            for (int t = 0; t < HSEG; ++t) s += p[(size_t)t * CHNV];
            degV[jj] = s;
        }
    }
}

// convert per-(chunk,seg) counts into per-(chunk,seg) STARTING CURSORS:
// part[chunk][seg][i] = rp16[node] + sum_{t<seg} count[chunk][t][i].
// This makes scatter slot assignment deterministic -> zero global atomics.
__global__ __launch_bounds__(256) void seg_offsets_kernel(
        int* __restrict__ partC, int* __restrict__ partV,
        const int* __restrict__ rp16C, const int* __restrict__ rp16V) {
    int j = blockIdx.x * blockDim.x + threadIdx.x;
    const int tot = NCON + NVAR;
    for (; j < tot; j += gridDim.x * blockDim.x) {
        if (j < NCON) {
            const int chunk = j / CHNC, off = j - chunk * CHNC;
            int* p = partC + (size_t)chunk * HSEG * CHNC + off;
            int run = rp16C[j];
#pragma unroll
            for (int t = 0; t < HSEG; ++t) {
                const int old = p[(size_t)t * CHNC];
                p[(size_t)t * CHNC] = run;
                run += old;
            }
        } else {
            const int jj = j - NCON;
            const int chunk = jj / CHNV, off = jj - chunk * CHNV;
            int* p = partV + (size_t)chunk * HSEG * CHNV + off;
            int run = rp16V[jj];
#pragma unroll
            for (int t = 0; t < HSEG; ++t) {
                const int old = p[(size_t)t * CHNV];
                p[(size_t)t * CHNV] = run;
                run += old;
            }
        }
    }
}

// atomic-free scatter: block (cg,seg) loads its cursor row into LDS, scans
// its edge segment, and for dsts in its chunk assigns slots via LDS cursor++
// (exact by seg_offsets construction; disjoint across blocks). Write regions:
// C-chunk 0.94MB / V-chunk 1.24MB; all 32 seg-blocks of a chunk share XCD
// cg&7 (blockIdx = seg*40+cg, 40%8==0) so lines combine in that L2.
// Replaces 3.2M device atomicAdds (~64us/direction floor at 25G/s, round-2).
__global__ __launch_bounds__(256) void scatter_lds_kernel(
        const int* __restrict__ ci, const int* __restrict__ vi,
        const float* __restrict__ ef,
        int* __restrict__ partC, int* __restrict__ partV,
        int2* __restrict__ epC, int2* __restrict__ epV, int E) {
    __shared__ int lcur[CHNV];
    const int cg  = blockIdx.x % (NCHC + NCHV);
    const int seg = blockIdx.x / (NCHC + NCHV);
    const bool isC = cg < NCHC;
    const int chunk  = isC ? cg : cg - NCHC;
    const int chunkN = isC ? CHNC : CHNV;
    const int base   = chunk * chunkN;
    const int* __restrict__ dst = isC ? ci : vi;
    const int* __restrict__ src = isC ? vi : ci;
    int2* __restrict__ ep = isC ? epC : epV;
    int* __restrict__ curs = (isC ? partC : partV) + (size_t)(chunk * HSEG + seg) * chunkN;

    for (int i = threadIdx.x; i < chunkN; i += 256) lcur[i] = curs[i];
    __syncthreads();

    const int s0 = (int)((long long)seg * E / HSEG);
    const int s1 = (int)((long long)(seg + 1) * E / HSEG);
    const int nvec = (s1 - s0) >> 2;
    const int4* d4 = (const int4*)(dst + s0);
    for (int i = threadIdx.x; i < nvec; i += 256) {
        const int4 t = d4[i];
        const int e0 = s0 + (i << 2);
        const unsigned r0 = (unsigned)(t.x - base);
        const unsigned r1 = (unsigned)(t.y - base);
        const unsigned r2 = (unsigned)(t.z - base);
        const unsigned r3 = (unsigned)(t.w - base);
        if (r0 < (unsigned)chunkN) {
            const int slot = atomicAdd(&lcur[r0], 1);
            ep[slot] = make_int2(src[e0 + 0], __float_as_int(ef[e0 + 0]));
        }
        if (r1 < (unsigned)chunkN) {
            const int slot = atomicAdd(&lcur[r1], 1);
            ep[slot] = make_int2(src[e0 + 1], __float_as_int(ef[e0 + 1]));
        }
        if (r2 < (unsigned)chunkN) {
            const int slot = atomicAdd(&lcur[r2], 1);
            ep[slot] = make_int2(src[e0 + 2], __float_as_int(ef[e0 + 2]));
        }
        if (r3 < (unsigned)chunkN) {
            const int slot = atomicAdd(&lcur[r3], 1);
            ep[slot] = make_int2(src[e0 + 3], __float_as_int(ef[e0 + 3]));
        }
    }
    for (int i = s0 + (nvec << 2) + threadIdx.x; i < s1; i += 256) {
        const unsigned rel = (unsigned)(dst[i] - base);
        if (rel < (unsigned)chunkN) {
            const int slot = atomicAdd(&lcur[rel], 1);
            ep[slot] = make_int2(src[i], __float_as_int(ef[i]));
        }
    }
}

// fallback: atomic histogram (used only if ws can't fit the partials)
__global__ __launch_bounds__(256) void hist2_kernel(
        const int* __restrict__ ci, const int* __restrict__ vi,
        int* __restrict__ degC, int* __restrict__ degV, int E) {
    int i = blockIdx.x * blockDim.x + threadIdx.x;
    for (; i < E; i += gridDim.x * blockDim.x) {
        atomicAdd(&degC[ci[i]], 1);
        atomicAdd(&degV[vi[i]], 1);
    }
}

template <bool PAD>
__global__ __launch_bounds__(256) void chunk_sum_kernel(const int* __restrict__ hist,
                                                        int* __restrict__ csum, int N) {
    __shared__ int wpart[4];
    const int base = blockIdx.x * 1024 + threadIdx.x * 4;
    int s = 0;
    if (base + 3 < N) {
        int4 t = *(const int4*)(hist + base);
        if (PAD) s = ((t.x+15)&~15) + ((t.y+15)&~15) + ((t.z+15)&~15) + ((t.w+15)&~15);
        else     s = t.x + t.y + t.z + t.w;
    } else {
#pragma unroll
        for (int j = 0; j < 4; ++j)
            if (base + j < N) { int v = hist[base + j]; s += PAD ? ((v+15)&~15) : v; }
    }
    s = wtotal64_i(s);
    if ((threadIdx.x & 63) == 0) wpart[threadIdx.x >> 6] = s;
    __syncthreads();
    if (threadIdx.x == 0) csum[blockIdx.x] = wpart[0] + wpart[1] + wpart[2] + wpart[3];
}

__global__ void chunk_offsets_kernel(const int* __restrict__ csum, int* __restrict__ coff,
                                     int* __restrict__ rowptr, int nchunk, int N) {
    const int lane = threadIdx.x;
    int carry = 0;
    for (int base = 0; base < nchunk; base += 64) {
        const int i = base + lane;
        int val = (i < nchunk) ? csum[i] : 0;
        int incl = val;
#pragma unroll
        for (int off = 1; off < 64; off <<= 1) {
            int t = __shfl_up(incl, off, 64);
            if (lane >= off) incl += t;
        }
        if (i < nchunk) coff[i] = incl - val + carry;
        carry += __shfl(incl, 63, 64);
    }
    if (lane == 0) rowptr[N] = carry;
}

template <bool PAD>
__global__ __launch_bounds__(256) void chunk_apply_kernel(
        const int* __restrict__ hist, const int* __restrict__ coff,
        int* __restrict__ rowptr, int* __restrict__ cursor, int N) {
    __shared__ int wpart[4];
    const int wv = threadIdx.x >> 6;
    const int lane = threadIdx.x & 63;
    const int base = blockIdx.x * 1024 + threadIdx.x * 4;
    int v0 = 0, v1 = 0, v2 = 0, v3 = 0;
    if (base + 3 < N) {
        int4 t = *(const int4*)(hist + base);
        v0 = t.x; v1 = t.y; v2 = t.z; v3 = t.w;
    } else {
        if (base + 0 < N) v0 = hist[base + 0];
        if (base + 1 < N) v1 = hist[base + 1];
        if (base + 2 < N) v2 = hist[base + 2];
        if (base + 3 < N) v3 = hist[base + 3];
    }
    if (PAD) { v0 = (v0+15)&~15; v1 = (v1+15)&~15; v2 = (v2+15)&~15; v3 = (v3+15)&~15; }
    const int s = v0 + v1 + v2 + v3;
    int incl = s;
#pragma unroll
    for (int off = 1; off < 64; off <<= 1) {
        int t = __shfl_up(incl, off, 64);
        if (lane >= off) incl += t;
    }
    if (lane == 63) wpart[wv] = incl;
    __syncthreads();
    int excl = coff[blockIdx.x] + incl - s;
    for (int w = 0; w < wv; ++w) excl += wpart[w];
    if (base + 0 < N) { rowptr[base + 0] = excl; cursor[base + 0] = excl; excl += v0; }
    if (base + 1 < N) { rowptr[base + 1] = excl; cursor[base + 1] = excl; excl += v1; }
    if (base + 2 < N) { rowptr[base + 2] = excl; cursor[base + 2] = excl; excl += v2; }
    if (base + 3 < N) { rowptr[base + 3] = excl; cursor[base + 3] = excl; excl += v3; }
}

// fallback scatter: XCD-bucketed, ONE direction per launch, device atomics
template <int NDST>
__global__ __launch_bounds__(256) void scatter_dir_kernel(
        const int* __restrict__ dst, const int* __restrict__ src,
        const float* __restrict__ ef,
        int* __restrict__ cur, int2* __restrict__ ep, int E) {
    const int rep = blockIdx.x & 7;
    const int stride = (gridDim.x >> 3) * blockDim.x;
    int i = (blockIdx.x >> 3) * blockDim.x + threadIdx.x;
    for (; i < E; i += stride) {
        const int d = dst[i];
        const int b = (int)(((long long)d * 8) / NDST);
        if (b == rep) {
            const int slot = atomicAdd(&cur[d], 1);
            ep[slot] = make_int2(src[i], __float_as_int(ef[i]));
        }
    }
}

// ---------------- fused node linear via MFMA: Y = X @ W^T (+b) -> f16 ----------------
// Round-8 validated layouts on HW:
//   A-frag: lane l holds X[n0+(l&15)][kc*32+(l>>4)*8+j]
//   B-frag: lane l holds W[ct*16+(l&15)][kc*32+(l>>4)*8+j]
//   D:      lane l, reg r -> row (l>>4)*4+r, col l&15 (+16*ct)

__global__ __launch_bounds__(256, 3) void lin2_kernel(
        const float* __restrict__ XR, const float* __restrict__ WR,
        const float* __restrict__ bR, _Float16* __restrict__ YR, int NR,
        const float* __restrict__ XL, const float* __restrict__ WL,
        _Float16* __restrict__ YL, int NL, int nbR) {
    const int wv   = threadIdx.x >> 6;
    const int lane = threadIdx.x & 63;
    const int col  = lane & 15;
    const int kgrp = lane >> 4;           // 0..3
    const bool isR = (int)blockIdx.x < nbR;
    const float* X = isR ? XR : XL;
    const float* W = isR ? WR : WL;
    _Float16* Y    = isR ? YR : YL;
    const int N    = isR ? NR : NL;
    const int b0   = isR ? 0 : nbR;
    const int nb   = isR ? nbR : (gridDim.x - nbR);

    f16x8 bf[4][2];
#pragma unroll
    for (int ct = 0; ct < 4; ++ct)
#pragma unroll
        for (int kc = 0; kc < 2; ++kc) {
            const float* wrow = W + (size_t)(ct * 16 + col) * EMB + kc * 32 + kgrp * 8;
            bf[ct][kc] = cvt8_f16(*(const float4*)wrow, *(const float4*)(wrow + 4));
        }
    float bias[4];
#pragma unroll
    for (int ct = 0; ct < 4; ++ct) bias[ct] = isR ? bR[ct * 16 + col] : 0.0f;

    const int ntile = (N + 15) >> 4;
    const int nW = nb * 4;
    for (int t = ((int)blockIdx.x - b0) * 4 + wv; t < ntile; t += nW) {
        const int n0 = t << 4;
        const int srow = min(n0 + col, N - 1);
        const float* xrow = X + (size_t)srow * EMB + kgrp * 8;
        const float4 x0 = *(const float4*)(xrow);
        const float4 x1 = *(const float4*)(xrow + 4);
        const float4 x2 = *(const float4*)(xrow + 32);
        const float4 x3 = *(const float4*)(xrow + 36);
        const f16x8 a0 = cvt8_f16(x0, x1);
        const f16x8 a1 = cvt8_f16(x2, x3);
        f32x4 acc[4];
#pragma unroll
        for (int ct = 0; ct < 4; ++ct) {
            acc[ct] = __builtin_amdgcn_mfma_f32_16x16x32_f16(
                a0, bf[ct][0], (f32x4){0.0f, 0.0f, 0.0f, 0.0f}, 0, 0, 0);
            acc[ct] = __builtin_amdgcn_mfma_f32_16x16x32_f16(
                a1, bf[ct][1], acc[ct], 0, 0, 0);
        }
#pragma unroll
        for (int r = 0; r < 4; ++r) {
            const int n = n0 + (kgrp << 2) + r;
            if (n < N) {
                _Float16* yrow = Y + (size_t)n * EMB + col;
#pragma unroll
                for (int ct = 0; ct < 4; ++ct)
                    yrow[ct * 16] = (_Float16)(acc[ct][r] + bias[ct]);
            }
        }
    }
}

// ---------------- edge stage: wave per node, abar accumulate ----------------
// Key identity: sum_e relu(LN(h_e)) @ Wf^T = (sum_e relu(LN(h_e))) @ Wf^T.
// (256,4) spill-free since round-7 moved the Wf matvec out (round-6 model:
// VGPR budget ~256/arg). LDS-transpose reduce + cross-node pipeline.

__global__ __launch_bounds__(256, 4) void edge_abar_kernel(
        const int* __restrict__ rp16, const int* __restrict__ deg,
        const int2* __restrict__ ep,
        const _Float16* __restrict__ RL, const _Float16* __restrict__ LL,
        const float* __restrict__ We, const float* __restrict__ g1,
        const float* __restrict__ b1, _Float16* __restrict__ ABAR, int Nr) {
    __shared__ __align__(16) float tbuf[4][16][68];   // [wave][col][k] padded stride
    const int wv   = threadIdx.x >> 6;
    const int lane = threadIdx.x & 63;
    const int col  = lane & 15;
    const int quad = lane >> 4;
    const int kb   = quad * 8;

    half2_t weh[8], gkh[8], bkh[8];
#pragma unroll
    for (int j = 0; j < 4; ++j) {
        weh[j]     = half2_t{(_Float16)We[kb + 2*j],      (_Float16)We[kb + 2*j + 1]};
        weh[4 + j] = half2_t{(_Float16)We[kb + 32 + 2*j], (_Float16)We[kb + 32 + 2*j + 1]};
        gkh[j]     = half2_t{(_Float16)g1[kb + 2*j],      (_Float16)g1[kb + 2*j + 1]};
        gkh[4 + j] = half2_t{(_Float16)g1[kb + 32 + 2*j], (_Float16)g1[kb + 32 + 2*j + 1]};
        bkh[j]     = half2_t{(_Float16)b1[kb + 2*j],      (_Float16)b1[kb + 2*j + 1]};
        bkh[4 + j] = half2_t{(_Float16)b1[kb + 32 + 2*j], (_Float16)b1[kb + 32 + 2*j + 1]};
    }

    const int nW = gridDim.x * 4;
    int n = blockIdx.x * 4 + wv;          // Nr >= 50000 > grid*4, so n < Nr here
    int pg0 = rp16[n] >> 4;
    int pg1 = rp16[n + 1] >> 4;
    int pdn = deg[n];

    bool livN = false; float fN = 0.0f;
    f16x8 llaN = {}, llbN = {};
    auto issue_group = [&](int gbase, int cnt) {
        livN = col < cnt;
        int2 p = ep[(gbase << 4) + col];
        const int s2 = livN ? p.x : 0;
        fN = livN ? __int_as_float(p.y) : 0.0f;
        llaN = *(const f16x8*)(LL + (size_t)s2 * EMB + kb);
        llbN = *(const f16x8*)(LL + (size_t)s2 * EMB + kb + 32);
    };
    if (pg0 < pg1) issue_group(pg0, pdn);     // prime first node's first group

    while (true) {
        const int g0 = pg0, g1e = pg1, dn = pdn;
        const int nn = n + nW;
        const bool hasNext = nn < Nr;
        if (hasNext) {                         // issue next node's meta EARLY
            pg0 = rp16[nn] >> 4;
            pg1 = rp16[nn + 1] >> 4;
            pdn = deg[nn];
        }

        half2_t rl2[8];
        *(f16x8*)&rl2[0] = *(const f16x8*)(RL + (size_t)n * EMB + kb);
        *(f16x8*)&rl2[4] = *(const f16x8*)(RL + (size_t)n * EMB + kb + 32);

        f32x2 acc2[8];
#pragma unroll
        for (int j = 0; j < 8; ++j) acc2[j] = f32x2{0.0f, 0.0f};

        bool didNext = false;
        for (int g = g0; g < g1e; ++g) {
            const bool liv = livN;
            const float f = fN;
            half2_t h2[8];
            *(f16x8*)&h2[0] = llaN;
            *(f16x8*)&h2[4] = llbN;
            if (g + 1 < g1e) {
                issue_group(g + 1, dn - ((g + 1 - g0) << 4));   // in-node prefetch
            } else if (hasNext && pg0 < pg1) {
                issue_group(pg0, pdn);                           // next-node prefetch
                didNext = true;
            }
            const _Float16 fh = (_Float16)f;
            const half2_t f2 = half2_t{fh, fh};
            const half2_t one2 = half2_t{(_Float16)1.0f, (_Float16)1.0f};
            float ps = 0.0f, pq = 0.0f;
#pragma unroll
            for (int j = 0; j < 8; ++j) {
                h2[j] = (h2[j] + rl2[j]) + f2 * weh[j];
                ps = dot2f(h2[j], one2, ps);
                pq = dot2f(h2[j], h2[j], pq);
            }
            ps += __shfl_xor(ps, 16, 64); ps += __shfl_xor(ps, 32, 64);
            pq += __shfl_xor(pq, 16, 64); pq += __shfl_xor(pq, 32, 64);
            const float mean = ps * (1.0f / EMB);
            const float var  = pq * (1.0f / EMB) - mean * mean;
            const float rs   = rsqrtf(var + EPSLN);
            const _Float16 rsh = (_Float16)rs;
            const _Float16 mnh = (_Float16)mean;
            const half2_t rs2 = half2_t{rsh, rsh};
            const half2_t mn2 = half2_t{mnh, mnh};
            const half2_t z2  = half2_t{(_Float16)0.0f, (_Float16)0.0f};
            if (liv) {
#pragma unroll
                for (int j = 0; j < 8; ++j) {
                    const half2_t sc = gkh[j] * rs2;
                    half2_t a = (h2[j] - mn2) * sc + bkh[j];
                    a = hmax2(a, z2);
                    f32x2 cv; cv.x = (float)a.x; cv.y = (float)a.y;
                    acc2[j] += cv;
                }
            }
        }

        // ---- LDS-transpose reduce ----
        float* tb = &tbuf[wv][col][0];
        *(float4*)(tb + kb)      = make_float4(acc2[0].x, acc2[0].y, acc2[1].x, acc2[1].y);
        *(float4*)(tb + kb + 4)  = make_float4(acc2[2].x, acc2[2].y, acc2[3].x, acc2[3].y);
        *(float4*)(tb + kb + 32) = make_float4(acc2[4].x, acc2[4].y, acc2[5].x, acc2[5].y);
        *(float4*)(tb + kb + 36) = make_float4(acc2[6].x, acc2[6].y, acc2[7].x, acc2[7].y);
        float t0[16];
#pragma unroll
        for (int c2 = 0; c2 < 16; ++c2) t0[c2] = tbuf[wv][c2][lane];
        const float s01 = (t0[0] + t0[1]) + (t0[2] + t0[3]);
        const float s23 = (t0[4] + t0[5]) + (t0[6] + t0[7]);
        const float s45 = (t0[8] + t0[9]) + (t0[10] + t0[11]);
        const float s67 = (t0[12] + t0[13]) + (t0[14] + t0[15]);
        ABAR[(size_t)n * EMB + lane] = (_Float16)((s01 + s23) + (s45 + s67));

        if (!hasNext) break;
        if (!didNext && pg0 < pg1) issue_group(pg0, pdn);   // zero-group edge cases
        n = nn;
    }
}

// ---------------- fallback edge path (wave per node, abar accumulate) ----------------

__global__ __launch_bounds__(256, 4) void edge_csr_kernel(
        const int* __restrict__ rowptr, const int2* __restrict__ ep,
        const _Float16* __restrict__ RL, const _Float16* __restrict__ LL,
        const float* __restrict__ Wecol, const float* __restrict__ g1,
        const float* __restrict__ b1,
        _Float16* __restrict__ ABAR, int Nr) {
    const int lane = threadIdx.x & 63;
    const float we  = Wecol[lane];
    const float g   = g1[lane];
    const float bb  = b1[lane];
    const int nW = gridDim.x * 4;
    for (int n = blockIdx.x * 4 + (threadIdx.x >> 6); n < Nr; n += nW) {
        const int beg = rowptr[n];
        const int end = rowptr[n + 1];
        const float rl = (float)RL[(size_t)n * EMB + lane];
        float acc = 0.0f;
        for (int idx = beg; idx < end; ++idx) {
            const int2 p = ep[idx];
            const float f = __int_as_float(p.y);
            float h = rl + (float)LL[(size_t)p.x * EMB + lane] + f * we;
            const float s1 = wtotal64(h);
            const float s2 = wtotal64(h * h);
            const float m   = s1 * (1.0f / EMB);
            const float var = s2 * (1.0f / EMB) - m * m;
            acc += fmaxf((h - m) * rsqrtf(var + EPSLN) * g + bb, 0.0f);
        }
        ABAR[(size_t)n * EMB + lane] = (_Float16)acc;
    }
}

// ---------------- fused output MLP via MFMA ----------------
// Per 16-node tile, 3 chained GEMMs (24 MFMA): agg=abar@Wf^T+deg*bf ->
// rowwise LN in D-layout (4-step shfl_xor over the 16-lane row group) ->
// o=relu(z@Wo1a^T+right@Wo1b^T+bo1) (z via LDS D->A transpose) ->
// right+=o@Wo2^T+bo2. LDS [16][72] f16 keeps 16B alignment, 2-way bank
// aliasing (free). ~180 VGPR -> (256,1), spill-free per round-6 model.

__global__ __launch_bounds__(256, 1) void out_kernel(
        const _Float16* __restrict__ ABAR, const int* __restrict__ deg,
        float* __restrict__ right,
        const float* __restrict__ g2, const float* __restrict__ b2,
        const float* __restrict__ Wf, const float* __restrict__ bfp,
        const float* __restrict__ Wo1, const float* __restrict__ Wo2,
        const float* __restrict__ bo1, const float* __restrict__ bo2, int N) {
    __shared__ __align__(16) _Float16 zt[4][16][72];
    __shared__ __align__(16) _Float16 ot[4][16][72];
    const int wv   = threadIdx.x >> 6;
    const int lane = threadIdx.x & 63;
    const int col  = lane & 15;
    const int kgrp = lane >> 4;

    f16x8 bF[4][2], b1a[4][2], b1b[4][2], b2f[4][2];
#pragma unroll
    for (int ct = 0; ct < 4; ++ct)
#pragma unroll
        for (int kc = 0; kc < 2; ++kc) {
            const int row = ct * 16 + col;
            const int ko  = kc * 32 + kgrp * 8;
            const float* wf = Wf  + (size_t)row * EMB + ko;
            const float* w1 = Wo1 + (size_t)row * 2 * EMB + ko;
            const float* w2 = Wo2 + (size_t)row * EMB + ko;
            bF[ct][kc]  = cvt8_f16(*(const float4*)wf, *(const float4*)(wf + 4));
            b1a[ct][kc] = cvt8_f16(*(const float4*)w1, *(const float4*)(w1 + 4));
            b1b[ct][kc] = cvt8_f16(*(const float4*)(w1 + EMB), *(const float4*)(w1 + EMB + 4));
            b2f[ct][kc] = cvt8_f16(*(const float4*)w2, *(const float4*)(w2 + 4));
        }
    float bfc[4], gc[4], bbc[4], bo1c[4], bo2c[4];
#pragma unroll
    for (int ct = 0; ct < 4; ++ct) {
        const int cd = ct * 16 + col;
        bfc[ct]  = bfp[cd];
        gc[ct]   = g2[cd];
        bbc[ct]  = b2[cd];
        bo1c[ct] = bo1[cd];
        bo2c[ct] = bo2[cd];
    }

    const int ntile = N >> 4;          // N % 16 == 0
    const int nW = gridDim.x * 4;
    for (int t = blockIdx.x * 4 + wv; t < ntile; t += nW) {
        const int n0 = t << 4;
        // ---- GEMM1: agg = abar @ Wf^T ----
        const _Float16* arow = ABAR + (size_t)(n0 + col) * EMB + kgrp * 8;
        const f16x8 aA0 = *(const f16x8*)(arow);
        const f16x8 aA1 = *(const f16x8*)(arow + 32);
        f32x4 acc[4];
#pragma unroll
        for (int ct = 0; ct < 4; ++ct) {
            acc[ct] = __builtin_amdgcn_mfma_f32_16x16x32_f16(
                aA0, bF[ct][0], (f32x4){0.0f, 0.0f, 0.0f, 0.0f}, 0, 0, 0);
            acc[ct] = __builtin_amdgcn_mfma_f32_16x16x32_f16(
                aA1, bF[ct][1], acc[ct], 0, 0, 0);
        }
        // deg for my 4 rows
        float dnr[4];
#pragma unroll
        for (int r = 0; r < 4; ++r) dnr[r] = (float)deg[n0 + (kgrp << 2) + r];
        // ---- rowwise LN in D-layout ----
#pragma unroll
        for (int r = 0; r < 4; ++r) {
            float s1 = 0.0f, s2 = 0.0f;
#pragma unroll
            for (int ct = 0; ct < 4; ++ct) {
                const float a = acc[ct][r] + dnr[r] * bfc[ct];
                acc[ct][r] = a;
                s1 += a; s2 += a * a;
            }
            s1 += __shfl_xor(s1, 1, 64); s2 += __shfl_xor(s2, 1, 64);
            s1 += __shfl_xor(s1, 2, 64); s2 += __shfl_xor(s2, 2, 64);
            s1 += __shfl_xor(s1, 4, 64); s2 += __shfl_xor(s2, 4, 64);
            s1 += __shfl_xor(s1, 8, 64); s2 += __shfl_xor(s2, 8, 64);
            const float mean = s1 * (1.0f / EMB);
            const float var  = s2 * (1.0f / EMB) - mean * mean;
            const float rs   = rsqrtf(var + EPSLN);
            const int zr = (kgrp << 2) + r;
#pragma unroll
            for (int ct = 0; ct < 4; ++ct)
                zt[wv][zr][ct * 16 + col] =
                    (_Float16)((acc[ct][r] - mean) * rs * gc[ct] + bbc[ct]);
        }
        // ---- GEMM3: o = relu(z@Wo1a^T + right@Wo1b^T + bo1) ----
        const _Float16* zrow = &zt[wv][col][kgrp * 8];
        const f16x8 zA0 = *(const f16x8*)(zrow);
        const f16x8 zA1 = *(const f16x8*)(zrow + 32);
        const float* rrow = right + (size_t)(n0 + col) * EMB + kgrp * 8;
        const f16x8 rA0 = cvt8_f16(*(const float4*)(rrow), *(const float4*)(rrow + 4));
        const f16x8 rA1 = cvt8_f16(*(const float4*)(rrow + 32), *(const float4*)(rrow + 36));
        f32x4 acc3[4];
#pragma unroll
        for (int ct = 0; ct < 4; ++ct) {
            acc3[ct] = __builtin_amdgcn_mfma_f32_16x16x32_f16(
                zA0, b1a[ct][0], (f32x4){0.0f, 0.0f, 0.0f, 0.0f}, 0, 0, 0);
            acc3[ct] = __builtin_amdgcn_mfma_f32_16x16x32_f16(
                zA1, b1a[ct][1], acc3[ct], 0, 0, 0);
            acc3[ct] = __builtin_amdgcn_mfma_f32_16x16x32_f16(
                rA0, b1b[ct][0], acc3[ct], 0, 0, 0);
            acc3[ct] = __builtin_amdgcn_mfma_f32_16x16x32_f16(
                rA1, b1b[ct][1], acc3[ct], 0, 0, 0);
        }
#pragma unroll
        for (int r = 0; r < 4; ++r) {
            const int orr = (kgrp << 2) + r;
#pragma unroll
            for (int ct = 0; ct < 4; ++ct)
                ot[wv][orr][ct * 16 + col] =
                    (_Float16)fmaxf(acc3[ct][r] + bo1c[ct], 0.0f);
        }
        // ---- GEMM4: right += o@Wo2^T + bo2 ----
        const _Float16* orow = &ot[wv][col][kgrp * 8];
        const f16x8 oA0 = *(const f16x8*)(orow);
        const f16x8 oA1 = *(const f16x8*)(orow + 32);
        f32x4 acc4[4];
#pragma unroll
        for (int ct = 0; ct < 4; ++ct) {
            acc4[ct] = __builtin_amdgcn_mfma_f32_16x16x32_f16(
                oA0, b2f[ct][0], (f32x4){0.0f, 0.0f, 0.0f, 0.0f}, 0, 0, 0);
            acc4[ct] = __builtin_amdgcn_mfma_f32_16x16x32_f16(
                oA1, b2f[ct][1], acc4[ct], 0, 0, 0);
        }
#pragma unroll
        for (int r = 0; r < 4; ++r) {
            float* rr = right + (size_t)(n0 + (kgrp << 2) + r) * EMB + col;
#pragma unroll
            for (int ct = 0; ct < 4; ++ct)
                rr[ct * 16] += acc4[ct][r] + bo2c[ct];
        }
    }
}

extern "C" void kernel_launch(void* const* d_in, const int* in_sizes, int n_in,
                              void* d_out, int out_size, void* d_ws, size_t ws_size,
                              hipStream_t stream) {
    const float* cf  = (const float*)d_in[0];
    const float* vfp = (const float*)d_in[1];
    const int*   ei  = (const int*)d_in[2];
    const float* ef  = (const float*)d_in[3];
    const float* Wl  = (const float*)d_in[4];
    const float* bl  = (const float*)d_in[5];
    const float* We  = (const float*)d_in[6];
    const float* Wr  = (const float*)d_in[7];
    const float* g1  = (const float*)d_in[8];
    const float* b1  = (const float*)d_in[9];
    const float* Wf  = (const float*)d_in[10];
    const float* bfp = (const float*)d_in[11];
    const float* g2  = (const float*)d_in[12];
    const float* b2  = (const float*)d_in[13];
    const float* Wo1 = (const float*)d_in[14];
    const float* bo1 = (const float*)d_in[15];
    const float* Wo2 = (const float*)d_in[16];
    const float* bo2 = (const float*)d_in[17];

    float* c = (float*)d_out;
    float* v = c + (size_t)NCON * EMB;
    (void)hipMemcpyAsync(c, cf,  (size_t)NCON * EMB * sizeof(float), hipMemcpyDeviceToDevice, stream);
    (void)hipMemcpyAsync(v, vfp, (size_t)NVAR * EMB * sizeof(float), hipMemcpyDeviceToDevice, stream);

    float* wsf = (float*)d_ws;
    size_t off = 0;
    _Float16* AGG = (_Float16*)(wsf + off); off += (size_t)NVAR * EMB / 2;  // f16 (abar)
    _Float16* RL  = (_Float16*)(wsf + off); off += (size_t)NVAR * EMB / 2;  // f16
    _Float16* LL  = (_Float16*)(wsf + off); off += (size_t)NVAR * EMB / 2;  // f16
    int* degC  = (int*)(wsf + off); off += NCON;
    int* degV  = (int*)(wsf + off); off += NVAR;
    int* rp16C = (int*)(wsf + off); off += NCON + 4;
    int* curC  = (int*)(wsf + off); off += NCON;
    int* rp16V = (int*)(wsf + off); off += NVAR + 4;
    int* curV  = (int*)(wsf + off); off += NVAR;
    int* csumC = (int*)(wsf + off); off += 128;
    int* coffC = (int*)(wsf + off); off += 128;
    int* csumV = (int*)(wsf + off); off += 128;
    int* coffV = (int*)(wsf + off); off += 128;
    size_t off_edges = off;
    int2* epC = (int2*)(wsf + off); off += (size_t)2 * PADEC;
    int2* epV = (int2*)(wsf + off); off += (size_t)2 * PADEV;
    const bool use_mfma = ws_size >= off * sizeof(float);
    // histogram/scatter partials (19.2 MB) after the edge arrays
    int* partC = (int*)(wsf + off); off += (size_t)NCHC * HSEG * CHNC;
    int* partV = (int*)(wsf + off); off += (size_t)NCHV * HSEG * CHNV;
    const bool use_ldshist = use_mfma && ws_size >= off * sizeof(float);
    if (!use_mfma) {
        off = off_edges;
        epC = (int2*)(wsf + off); off += (size_t)2 * NEDGE;
        epV = (int2*)(wsf + off); off += (size_t)2 * NEDGE;
    }

    const int* ci = ei;
    const int* vi = ei + NEDGE;

    const dim3 blk(256);
    const int NB = 2048;
    const int NBL = 1536;
    const int nchC = (NCON + 1023) / 1024;   // 49
    const int nchV = (NVAR + 1023) / 1024;   // 98
    const int NGRP = NCHC + NCHV;            // 40

    if (use_ldshist) {
        hist_part_kernel<<<NGRP * HSEG, blk, 0, stream>>>(ci, vi, partC, partV, NEDGE);
        hist_reduce_kernel<<<640, blk, 0, stream>>>(partC, partV, degC, degV);
    } else {
        (void)hipMemsetAsync(degC, 0, NCON * sizeof(int), stream);
        (void)hipMemsetAsync(degV, 0, NVAR * sizeof(int), stream);
        hist2_kernel<<<1024, blk, 0, stream>>>(ci, vi, degC, degV, NEDGE);
    }
    if (use_mfma) {
        chunk_sum_kernel<true><<<nchC, blk, 0, stream>>>(degC, csumC, NCON);
        chunk_sum_kernel<true><<<nchV, blk, 0, stream>>>(degV, csumV, NVAR);
        chunk_offsets_kernel<<<1, 64, 0, stream>>>(csumC, coffC, rp16C, nchC, NCON);
        chunk_offsets_kernel<<<1, 64, 0, stream>>>(csumV, coffV, rp16V, nchV, NVAR);
        chunk_apply_kernel<true><<<nchC, blk, 0, stream>>>(degC, coffC, rp16C, curC, NCON);
        chunk_apply_kernel<true><<<nchV, blk, 0, stream>>>(degV, coffV, rp16V, curV, NVAR);
    } else {
        chunk_sum_kernel<false><<<nchC, blk, 0, stream>>>(degC, csumC, NCON);
        chunk_sum_kernel<false><<<nchV, blk, 0, stream>>>(degV, csumV, NVAR);
        chunk_offsets_kernel<<<1, 64, 0, stream>>>(csumC, coffC, rp16C, nchC, NCON);
        chunk_offsets_kernel<<<1, 64, 0, stream>>>(csumV, coffV, rp16V, nchV, NVAR);
        chunk_apply_kernel<false><<<nchC, blk, 0, stream>>>(degC, coffC, rp16C, curC, NCON);
        chunk_apply_kernel<false><<<nchV, blk, 0, stream>>>(degV, coffV, rp16V, curV, NVAR);
    }
    if (use_ldshist) {
        // two-pass deterministic scatter: counts -> per-(chunk,seg) cursors,
        // then atomic-free LDS-cursor scatter (both directions, one launch).
        seg_offsets_kernel<<<640, blk, 0, stream>>>(partC, partV, rp16C, rp16V);
        scatter_lds_kernel<<<NGRP * HSEG, blk, 0, stream>>>(
            ci, vi, ef, partC, partV, epC, epV, NEDGE);
    } else {
        scatter_dir_kernel<NCON><<<2048, blk, 0, stream>>>(ci, vi, ef, curC, epC, NEDGE);
        scatter_dir_kernel<NVAR><<<2048, blk, 0, stream>>>(vi, ci, ef, curV, epV, NEDGE);
    }

    for (int k = 0; k < 4; ++k) {
        const bool v2c = ((k & 1) == 0);
        float* right   = v2c ? c : v;
        float* left    = v2c ? v : c;
        const int Nr   = v2c ? NCON : NVAR;
        const int Nl   = v2c ? NVAR : NCON;
        const int nbR  = v2c ? NBL / 3 : 2 * NBL / 3;   // split blocks ~ Nr : Nl
        const int* degR = v2c ? degC : degV;

        lin2_kernel<<<NBL, blk, 0, stream>>>(
            right, Wl + (size_t)k * EMB * EMB, bl + (size_t)k * EMB, RL, Nr,
            left,  Wr + (size_t)k * EMB * EMB, LL, Nl, nbR);

        if (use_mfma) {
            edge_abar_kernel<<<NB, blk, 0, stream>>>(
                v2c ? rp16C : rp16V, degR, v2c ? epC : epV,
                RL, LL, We + (size_t)k * EMB,
                g1 + (size_t)k * EMB, b1 + (size_t)k * EMB,
                AGG, Nr);
        } else {
            edge_csr_kernel<<<NB, blk, 0, stream>>>(
                v2c ? rp16C : rp16V, v2c ? epC : epV,
                RL, LL, We + (size_t)k * EMB,
                g1 + (size_t)k * EMB, b1 + (size_t)k * EMB,
                AGG, Nr);
        }
        out_kernel<<<NB, blk, 0, stream>>>(AGG, degR, right,
                                           g2 + (size_t)k * EMB, b2 + (size_t)k * EMB,
                                           Wf + (size_t)k * EMB * EMB,
                                           bfp + (size_t)k * EMB,
                                           Wo1 + (size_t)k * EMB * 2 * EMB,
                                           Wo2 + (size_t)k * EMB * EMB,
                                           bo1 + (size_t)k * EMB, bo2 + (size_t)k * EMB,
                                           Nr);
    }
}